// Round 14
// baseline (1375.258 us; speedup 1.0000x reference)
//
#include <hip/hip_runtime.h>

// ---------------------------------------------------------------------------
// HybridThoughtAwareAttention  (B=2,S=2048,E=1024,H=16,D=64,K_TOP=64,M=256)
// Round 21: sparse_sel spill fix. Round-20's QBLK=16 win carried a 160 MB
// scratch-spill (su[16][4]=64 VGPRs over budget; WRITE_SIZE 170 MB). Same
// selection math, but 512-thread blocks: each of 8 waves covers 256 keys
// (8 tiles) => su[8][4]=32 VGPRs, live set ~94 regs, no spill. MFMA count,
// Khi traffic, per-row radix/scan order, gcidx layout all unchanged.
// All other kernels identical to the measured round-20 source.
// ---------------------------------------------------------------------------

constexpr int cB = 2, cS = 2048, cE = 1024, cH = 16, cD = 64, cKTOP = 64, cM = 256;
constexpr float cEPS = 1e-6f;

typedef _Float16 half8 __attribute__((ext_vector_type(8)));
typedef float f32x16 __attribute__((ext_vector_type(16)));

__device__ __forceinline__ unsigned int f2key(float f) {    // monotone f32->u32
    unsigned int u = __float_as_uint(f);
    return (u & 0x80000000u) ? ~u : (u | 0x80000000u);
}

__device__ __forceinline__ unsigned short h2u(_Float16 h) {
    union { _Float16 h; unsigned short u; } x; x.h = h; return x.u;
}

__device__ __forceinline__ half8 ld_half8(const unsigned short* p) {
    union { uint4 u; half8 h; } x;
    x.u = *(const uint4*)p;
    return x.h;
}

// ---------------------------------------------------------------------------
// Fused OpenBLAS-mimicking fp32 GEMM for Qs AND Ks (unchanged).
// ---------------------------------------------------------------------------
__global__ __launch_bounds__(256)
void gemm_qk2_blas(const float* __restrict__ A,
                   const float* __restrict__ Wq,
                   const float* __restrict__ Wk,
                   const float* __restrict__ bq,
                   const float* __restrict__ bk_,
                   float* __restrict__ Cq,
                   float* __restrict__ Ck,
                   unsigned short* __restrict__ khi,
                   int K, int N)
{
    __shared__ __align__(16) float As[16][68];
    __shared__ __align__(16) float Bq[16][68];
    __shared__ __align__(16) float Bk[16][68];
    const int t  = threadIdx.x;
    const int r0 = blockIdx.y * 64;
    const int c0 = blockIdx.x * 64;
    const int tm = t >> 4, tn = t & 15;
    float paccQ[4][4] = {};
    float caccQ[4][4] = {};
    float paccK[4][4] = {};
    float caccK[4][4] = {};

    const int ar = t >> 2, ak = (t & 3) * 4;
    const int bk = t >> 4, bc = (t & 15) * 4;

    for (int k0 = 0; k0 < K; k0 += 16) {
        const float4 av  = *(const float4*)(A  + (size_t)(r0 + ar) * K + (k0 + ak));
        const float4 bqv = *(const float4*)(Wq + (size_t)(k0 + bk) * N + (c0 + bc));
        const float4 bkv = *(const float4*)(Wk + (size_t)(k0 + bk) * N + (c0 + bc));
        As[ak + 0][ar] = av.x;
        As[ak + 1][ar] = av.y;
        As[ak + 2][ar] = av.z;
        As[ak + 3][ar] = av.w;
        *(float4*)&Bq[bk][bc] = bqv;
        *(float4*)&Bk[bk][bc] = bkv;
        __syncthreads();
        #pragma unroll
        for (int kk = 0; kk < 16; ++kk) {
            const float4 a4  = *(const float4*)&As[kk][tm * 4];
            const float4 q4  = *(const float4*)&Bq[kk][tn * 4];
            const float4 k4  = *(const float4*)&Bk[kk][tn * 4];
            const float a[4]  = {a4.x, a4.y, a4.z, a4.w};
            const float bqr[4] = {q4.x, q4.y, q4.z, q4.w};
            const float bkr[4] = {k4.x, k4.y, k4.z, k4.w};
            #pragma unroll
            for (int i = 0; i < 4; ++i)
                #pragma unroll
                for (int j = 0; j < 4; ++j) {
                    paccQ[i][j] = fmaf(a[i], bqr[j], paccQ[i][j]);
                    paccK[i][j] = fmaf(a[i], bkr[j], paccK[i][j]);
                }
        }
        __syncthreads();
        const int kn = k0 + 16;
        if (kn == 384 || kn == 768 || kn == K) {   // OpenBLAS KC=384 panel flush
            #pragma unroll
            for (int i = 0; i < 4; ++i)
                #pragma unroll
                for (int j = 0; j < 4; ++j) {
                    caccQ[i][j] = caccQ[i][j] + paccQ[i][j];
                    paccQ[i][j] = 0.f;
                    caccK[i][j] = caccK[i][j] + paccK[i][j];
                    paccK[i][j] = 0.f;
                }
        }
    }
    #pragma unroll
    for (int i = 0; i < 4; ++i) {
        const int r = r0 + tm * 4 + i;
        const int c = c0 + tn * 4;
        float4 vq;
        vq.x = caccQ[i][0] + bq[c + 0];
        vq.y = caccQ[i][1] + bq[c + 1];
        vq.z = caccQ[i][2] + bq[c + 2];
        vq.w = caccQ[i][3] + bq[c + 3];
        *(float4*)&Cq[(size_t)r * N + c] = vq;
        float4 vk;
        vk.x = caccK[i][0] + bk_[c + 0];
        vk.y = caccK[i][1] + bk_[c + 1];
        vk.z = caccK[i][2] + bk_[c + 2];
        vk.w = caccK[i][3] + bk_[c + 3];
        *(float4*)&Ck[(size_t)r * N + c] = vk;
        ushort4 hs;
        hs.x = h2u((_Float16)vk.x);
        hs.y = h2u((_Float16)vk.y);
        hs.z = h2u((_Float16)vk.z);
        hs.w = h2u((_Float16)vk.w);
        *(ushort4*)&khi[(size_t)r * N + c] = hs;
    }
}

// ---------------------------------------------------------------------------
// Weight prep for hi/lo MFMA GEMM: W (K x N, fp32) -> WT hi/lo (N x K, f16).
// ---------------------------------------------------------------------------
__global__ __launch_bounds__(256)
void conv_wT(const float* __restrict__ W,
             unsigned short* __restrict__ wthi,
             unsigned short* __restrict__ wtlo)
{
    __shared__ float tile[64][68];
    const int t  = threadIdx.x;
    const int k0 = blockIdx.y * 64;
    const int n0 = blockIdx.x * 64;
    const int r  = t >> 4, c4 = (t & 15) * 4;
    #pragma unroll
    for (int i = 0; i < 4; ++i) {
        const int k = r + 16 * i;
        const float4 v = *(const float4*)&W[(size_t)(k0 + k) * cE + n0 + c4];
        tile[k][c4 + 0] = v.x; tile[k][c4 + 1] = v.y;
        tile[k][c4 + 2] = v.z; tile[k][c4 + 3] = v.w;
    }
    __syncthreads();
    #pragma unroll
    for (int i = 0; i < 4; ++i) {
        const int n = r + 16 * i;
        unsigned int hp[2], lp[2];
        #pragma unroll
        for (int p = 0; p < 2; ++p) {
            unsigned short hh[2], ll[2];
            #pragma unroll
            for (int j = 0; j < 2; ++j) {
                const float f = tile[c4 + p * 2 + j][n];
                const _Float16 h = (_Float16)f;
                hh[j] = h2u(h);
                ll[j] = h2u((_Float16)(f - (float)h));
            }
            hp[p] = (unsigned int)hh[0] | ((unsigned int)hh[1] << 16);
            lp[p] = (unsigned int)ll[0] | ((unsigned int)ll[1] << 16);
        }
        uint2 hv, lv;
        hv.x = hp[0]; hv.y = hp[1];
        lv.x = lp[0]; lv.y = lp[1];
        *(uint2*)&wthi[(size_t)(n0 + n) * cE + k0 + c4] = hv;
        *(uint2*)&wtlo[(size_t)(n0 + n) * cE + k0 + c4] = lv;
    }
}

// ---------------------------------------------------------------------------
// f16 hi/lo 3-product MFMA GEMM (unchanged).
// ---------------------------------------------------------------------------
__global__ __launch_bounds__(256)
void gemm_hilo(const float* __restrict__ A,
               const unsigned short* __restrict__ wthi,
               const unsigned short* __restrict__ wtlo,
               const float* __restrict__ bias,
               float* __restrict__ C)
{
    __shared__ __align__(16) unsigned short Ah[128][24];   // 24 = 16 + 8 pad
    __shared__ __align__(16) unsigned short Al[128][24];
    __shared__ __align__(16) unsigned short Bh[64][24];
    __shared__ __align__(16) unsigned short Bl[64][24];

    const int t    = threadIdx.x;
    const int lane = t & 63, wave = t >> 6;
    const int wr   = wave >> 1, wc = wave & 1;
    const int r0   = blockIdx.y * 128, c0 = blockIdx.x * 64;
    const int fr   = lane & 31, g5 = lane >> 5;

    const int arow = t >> 1, aka = (t & 1) * 8;
    const int bsel = t >> 7;                 // waves 0,1: hi; waves 2,3: lo
    const int brow = (t & 127) >> 1, bkb = (t & 1) * 8;
    const unsigned short* wsrc = bsel ? wtlo : wthi;

    f32x16 acc0 = {0.f,0.f,0.f,0.f,0.f,0.f,0.f,0.f,0.f,0.f,0.f,0.f,0.f,0.f,0.f,0.f};
    f32x16 acc1 = {0.f,0.f,0.f,0.f,0.f,0.f,0.f,0.f,0.f,0.f,0.f,0.f,0.f,0.f,0.f,0.f};

    for (int k0 = 0; k0 < cE; k0 += 16) {
        const float4 x0 = *(const float4*)&A[(size_t)(r0 + arow) * cE + k0 + aka];
        const float4 x1 = *(const float4*)&A[(size_t)(r0 + arow) * cE + k0 + aka + 4];
        const float xf[8] = {x0.x, x0.y, x0.z, x0.w, x1.x, x1.y, x1.z, x1.w};
        unsigned int hw[4], lw[4];
        #pragma unroll
        for (int p = 0; p < 4; ++p) {
            unsigned short hh[2], ll[2];
            #pragma unroll
            for (int j = 0; j < 2; ++j) {
                const float f = xf[p * 2 + j];
                const _Float16 h = (_Float16)f;
                hh[j] = h2u(h);
                ll[j] = h2u((_Float16)(f - (float)h));
            }
            hw[p] = (unsigned int)hh[0] | ((unsigned int)hh[1] << 16);
            lw[p] = (unsigned int)ll[0] | ((unsigned int)ll[1] << 16);
        }
        uint4 hv, lv;
        hv.x = hw[0]; hv.y = hw[1]; hv.z = hw[2]; hv.w = hw[3];
        lv.x = lw[0]; lv.y = lw[1]; lv.z = lw[2]; lv.w = lw[3];
        *(uint4*)&Ah[arow][aka] = hv;
        *(uint4*)&Al[arow][aka] = lv;

        const uint4 wv = *(const uint4*)&wsrc[(size_t)(c0 + brow) * cE + k0 + bkb];
        if (bsel) *(uint4*)&Bl[brow][bkb] = wv;
        else      *(uint4*)&Bh[brow][bkb] = wv;
        __syncthreads();

        const half8 a0h = ld_half8(&Ah[wr * 64 + fr][g5 * 8]);
        const half8 a0l = ld_half8(&Al[wr * 64 + fr][g5 * 8]);
        const half8 a1h = ld_half8(&Ah[wr * 64 + 32 + fr][g5 * 8]);
        const half8 a1l = ld_half8(&Al[wr * 64 + 32 + fr][g5 * 8]);
        const half8 bh  = ld_half8(&Bh[wc * 32 + fr][g5 * 8]);
        const half8 bl  = ld_half8(&Bl[wc * 32 + fr][g5 * 8]);

        acc0 = __builtin_amdgcn_mfma_f32_32x32x16_f16(a0l, bh, acc0, 0, 0, 0);
        acc0 = __builtin_amdgcn_mfma_f32_32x32x16_f16(a0h, bl, acc0, 0, 0, 0);
        acc0 = __builtin_amdgcn_mfma_f32_32x32x16_f16(a0h, bh, acc0, 0, 0, 0);
        acc1 = __builtin_amdgcn_mfma_f32_32x32x16_f16(a1l, bh, acc1, 0, 0, 0);
        acc1 = __builtin_amdgcn_mfma_f32_32x32x16_f16(a1h, bl, acc1, 0, 0, 0);
        acc1 = __builtin_amdgcn_mfma_f32_32x32x16_f16(a1h, bh, acc1, 0, 0, 0);
        __syncthreads();
    }

    const int col = c0 + wc * 32 + fr;
    const float bv = bias ? bias[col] : 0.f;
    #pragma unroll
    for (int rg = 0; rg < 16; ++rg) {
        const int row = r0 + wr * 64 + (rg & 3) + 8 * (rg >> 2) + 4 * g5;
        C[(size_t)row * cE + col] = acc0[rg] + bv;
    }
    #pragma unroll
    for (int rg = 0; rg < 16; ++rg) {
        const int row = r0 + wr * 64 + 32 + (rg & 3) + 8 * (rg >> 2) + 4 * g5;
        C[(size_t)row * cE + col] = acc1[rg] + bv;
    }
}

// ---------------------------------------------------------------------------
// Fused output GEMM, hi/lo MFMA (unchanged).
// ---------------------------------------------------------------------------
__global__ __launch_bounds__(256)
void out_gemm_hilo(const float* __restrict__ As_, const float* __restrict__ Ap_,
                   const unsigned short* __restrict__ w1hi,
                   const unsigned short* __restrict__ w1lo,
                   const unsigned short* __restrict__ w2hi,
                   const unsigned short* __restrict__ w2lo,
                   const float* __restrict__ bos, const float* __restrict__ bop,
                   const float* __restrict__ gates, float* __restrict__ out)
{
    __shared__ __align__(16) unsigned short A1h[128][24], A1l[128][24];
    __shared__ __align__(16) unsigned short A2h[128][24], A2l[128][24];
    __shared__ __align__(16) unsigned short B1h[64][24],  B1l[64][24];
    __shared__ __align__(16) unsigned short B2h[64][24],  B2l[64][24];

    const int t    = threadIdx.x;
    const int lane = t & 63, wave = t >> 6;
    const int wr   = wave >> 1, wc = wave & 1;
    const int r0   = blockIdx.y * 128, c0 = blockIdx.x * 64;
    const int fr   = lane & 31, g5 = lane >> 5;
    const int b    = r0 >> 11;
    const float gs = gates[b * 2 + 0], gp = gates[b * 2 + 1];

    const int arow = t >> 1, aka = (t & 1) * 8;
    const int bsel = t >> 7;
    const int brow = (t & 127) >> 1, bkb = (t & 1) * 8;
    const unsigned short* s1 = bsel ? w1lo : w1hi;
    const unsigned short* s2 = bsel ? w2lo : w2hi;

    f32x16 acc0 = {0.f,0.f,0.f,0.f,0.f,0.f,0.f,0.f,0.f,0.f,0.f,0.f,0.f,0.f,0.f,0.f};
    f32x16 acc1 = {0.f,0.f,0.f,0.f,0.f,0.f,0.f,0.f,0.f,0.f,0.f,0.f,0.f,0.f,0.f,0.f};

    for (int k0 = 0; k0 < cE; k0 += 16) {
        {
            const float4 x0 = *(const float4*)&As_[(size_t)(r0 + arow) * cE + k0 + aka];
            const float4 x1 = *(const float4*)&As_[(size_t)(r0 + arow) * cE + k0 + aka + 4];
            const float xf[8] = {x0.x * gs, x0.y * gs, x0.z * gs, x0.w * gs,
                                 x1.x * gs, x1.y * gs, x1.z * gs, x1.w * gs};
            unsigned int hw[4], lw[4];
            #pragma unroll
            for (int p = 0; p < 4; ++p) {
                unsigned short hh[2], ll[2];
                #pragma unroll
                for (int j = 0; j < 2; ++j) {
                    const float f = xf[p * 2 + j];
                    const _Float16 h = (_Float16)f;
                    hh[j] = h2u(h);
                    ll[j] = h2u((_Float16)(f - (float)h));
                }
                hw[p] = (unsigned int)hh[0] | ((unsigned int)hh[1] << 16);
                lw[p] = (unsigned int)ll[0] | ((unsigned int)ll[1] << 16);
            }
            uint4 hv, lv;
            hv.x = hw[0]; hv.y = hw[1]; hv.z = hw[2]; hv.w = hw[3];
            lv.x = lw[0]; lv.y = lw[1]; lv.z = lw[2]; lv.w = lw[3];
            *(uint4*)&A1h[arow][aka] = hv;
            *(uint4*)&A1l[arow][aka] = lv;
        }
        {
            const float4 x0 = *(const float4*)&Ap_[(size_t)(r0 + arow) * cE + k0 + aka];
            const float4 x1 = *(const float4*)&Ap_[(size_t)(r0 + arow) * cE + k0 + aka + 4];
            const float xf[8] = {x0.x * gp, x0.y * gp, x0.z * gp, x0.w * gp,
                                 x1.x * gp, x1.y * gp, x1.z * gp, x1.w * gp};
            unsigned int hw[4], lw[4];
            #pragma unroll
            for (int p = 0; p < 4; ++p) {
                unsigned short hh[2], ll[2];
                #pragma unroll
                for (int j = 0; j < 2; ++j) {
                    const float f = xf[p * 2 + j];
                    const _Float16 h = (_Float16)f;
                    hh[j] = h2u(h);
                    ll[j] = h2u((_Float16)(f - (float)h));
                }
                hw[p] = (unsigned int)hh[0] | ((unsigned int)hh[1] << 16);
                lw[p] = (unsigned int)ll[0] | ((unsigned int)ll[1] << 16);
            }
            uint4 hv, lv;
            hv.x = hw[0]; hv.y = hw[1]; hv.z = hw[2]; hv.w = hw[3];
            lv.x = lw[0]; lv.y = lw[1]; lv.z = lw[2]; lv.w = lw[3];
            *(uint4*)&A2h[arow][aka] = hv;
            *(uint4*)&A2l[arow][aka] = lv;
        }
        {
            const uint4 w1 = *(const uint4*)&s1[(size_t)(c0 + brow) * cE + k0 + bkb];
            if (bsel) *(uint4*)&B1l[brow][bkb] = w1;
            else      *(uint4*)&B1h[brow][bkb] = w1;
            const uint4 w2 = *(const uint4*)&s2[(size_t)(c0 + brow) * cE + k0 + bkb];
            if (bsel) *(uint4*)&B2l[brow][bkb] = w2;
            else      *(uint4*)&B2h[brow][bkb] = w2;
        }
        __syncthreads();

        const half8 b1h = ld_half8(&B1h[wc * 32 + fr][g5 * 8]);
        const half8 b1l = ld_half8(&B1l[wc * 32 + fr][g5 * 8]);
        const half8 b2h = ld_half8(&B2h[wc * 32 + fr][g5 * 8]);
        const half8 b2l = ld_half8(&B2l[wc * 32 + fr][g5 * 8]);
        {
            const half8 a1h = ld_half8(&A1h[wr * 64 + fr][g5 * 8]);
            const half8 a1l = ld_half8(&A1l[wr * 64 + fr][g5 * 8]);
            const half8 a2h = ld_half8(&A2h[wr * 64 + fr][g5 * 8]);
            const half8 a2l = ld_half8(&A2l[wr * 64 + fr][g5 * 8]);
            acc0 = __builtin_amdgcn_mfma_f32_32x32x16_f16(a1l, b1h, acc0, 0, 0, 0);
            acc0 = __builtin_amdgcn_mfma_f32_32x32x16_f16(a1h, b1l, acc0, 0, 0, 0);
            acc0 = __builtin_amdgcn_mfma_f32_32x32x16_f16(a1h, b1h, acc0, 0, 0, 0);
            acc0 = __builtin_amdgcn_mfma_f32_32x32x16_f16(a2l, b2h, acc0, 0, 0, 0);
            acc0 = __builtin_amdgcn_mfma_f32_32x32x16_f16(a2h, b2l, acc0, 0, 0, 0);
            acc0 = __builtin_amdgcn_mfma_f32_32x32x16_f16(a2h, b2h, acc0, 0, 0, 0);
        }
        {
            const half8 a1h = ld_half8(&A1h[wr * 64 + 32 + fr][g5 * 8]);
            const half8 a1l = ld_half8(&A1l[wr * 64 + 32 + fr][g5 * 8]);
            const half8 a2h = ld_half8(&A2h[wr * 64 + 32 + fr][g5 * 8]);
            const half8 a2l = ld_half8(&A2l[wr * 64 + 32 + fr][g5 * 8]);
            acc1 = __builtin_amdgcn_mfma_f32_32x32x16_f16(a1l, b1h, acc1, 0, 0, 0);
            acc1 = __builtin_amdgcn_mfma_f32_32x32x16_f16(a1h, b1l, acc1, 0, 0, 0);
            acc1 = __builtin_amdgcn_mfma_f32_32x32x16_f16(a1h, b1h, acc1, 0, 0, 0);
            acc1 = __builtin_amdgcn_mfma_f32_32x32x16_f16(a2l, b2h, acc1, 0, 0, 0);
            acc1 = __builtin_amdgcn_mfma_f32_32x32x16_f16(a2h, b2l, acc1, 0, 0, 0);
            acc1 = __builtin_amdgcn_mfma_f32_32x32x16_f16(a2h, b2h, acc1, 0, 0, 0);
        }
        __syncthreads();
    }

    const int col = c0 + wc * 32 + fr;
    const float bv = gs * bos[col] + gp * bop[col];
    #pragma unroll
    for (int rg = 0; rg < 16; ++rg) {
        const int row = r0 + wr * 64 + (rg & 3) + 8 * (rg >> 2) + 4 * g5;
        out[(size_t)row * cE + col] = acc0[rg] + bv;
    }
    #pragma unroll
    for (int rg = 0; rg < 16; ++rg) {
        const int row = r0 + wr * 64 + 32 + (rg & 3) + 8 * (rg >> 2) + 4 * g5;
        out[(size_t)row * cE + col] = acc1[rg] + bv;
    }
}

// ---------------------------------------------------------------------------
// Sparse selection, QBLK=16, 512 threads (8 waves x 8 tiles): su[8][4]=32
// VGPRs per thread -> no scratch spill. Same MFMA total, same per-row
// selection math and gcidx layout as round 20.
// ---------------------------------------------------------------------------
__global__ __launch_bounds__(512, 4)
void sparse_sel(const float* __restrict__ Q,
                const unsigned short* __restrict__ Khi,
                unsigned short* __restrict__ gcidx,
                int* __restrict__ gcnt)
{
    __shared__ __align__(16) unsigned short Qhi[16][72];  // 2.25 KB
    __shared__ unsigned int hist[16][257];                // 16.4 KB
    __shared__ int cnt[16];
    __shared__ int t16hi[16], rem[16], t16[16];

    const int t   = threadIdx.x;
    const int bh  = blockIdx.y;
    const int b   = bh >> 4;
    const int h64 = (bh & 15) * 64;
    const int q0  = blockIdx.x * 16;
    const size_t rid0 = (size_t)bh * 2048 + q0;           // linear row id base

    if (t < 256) {
        const int r = t >> 4, c4 = (t & 15) * 4;
        const float4 v =
            *(const float4*)&Q[((size_t)(b * cS + q0 + r)) * cE + h64 + c4];
        const float f[4] = {v.x, v.y, v.z, v.w};
        #pragma unroll
        for (int i = 0; i < 4; ++i)
            Qhi[r][c4 + i] = h2u((_Float16)f[i]);
    }
    for (int i = t; i < 16 * 257; i += 512) (&hist[0][0])[i] = 0u;
    if (t < 16) cnt[t] = 0;
    __syncthreads();                                               // B1

    const int lane = t & 63;
    const int wv   = t >> 6;            // 0..7, each wave covers 256 keys
    const int col  = lane & 31;
    const int g5   = lane >> 5;
    const int base0 = 4 * g5;           // rows from acc regs 0..3
    const int base1 = 8 + 4 * g5;       // rows from acc regs 4..7

    // ---- phase A: single-product f16 MFMA scores, keys wv*256 .. +256 ----
    half8 ahi[4];
    {
        const int arow = col & 15;      // 16 valid Q rows (dup x2 over 32)
        #pragma unroll
        for (int ks = 0; ks < 4; ++ks)
            ahi[ks] = ld_half8(&Qhi[arow][g5 * 8 + ks * 16]);
    }
    unsigned int su[8][4];              // u16 keys, 8 rows x 8 tiles
    {
        const size_t kbase = ((size_t)(b * cS + wv * 256 + col)) * cE + h64;
        #pragma unroll
        for (int tl = 0; tl < 8; ++tl) {
            const unsigned short* kh = Khi + kbase + (size_t)tl * 32 * cE;
            f32x16 acc = {0.f,0.f,0.f,0.f,0.f,0.f,0.f,0.f,
                          0.f,0.f,0.f,0.f,0.f,0.f,0.f,0.f};
            #pragma unroll
            for (int ks = 0; ks < 4; ++ks) {
                const half8 bh8 = ld_half8(kh + g5 * 8 + ks * 16);
                acc = __builtin_amdgcn_mfma_f32_32x32x16_f16(ahi[ks], bh8, acc, 0, 0, 0);
            }
            unsigned int k[8];
            #pragma unroll
            for (int r = 0; r < 8; ++r)
                k[r] = f2key(acc[r] * 0.125f) >> 16;
            su[tl][0] = k[0] | (k[1] << 16);
            su[tl][1] = k[2] | (k[3] << 16);
            su[tl][2] = k[4] | (k[5] << 16);
            su[tl][3] = k[6] | (k[7] << 16);
            atomicAdd(&hist[base0 + 0][k[0] >> 8], 1u);
            atomicAdd(&hist[base0 + 1][k[1] >> 8], 1u);
            atomicAdd(&hist[base0 + 2][k[2] >> 8], 1u);
            atomicAdd(&hist[base0 + 3][k[3] >> 8], 1u);
            atomicAdd(&hist[base1 + 0][k[4] >> 8], 1u);
            atomicAdd(&hist[base1 + 1][k[5] >> 8], 1u);
            atomicAdd(&hist[base1 + 2][k[6] >> 8], 1u);
            atomicAdd(&hist[base1 + 3][k[7] >> 8], 1u);
        }
    }
    __syncthreads();                                               // B2
    if (t < 16) {
        int need = cKTOP + 1;   // 65
        int hb = 0;
        for (int bin = 255; bin >= 0; --bin) {
            const int c = (int)hist[t][bin];
            if (c >= need) { hb = bin; break; }
            need -= c;
        }
        t16hi[t] = hb;
        rem[t] = need;
    }
    __syncthreads();                                               // B3
    for (int i = t; i < 16 * 257; i += 512) (&hist[0][0])[i] = 0u;  // pass 2
    __syncthreads();                                               // B3b
    #pragma unroll
    for (int tl = 0; tl < 8; ++tl)
        #pragma unroll
        for (int w = 0; w < 4; ++w) {
            const unsigned int u = su[tl][w];
            const int rlo = (w < 2 ? base0 : base1) + (w & 1) * 2;
            const int rhi = rlo + 1;
            const unsigned int vlo = u & 0xFFFFu;
            const unsigned int vhi = u >> 16;
            if ((int)(vlo >> 8) == t16hi[rlo]) atomicAdd(&hist[rlo][vlo & 255u], 1u);
            if ((int)(vhi >> 8) == t16hi[rhi]) atomicAdd(&hist[rhi][vhi & 255u], 1u);
        }
    __syncthreads();                                               // B4
    if (t < 16) {
        int need = rem[t];
        int lb = 0;
        for (int bin = 255; bin >= 0; --bin) {
            const int c = (int)hist[t][bin];
            if (c >= need) { lb = bin; break; }
            need -= c;
        }
        t16[t] = (t16hi[t] << 8) | lb;
    }
    __syncthreads();                                               // B5

    // ---- candidate scan: u16 >= T16 - 3; write straight to global ----
    #pragma unroll
    for (int tl = 0; tl < 8; ++tl) {
        const int key = wv * 256 + tl * 32 + col;
        #pragma unroll
        for (int w = 0; w < 4; ++w) {
            const unsigned int u = su[tl][w];
            const int rlo = (w < 2 ? base0 : base1) + (w & 1) * 2;
            const int rhi = rlo + 1;
            const int v0 = (int)(u & 0xFFFFu);
            const int v1 = (int)(u >> 16);
            if (v0 >= max(t16[rlo] - 3, 0)) {
                const int slot = atomicAdd(&cnt[rlo], 1);
                if (slot < 128) gcidx[(rid0 + rlo) * 128 + slot] = (unsigned short)key;
            }
            if (v1 >= max(t16[rhi] - 3, 0)) {
                const int slot = atomicAdd(&cnt[rhi], 1);
                if (slot < 128) gcidx[(rid0 + rhi) * 128 + slot] = (unsigned short)key;
            }
        }
    }
    __syncthreads();                                               // B6
    if (t < 16) gcnt[rid0 + t] = cnt[t];
}

// ---------------------------------------------------------------------------
// Sparse attention (phases C/D, unchanged): fp64 recompute, ranking, hedge
// weights, unroll-8 PV gather. __launch_bounds__(256,8).
// ---------------------------------------------------------------------------
__global__ __launch_bounds__(256, 8)
void sparse_att(const float* __restrict__ Q,
                const unsigned short* __restrict__ gcidx,
                const int* __restrict__ gcnt,
                const float* __restrict__ Ks, const float* __restrict__ V,
                float* __restrict__ O)
{
    __shared__ float QfT[64][8];                 // 2 KB  (Q transposed)
    __shared__ unsigned short cidx[8][128];      // 2 KB
    __shared__ double cval[8][128];              // 8 KB
    __shared__ float cw[8][128];                 // 4 KB
    __shared__ int cnt[8];
    __shared__ double T64s[8], s65s[8], rowm[8];

    const int t   = threadIdx.x;
    const int bh  = blockIdx.y;
    const int b   = bh >> 4;
    const int h64 = (bh & 15) * 64;
    const int q0  = blockIdx.x * 8;
    const size_t rid0 = ((size_t)bh * 256 + blockIdx.x) * 8;

    if (t < 128) {
        const int r = t >> 4, c4 = (t & 15) * 4;
        const float4 v =
            *(const float4*)&Q[((size_t)(b * cS + q0 + r)) * cE + h64 + c4];
        QfT[c4 + 0][r] = v.x; QfT[c4 + 1][r] = v.y;
        QfT[c4 + 2][r] = v.z; QfT[c4 + 3][r] = v.w;
    }
    // 8 rows x 128 u16 are contiguous in gcidx -> one ushort4 per thread
    ((ushort4*)&cidx[0][0])[t] = ((const ushort4*)&gcidx[rid0 * 128])[t];
    if (t < 8) cnt[t] = gcnt[rid0 + t];
    __syncthreads();                                               // B6'

    const int wv = t >> 6, lane = t & 63;

    // ---- phase C: fp64 recompute, lane = candidate (2 rows per wave) ----
    #pragma unroll
    for (int rx = 0; rx < 2; ++rx) {
        const int rr = wv * 2 + rx;
        const int n = min(cnt[rr], 128);
        for (int c = lane; c < n; c += 64) {
            const int key = cidx[rr][c];
            const float* kp = Ks + ((size_t)(b * cS + key)) * cE + h64;
            double a = 0.0;
            #pragma unroll 4
            for (int d4 = 0; d4 < 64; d4 += 4) {
                const float4 kv = *(const float4*)&kp[d4];
                a = fma((double)QfT[d4 + 0][rr], (double)kv.x, a);
                a = fma((double)QfT[d4 + 1][rr], (double)kv.y, a);
                a = fma((double)QfT[d4 + 2][rr], (double)kv.z, a);
                a = fma((double)QfT[d4 + 3][rr], (double)kv.w, a);
            }
            cval[rr][c] = a * 0.125;
        }
    }
    __syncthreads();                                               // B7

    // ---- ranking: T64 (rank 63), s65 (rank 64), m (rank 0) ----
    #pragma unroll
    for (int rx = 0; rx < 2; ++rx) {
        const int rr = wv * 2 + rx;
        const int n = min(cnt[rr], 128);
        for (int c = lane; c < n; c += 64) {
            const double v = cval[rr][c];
            int rank = 0;
            for (int i = 0; i < n; ++i) rank += (cval[rr][i] > v) ? 1 : 0;
            if (rank == 0)  rowm[rr] = v;
            if (rank == 63) T64s[rr] = v;
            if (rank == 64) s65s[rr] = v;
        }
    }
    __syncthreads();                                               // B8

    // ---- weights: hedge formula (unchanged) ----
    #pragma unroll
    for (int rx = 0; rx < 2; ++rx) {
        const int rr = wv * 2 + rx;
        const int n = min(cnt[rr], 128);
        const double T64 = T64s[rr], s65 = s65s[rr], m = rowm[rr];
        float za = 0.f;
        for (int c = lane; c < n; c += 64) {
            const double v = cval[rr][c];
            if (v >= T64) za += expf((float)(v - m));
        }
        #pragma unroll
        for (int off = 32; off >= 1; off >>= 1)
            za += __shfl_xor(za, off);
        const float g   = (float)(T64 - s65);
        const float gm  = fmaxf(g - 5e-7f, 0.f);
        const float wB  = 0.5f * erfcf(gm * (1.0f / 2.2e-6f));
        const float wA  = 1.f - wB;
        const float e64 = expf((float)(T64 - m));
        const float e65 = expf((float)(s65 - m));
        const float ZB  = za - e64 + e65;
        const float cIn = wA / za + wB / ZB;
        const float c64 = wA / za;
        const float c65 = wB / ZB;
        for (int c = lane; c < n; c += 64) {
            const double v = cval[rr][c];
            float cc = 0.f;
            if (v > T64)       cc = cIn;
            else if (v == T64) cc = c64;
            else if (v == s65) cc = c65;
            cw[rr][c] = (cc != 0.f) ? cc * expf((float)(v - m)) : 0.f;
        }
    }
    __syncthreads();                                               // B9

    // ---- phase D: sparse PV gather, unroll-8 pipelined (same sum order) ----
    #pragma unroll
    for (int rx = 0; rx < 2; ++rx) {
        const int rr = wv * 2 + rx;
        const int n = min(cnt[rr], 128);
        float o = 0.f;
        int j = 0;
        for (; j + 8 <= n; j += 8) {
            float wreg[8];
            int   kreg[8];
            #pragma unroll
            for (int u = 0; u < 8; ++u) {
                wreg[u] = cw[rr][j + u];
                kreg[u] = cidx[rr][j + u];
            }
            float vreg[8];
            #pragma unroll
            for (int u = 0; u < 8; ++u)
                vreg[u] = V[((size_t)(b * cS + kreg[u])) * cE + h64 + lane];
            #pragma unroll
            for (int u = 0; u < 8; ++u)
                o = fmaf(wreg[u], vreg[u], o);
        }
        for (; j < n; ++j)
            o = fmaf(cw[rr][j],
                     V[((size_t)(b * cS + cidx[rr][j])) * cE + h64 + lane], o);
        O[((size_t)(b * cS + q0 + rr)) * cE + h64 + lane] = o;
    }
}

// ---------------------------------------------------------------------------
// Performer kv (unchanged)
// ---------------------------------------------------------------------------
__global__ __launch_bounds__(256)
void perf_kv(const float* __restrict__ Kp, const float* __restrict__ Vp,
             const float* __restrict__ Wfeat,
             float* __restrict__ kvpart, float* __restrict__ zpart)
{
    __shared__ __align__(16) float Wf[64][68];
    __shared__ __align__(16) float Kt[64][68];
    __shared__ __align__(16) float Vt[64][68];
    __shared__ __align__(16) float Ph[64][68];
    const int t    = threadIdx.x;
    const int mc   = blockIdx.x & 3;
    const int sc   = blockIdx.x >> 2;          // 0 or 1
    const int bh   = blockIdx.y;
    const int b    = bh >> 4;
    const int h64  = (bh & 15) * 64;
    const int m0   = mc * 64;
    const int sbase = sc * 1024;

    #pragma unroll
    for (int i = 0; i < 4; ++i) {
        const int lin = t + 256 * i;
        const int d   = lin >> 4;
        const int m4  = (lin & 15) * 4;
        *(float4*)&Wf[d][m4] = *(const float4*)&Wfeat[d * cM + m0 + m4];
    }

    const int tm = t >> 4, tn = t & 15;
    const int sr = tm * 4;
    const int cn = tn * 4;
    float akv[4][4] = {};
    float az = 0.f;

    for (int st = 0; st < 16; ++st) {
        const int s0g = sbase + st * 64;
        __syncthreads();
        #pragma unroll
        for (int i = 0; i < 4; ++i) {
            const int row = tm + 16 * i;
            const size_t base = ((size_t)(b * cS + s0g + row)) * cE + h64 + cn;
            *(float4*)&Kt[row][cn] = *(const float4*)&Kp[base];
            *(float4*)&Vt[row][cn] = *(const float4*)&Vp[base];
        }
        __syncthreads();
        float4 p0 = {0,0,0,0}, p1 = {0,0,0,0}, p2 = {0,0,0,0}, p3 = {0,0,0,0};
        #pragma unroll 8
        for (int d = 0; d < 64; ++d) {
            const float4 wv = *(const float4*)&Wf[d][cn];
            const float k0 = Kt[sr + 0][d], k1 = Kt[sr + 1][d];
            const float k2 = Kt[sr + 2][d], k3 = Kt[sr + 3][d];
            p0.x = fmaf(k0, wv.x, p0.x); p0.y = fmaf(k0, wv.y, p0.y);
            p0.z = fmaf(k0, wv.z, p0.z); p0.w = fmaf(k0, wv.w, p0.w);
            p1.x = fmaf(k1, wv.x, p1.x); p1.y = fmaf(k1, wv.y, p1.y);
            p1.z = fmaf(k1, wv.z, p1.z); p1.w = fmaf(k1, wv.w, p1.w);
            p2.x = fmaf(k2, wv.x, p2.x); p2.y = fmaf(k2, wv.y, p2.y);
            p2.z = fmaf(k2, wv.z, p2.z); p2.w = fmaf(k2, wv.w, p2.w);
            p3.x = fmaf(k3, wv.x, p3.x); p3.y = fmaf(k3, wv.y, p3.y);
            p3.z = fmaf(k3, wv.z, p3.z); p3.w = fmaf(k3, wv.w, p3.w);
        }
        p0.x = fmaxf(p0.x, 0.f) + cEPS; p0.y = fmaxf(p0.y, 0.f) + cEPS;
        p0.z = fmaxf(p0.z, 0.f) + cEPS; p0.w = fmaxf(p0.w, 0.f) + cEPS;
        p1.x = fmaxf(p1.x, 0.f) + cEPS; p1.y = fmaxf(p1.y, 0.f) + cEPS;
        p1.z = fmaxf(p1.z, 0.f) + cEPS; p1.w = fmaxf(p1.w, 0.f) + cEPS;
        p2.x = fmaxf(p2.x, 0.f) + cEPS; p2.y = fmaxf(p2.y, 0.f) + cEPS;
        p2.z = fmaxf(p2.z, 0.f) + cEPS; p2.w = fmaxf(p2.w, 0.f) + cEPS;
        p3.x = fmaxf(p3.x, 0.f) + cEPS; p3.y = fmaxf(p3.y, 0.f) + cEPS;
        p3.z = fmaxf(p3.z, 0.f) + cEPS; p3.w = fmaxf(p3.w, 0.f) + cEPS;
        *(float4*)&Ph[sr + 0][cn] = p0;
        *(float4*)&Ph[sr + 1][cn] = p1;
        *(float4*)&Ph[sr + 2][cn] = p2;
        *(float4*)&Ph[sr + 3][cn] = p3;
        __syncthreads();
        #pragma unroll 8
        for (int ss = 0; ss < 64; ++ss) {
            const float4 pv = *(const float4*)&Ph[ss][sr];
            const float4 vv = *(const float4*)&Vt[ss][cn];
            akv[0][0] = fmaf(pv.x, vv.x, akv[0][0]); akv[0][1] = fmaf(pv.x, vv.y, akv[0][1]);
            akv[0][2] = fmaf(pv.x, vv.z, akv[0][2]); akv[0][3] = fmaf(pv.x, vv.w, akv[0][3]);
            akv[1][0] = fmaf(pv.y, vv.x, akv[1][0]); akv[1][1] = fmaf(pv.y, vv.y, akv[1][1]);
            akv[1][2] = fmaf(pv.y, vv.z, akv[1][2]); akv[1][3] = fmaf(pv.y, vv.w, akv[1][3]);
            akv[2][0] = fmaf(pv.z, vv.x, akv[2][0]); akv[2][1] = fmaf(pv.z, vv.y, akv[2][1]);
            akv[2][2] = fmaf(pv.z, vv.z, akv[2][2]); akv[2][3] = fmaf(pv.z, vv.w, akv[2][3]);
            akv[3][0] = fmaf(pv.w, vv.x, akv[3][0]); akv[3][1] = fmaf(pv.w, vv.y, akv[3][1]);
            akv[3][2] = fmaf(pv.w, vv.z, akv[3][2]); akv[3][3] = fmaf(pv.w, vv.w, akv[3][3]);
        }
        if (t < 64) {
            float a = 0.f;
            #pragma unroll 8
            for (int ss = 0; ss < 64; ++ss) a += Ph[ss][t];
            az += a;
        }
    }
    const size_t obase = ((size_t)(sc * 32 + bh)) * cM + m0;
    #pragma unroll
    for (int i = 0; i < 4; ++i) {
        float4 v; v.x = akv[i][0]; v.y = akv[i][1]; v.z = akv[i][2]; v.w = akv[i][3];
        *(float4*)&kvpart[(obase + sr + i) * cD + cn] = v;
    }
    if (t < 64) zpart[obase + t] = az;
}

// ---------------------------------------------------------------------------
// Performer num/den (unchanged)
// ---------------------------------------------------------------------------
__global__ __launch_bounds__(256)
void perf_numden(const float* __restrict__ Qp, const float* __restrict__ Wfeat,
                 const float* __restrict__ kvpart, const float* __restrict__ zpart,
                 float* __restrict__ Ap)
{
    __shared__ __align__(16) float Wf[64][68];
    __shared__ __align__(16) float Qt[64][68];
    __shared__ __align__(16) float KV[64][68];
    __shared__ __align__(16) float Ph[64][68];
    __shared__ __align__(16) float zl[64];
    __shared__ float den[64];
    const int t   = threadIdx.x;
    const int stb = blockIdx.x;
    const int bh  = blockIdx.y;
    const int b   = bh >> 4;
    const int h64 = (bh & 15) * 64;
    const int s0  = stb * 64;
    const int tm  = t >> 4, tn = t & 15;
    const int sr  = tm * 4, cn = tn * 4;

    #pragma unroll
    for (int i = 0; i < 4; ++i) {
        const int row = tm + 16 * i;
        *(float4*)&Qt[row][cn] =
            *(const float4*)&Qp[((size_t)(b * cS + s0 + row)) * cE + h64 + cn];
    }

    float num[4][4] = {};
    float dacc = 0.f;

    for (int mc = 0; mc < 4; ++mc) {
        const int m0 = mc * 64;
        __syncthreads();
        #pragma unroll
        for (int i = 0; i < 4; ++i) {
            const int lin = t + 256 * i;
            const int d   = lin >> 4;
            const int m4  = (lin & 15) * 4;
            *(float4*)&Wf[d][m4] = *(const float4*)&Wfeat[d * cM + m0 + m4];
        }
        #pragma unroll
        for (int i = 0; i < 4; ++i) {
            const int row = tm + 16 * i;
            const size_t o0 = ((size_t)bh * cM + m0 + row) * cD + cn;
            const size_t o1 = ((size_t)(32 + bh) * cM + m0 + row) * cD + cn;
            const float4 a = *(const float4*)&kvpart[o0];
            const float4 c = *(const float4*)&kvpart[o1];
            float4 v; v.x = a.x + c.x; v.y = a.y + c.y; v.z = a.z + c.z; v.w = a.w + c.w;
            *(float4*)&KV[row][cn] = v;
        }
        if (t < 64)
            zl[t] = zpart[(size_t)bh * cM + m0 + t] + zpart[(size_t)(32 + bh) * cM + m0 + t];
        __syncthreads();
        float4 p0 = {0,0,0,0}, p1 = {0,0,0,0}, p2 = {0,0,0,0}, p3 = {0,0,0,0};
        #pragma unroll 8
        for (int d = 0; d < 64; ++d) {
            const float4 wv = *(const float4*)&Wf[d][cn];
            const float q0 = Qt[sr + 0][d], q1 = Qt[sr + 1][d];
            const float q2 = Qt[sr + 2][d], q3 = Qt[sr + 3][d];
            p0.x = fmaf(q0, wv.x, p0.x); p0.y = fmaf(q0, wv.y, p0.y);
            p0.z = fmaf(q0, wv.z, p0.z); p0.w = fmaf(q0, wv.w, p0.w);
            p1.x = fmaf(q1, wv.x, p1.x); p1.y = fmaf(q1, wv.y, p1.y);
            p1.z = fmaf(q1, wv.z, p1.z); p1.w = fmaf(q1, wv.w, p1.w);
            p2.x = fmaf(q2, wv.x, p2.x); p2.y = fmaf(q2, wv.y, p2.y);
            p2.z = fmaf(q2, wv.z, p2.z); p2.w = fmaf(q2, wv.w, p2.w);
            p3.x = fmaf(q3, wv.x, p3.x); p3.y = fmaf(q3, wv.y, p3.y);
            p3.z = fmaf(q3, wv.z, p3.z); p3.w = fmaf(q3, wv.w, p3.w);
        }
        p0.x = fmaxf(p0.x, 0.f) + cEPS; p0.y = fmaxf(p0.y, 0.f) + cEPS;
        p0.z = fmaxf(p0.z, 0.f) + cEPS; p0.w = fmaxf(p0.w, 0.f) + cEPS;
        p1.x = fmaxf(p1.x, 0.f) + cEPS; p1.y = fmaxf(p1.y, 0.f) + cEPS;
        p1.z = fmaxf(p1.z, 0.f) + cEPS; p1.w = fmaxf(p1.w, 0.f) + cEPS;
        p2.x = fmaxf(p2.x, 0.f) + cEPS; p2.y = fmaxf(p2.y, 0.f) + cEPS;
        p2.z = fmaxf(p2.z, 0.f) + cEPS; p2.w = fmaxf(p2.w, 0.f) + cEPS;
        p3.x = fmaxf(p3.x, 0.f) + cEPS; p3.y = fmaxf(p3.y, 0.f) + cEPS;
        p3.z = fmaxf(p3.z, 0.f) + cEPS; p3.w = fmaxf(p3.w, 0.f) + cEPS;
        *(float4*)&Ph[sr + 0][cn] = p0;
        *(float4*)&Ph[sr + 1][cn] = p1;
        *(float4*)&Ph[sr + 2][cn] = p2;
        *(float4*)&Ph[sr + 3][cn] = p3;
        __syncthreads();
        #pragma unroll 8
        for (int mm = 0; mm < 64; ++mm) {
            const float4 kvv = *(const float4*)&KV[mm][cn];
            const float a0 = Ph[sr + 0][mm], a1 = Ph[sr + 1][mm];
            const float a2 = Ph[sr + 2][mm], a3 = Ph[sr + 3][mm];
            num[0][0] = fmaf(a0, kvv.x, num[0][0]); num[0][1] = fmaf(a0, kvv.y, num[0][1]);
            num[0][2] = fmaf(a0, kvv.z, num[0][2]); num[0][3] = fmaf(a0, kvv.w, num[0][3]);
            num[1][0] = fmaf(a1, kvv.x, num[1][0]); num[1][1] = fmaf(a1, kvv.y, num[1][1]);
            num[1][2] = fmaf(a1, kvv.z, num[1][2]); num[1][3] = fmaf(a1, kvv.w, num[1][3]);
            num[2][0] = fmaf(a2, kvv.x, num[2][0]); num[2][1] = fmaf(a2, kvv.y, num[2][1]);
            num[2][2] = fmaf(a2, kvv.z, num[2][2]); num[2][3] = fmaf(a2, kvv.w, num[2][3]);
            num[3][0] = fmaf(a3, kvv.x, num[3][0]); num[3][1] = fmaf(a3, kvv.y, num[3][1]);
            num[3][2] = fmaf(a3, kvv.z, num[3][2]); num[3][3] = fmaf(a3, kvv.w, num[3][3]);
        }
        if (t < 64) {
            float a = 0.f;
            #pragma unroll
            for (int m4 = 0; m4 < 64; m4 += 4) {
                const float4 ph = *(const float4*)&Ph[t][m4];
                const float4 zz = *(const float4*)&zl[m4];
                a = fmaf(ph.x, zz.x, a); a = fmaf(ph.y, zz.y, a);
                a = fmaf(ph.z, zz.z, a); a = fmaf(ph.w, zz.w, a);
            }
            dacc += a;
        }
    }
    __syncthreads();
    if (t < 64) den[t] = dacc + cEPS;
    __syncthreads();
    #pragma unroll
    for (int i = 0; i < 4; ++i) {
        const float di = 1.f / den[sr + i];
        float4 v;
        v.x = num[i][0] * di; v.y = num[i][1] * di;
        v.z = num[i][2] * di; v.w = num[i][3] * di;
        *(float4*)&Ap[((size_t)(b * cS + s0 + sr + i)) * cE + h64 + cn] = v;
    }
}

// ---------------------------------------------------------------------------
// Gate (unchanged)
// ---------------------------------------------------------------------------
__global__ __launch_bounds__(256)
void gate_avg(const float* __restrict__ x, double* __restrict__ avgpart)
{
    const int i  = blockIdx.x * 256 + threadIdx.x;    // 0..2047: (b,e)
    const int sc = blockIdx.y;                        // 0..15
    const int b  = i >> 10, e = i & 1023;
    double acc = 0.0;
    const int sEnd = sc * 128 + 128;
    for (int s = sc * 128; s < sEnd; ++s)
        acc += (double)x[((size_t)(b * cS + s)) * cE + e];
    avgpart[(size_t)sc * 2048 + i] = acc;
}

__global__ void gate_final(const double* __restrict__ avgpart, const float* __restrict__ Wg,
                           const float* __restrict__ bg, float* __restrict__ gates)
{
    const int t = threadIdx.x;
    const int b = t >> 6, lane = t & 63;
    float l0 = 0.f, l1 = 0.f;
    for (int e = lane; e < cE; e += 64) {
        double s = 0.0;
        #pragma unroll
        for (int sc = 0; sc < 16; ++sc)
            s += avgpart[(size_t)sc * 2048 + b * 1024 + e];
        const float a = (float)(s / (double)cS);
        l0 = fmaf(a, Wg[e * 2 + 0], l0);
        l1 = fmaf(a, Wg[e * 2 + 1], l1);
    }
    for (int off = 32; off >= 1; off >>= 1) {
        l0 += __shfl_down(l0, off);
        l1 += __shfl_down(l1, off);
    }
    if (lane == 0) {
        l0 += bg[0]; l1 += bg[1];
        const float m = fmaxf(l0, l1);
        const float e0 = expf(l0 - m), e1 = expf(l1 - m);
        const float s = e0 + e1;
        gates[b * 2 + 0] = e0 / s;
        gates[b * 2 + 1] = e1 / s;
    }
}

// ---------------------------------------------------------------------------
extern "C" void kernel_launch(void* const* d_in, const int* in_sizes, int n_in,
                              void* d_out, int out_size, void* d_ws, size_t ws_size,
                              hipStream_t stream)
{
    (void)in_sizes; (void)n_in; (void)out_size; (void)ws_size;
    const float* x     = (const float*)d_in[0];
    const float* Wq_s  = (const float*)d_in[1];
    const float* Wk_s  = (const float*)d_in[2];
    const float* Wv_s  = (const float*)d_in[3];
    const float* Wo_s  = (const float*)d_in[4];
    const float* bq_s  = (const float*)d_in[5];
    const float* bk_s  = (const float*)d_in[6];
    const float* bv_s  = (const float*)d_in[7];
    const float* bo_s  = (const float*)d_in[8];
    const float* Wq_p  = (const float*)d_in[9];
    const float* Wk_p  = (const float*)d_in[10];
    const float* Wv_p  = (const float*)d_in[11];
    const float* Wo_p  = (const float*)d_in[12];
    const float* bo_p  = (const float*)d_in[13];
    const float* Wfeat = (const float*)d_in[14];
    const float* Wg    = (const float*)d_in[15];
    const float* bg    = (const float*)d_in[16];

    float* ws = (float*)d_ws;
    const size_t NRE = (size_t)cB * cS * cE;
    float* Qs    = ws;              // later: Qp
    float* Ks    = Qs + NRE;        // later: Kp
    float* KsT   = Ks + NRE;        // sparse: Khi (u16); later: Apout
    float* Vs    = KsT + NRE;       // later: Vp
    float* Asout = Vs + NRE;
    float* kvpart = Asout + NRE;                           // 2*32*256*64
    float* zpart  = kvpart + (size_t)2 * 32 * cM * cD;     // 2*32*256
    double* avgpart = (double*)(zpart + (size_t)2 * 32 * cM);  // 16*2048 doubles
    float* gates = (float*)(avgpart + (size_t)16 * 2048);  // 4
    unsigned short* wthi  = (unsigned short*)(gates + 16); // 1M ushorts (scratch, reused)
    unsigned short* wtlo  = wthi + (size_t)cE * cE;
    unsigned short* wo1hi = wtlo + (size_t)cE * cE;        // Wo_s split (persistent)
    unsigned short* wo1lo = wo1hi + (size_t)cE * cE;
    unsigned short* wo2hi = wo1lo + (size_t)cE * cE;       // Wo_p split (persistent)
    unsigned short* wo2lo = wo2hi + (size_t)cE * cE;
    unsigned short* gcidx = wo2lo + (size_t)cE * cE;       // 65536 rows * 128 u16 = 16 MB
    int* gcnt = (int*)(gcidx + (size_t)65536 * 128);       // 65536 ints

    unsigned short* Khi = (unsigned short*)KsT;            // NRE ushorts (8 MB)

    // ---- output-weight splits (independent of everything else) ----
    conv_wT<<<dim3(16, 16), 256, 0, stream>>>(Wo_s, wo1hi, wo1lo);
    conv_wT<<<dim3(16, 16), 256, 0, stream>>>(Wo_p, wo2hi, wo2lo);

    // ---- sparse branch: fused BLAS-mimic fp32 Q+K (+Khi), MFMA V ----
    gemm_qk2_blas<<<dim3(16, 64), 256, 0, stream>>>(x, Wq_s, Wk_s, bq_s, bk_s,
                                                    Qs, Ks, Khi, cE, cE);
    conv_wT<<<dim3(16, 16), 256, 0, stream>>>(Wv_s, wthi, wtlo);
    gemm_hilo<<<dim3(16, 32), 256, 0, stream>>>(x, wthi, wtlo, bv_s, Vs);
    sparse_sel<<<dim3(128, 32), 512, 0, stream>>>(Qs, Khi, gcidx, gcnt);
    sparse_att<<<dim3(256, 32), 256, 0, stream>>>(Qs, gcidx, gcnt, Ks, Vs, Asout);

    // ---- performer branch (reuses buffers) ----
    float* Qp    = Qs;
    float* Kp    = Ks;
    float* Vp    = Vs;
    float* Apout = KsT;
    conv_wT<<<dim3(16, 16), 256, 0, stream>>>(Wq_p, wthi, wtlo);
    gemm_hilo<<<dim3(16, 32), 256, 0, stream>>>(x, wthi, wtlo, nullptr, Qp);
    conv_wT<<<dim3(16, 16), 256, 0, stream>>>(Wk_p, wthi, wtlo);
    gemm_hilo<<<dim3(16, 32), 256, 0, stream>>>(x, wthi, wtlo, nullptr, Kp);
    conv_wT<<<dim3(16, 16), 256, 0, stream>>>(Wv_p, wthi, wtlo);
    gemm_hilo<<<dim3(16, 32), 256, 0, stream>>>(x, wthi, wtlo, nullptr, Vp);
    perf_kv<<<dim3(8, 32), 256, 0, stream>>>(Kp, Vp, Wfeat, kvpart, zpart);
    perf_numden<<<dim3(32, 32), 256, 0, stream>>>(Qp, Wfeat, kvpart, zpart, Apout);

    // ---- gate + fused MFMA output ----
    gate_avg<<<dim3(8, 16), 256, 0, stream>>>(x, avgpart);
    gate_final<<<dim3(1), 128, 0, stream>>>(avgpart, Wg, bg, gates);
    out_gemm_hilo<<<dim3(16, 32), 256, 0, stream>>>(Asout, Apout,
                                                    wo1hi, wo1lo, wo2hi, wo2lo,
                                                    bo_s, bo_p, gates,
                                                    (float*)d_out);
}

// Round 15
// 1371.673 us; speedup vs baseline: 1.0026x; 1.0026x over previous
//
#include <hip/hip_runtime.h>

// ---------------------------------------------------------------------------
// HybridThoughtAwareAttention  (B=2,S=2048,E=1024,H=16,D=64,K_TOP=64,M=256)
// Round 22: sparse_sel dual-copy histogram. Counters across rounds 19-21
// show an invariant ~330 us + SQ_LDS_BANK_CONFLICT 4.16e7 in the selection
// kernel regardless of spill/threads/QBLK: the 134M same-address LDS atomic
// increments (scores cluster into few hot bins) serialize. Fix: two
// histogram copies indexed by (lane>>4)&1; serial scans sum both copies.
// Same increment multiset => identical thresholds => bit-identical output.
// All else identical to round 21.
// ---------------------------------------------------------------------------

constexpr int cB = 2, cS = 2048, cE = 1024, cH = 16, cD = 64, cKTOP = 64, cM = 256;
constexpr float cEPS = 1e-6f;

typedef _Float16 half8 __attribute__((ext_vector_type(8)));
typedef float f32x16 __attribute__((ext_vector_type(16)));

__device__ __forceinline__ unsigned int f2key(float f) {    // monotone f32->u32
    unsigned int u = __float_as_uint(f);
    return (u & 0x80000000u) ? ~u : (u | 0x80000000u);
}

__device__ __forceinline__ unsigned short h2u(_Float16 h) {
    union { _Float16 h; unsigned short u; } x; x.h = h; return x.u;
}

__device__ __forceinline__ half8 ld_half8(const unsigned short* p) {
    union { uint4 u; half8 h; } x;
    x.u = *(const uint4*)p;
    return x.h;
}

// ---------------------------------------------------------------------------
// Fused OpenBLAS-mimicking fp32 GEMM for Qs AND Ks (unchanged).
// ---------------------------------------------------------------------------
__global__ __launch_bounds__(256)
void gemm_qk2_blas(const float* __restrict__ A,
                   const float* __restrict__ Wq,
                   const float* __restrict__ Wk,
                   const float* __restrict__ bq,
                   const float* __restrict__ bk_,
                   float* __restrict__ Cq,
                   float* __restrict__ Ck,
                   unsigned short* __restrict__ khi,
                   int K, int N)
{
    __shared__ __align__(16) float As[16][68];
    __shared__ __align__(16) float Bq[16][68];
    __shared__ __align__(16) float Bk[16][68];
    const int t  = threadIdx.x;
    const int r0 = blockIdx.y * 64;
    const int c0 = blockIdx.x * 64;
    const int tm = t >> 4, tn = t & 15;
    float paccQ[4][4] = {};
    float caccQ[4][4] = {};
    float paccK[4][4] = {};
    float caccK[4][4] = {};

    const int ar = t >> 2, ak = (t & 3) * 4;
    const int bk = t >> 4, bc = (t & 15) * 4;

    for (int k0 = 0; k0 < K; k0 += 16) {
        const float4 av  = *(const float4*)(A  + (size_t)(r0 + ar) * K + (k0 + ak));
        const float4 bqv = *(const float4*)(Wq + (size_t)(k0 + bk) * N + (c0 + bc));
        const float4 bkv = *(const float4*)(Wk + (size_t)(k0 + bk) * N + (c0 + bc));
        As[ak + 0][ar] = av.x;
        As[ak + 1][ar] = av.y;
        As[ak + 2][ar] = av.z;
        As[ak + 3][ar] = av.w;
        *(float4*)&Bq[bk][bc] = bqv;
        *(float4*)&Bk[bk][bc] = bkv;
        __syncthreads();
        #pragma unroll
        for (int kk = 0; kk < 16; ++kk) {
            const float4 a4  = *(const float4*)&As[kk][tm * 4];
            const float4 q4  = *(const float4*)&Bq[kk][tn * 4];
            const float4 k4  = *(const float4*)&Bk[kk][tn * 4];
            const float a[4]  = {a4.x, a4.y, a4.z, a4.w};
            const float bqr[4] = {q4.x, q4.y, q4.z, q4.w};
            const float bkr[4] = {k4.x, k4.y, k4.z, k4.w};
            #pragma unroll
            for (int i = 0; i < 4; ++i)
                #pragma unroll
                for (int j = 0; j < 4; ++j) {
                    paccQ[i][j] = fmaf(a[i], bqr[j], paccQ[i][j]);
                    paccK[i][j] = fmaf(a[i], bkr[j], paccK[i][j]);
                }
        }
        __syncthreads();
        const int kn = k0 + 16;
        if (kn == 384 || kn == 768 || kn == K) {   // OpenBLAS KC=384 panel flush
            #pragma unroll
            for (int i = 0; i < 4; ++i)
                #pragma unroll
                for (int j = 0; j < 4; ++j) {
                    caccQ[i][j] = caccQ[i][j] + paccQ[i][j];
                    paccQ[i][j] = 0.f;
                    caccK[i][j] = caccK[i][j] + paccK[i][j];
                    paccK[i][j] = 0.f;
                }
        }
    }
    #pragma unroll
    for (int i = 0; i < 4; ++i) {
        const int r = r0 + tm * 4 + i;
        const int c = c0 + tn * 4;
        float4 vq;
        vq.x = caccQ[i][0] + bq[c + 0];
        vq.y = caccQ[i][1] + bq[c + 1];
        vq.z = caccQ[i][2] + bq[c + 2];
        vq.w = caccQ[i][3] + bq[c + 3];
        *(float4*)&Cq[(size_t)r * N + c] = vq;
        float4 vk;
        vk.x = caccK[i][0] + bk_[c + 0];
        vk.y = caccK[i][1] + bk_[c + 1];
        vk.z = caccK[i][2] + bk_[c + 2];
        vk.w = caccK[i][3] + bk_[c + 3];
        *(float4*)&Ck[(size_t)r * N + c] = vk;
        ushort4 hs;
        hs.x = h2u((_Float16)vk.x);
        hs.y = h2u((_Float16)vk.y);
        hs.z = h2u((_Float16)vk.z);
        hs.w = h2u((_Float16)vk.w);
        *(ushort4*)&khi[(size_t)r * N + c] = hs;
    }
}

// ---------------------------------------------------------------------------
// Weight prep for hi/lo MFMA GEMM: W (K x N, fp32) -> WT hi/lo (N x K, f16).
// ---------------------------------------------------------------------------
__global__ __launch_bounds__(256)
void conv_wT(const float* __restrict__ W,
             unsigned short* __restrict__ wthi,
             unsigned short* __restrict__ wtlo)
{
    __shared__ float tile[64][68];
    const int t  = threadIdx.x;
    const int k0 = blockIdx.y * 64;
    const int n0 = blockIdx.x * 64;
    const int r  = t >> 4, c4 = (t & 15) * 4;
    #pragma unroll
    for (int i = 0; i < 4; ++i) {
        const int k = r + 16 * i;
        const float4 v = *(const float4*)&W[(size_t)(k0 + k) * cE + n0 + c4];
        tile[k][c4 + 0] = v.x; tile[k][c4 + 1] = v.y;
        tile[k][c4 + 2] = v.z; tile[k][c4 + 3] = v.w;
    }
    __syncthreads();
    #pragma unroll
    for (int i = 0; i < 4; ++i) {
        const int n = r + 16 * i;
        unsigned int hp[2], lp[2];
        #pragma unroll
        for (int p = 0; p < 2; ++p) {
            unsigned short hh[2], ll[2];
            #pragma unroll
            for (int j = 0; j < 2; ++j) {
                const float f = tile[c4 + p * 2 + j][n];
                const _Float16 h = (_Float16)f;
                hh[j] = h2u(h);
                ll[j] = h2u((_Float16)(f - (float)h));
            }
            hp[p] = (unsigned int)hh[0] | ((unsigned int)hh[1] << 16);
            lp[p] = (unsigned int)ll[0] | ((unsigned int)ll[1] << 16);
        }
        uint2 hv, lv;
        hv.x = hp[0]; hv.y = hp[1];
        lv.x = lp[0]; lv.y = lp[1];
        *(uint2*)&wthi[(size_t)(n0 + n) * cE + k0 + c4] = hv;
        *(uint2*)&wtlo[(size_t)(n0 + n) * cE + k0 + c4] = lv;
    }
}

// ---------------------------------------------------------------------------
// f16 hi/lo 3-product MFMA GEMM (unchanged).
// ---------------------------------------------------------------------------
__global__ __launch_bounds__(256)
void gemm_hilo(const float* __restrict__ A,
               const unsigned short* __restrict__ wthi,
               const unsigned short* __restrict__ wtlo,
               const float* __restrict__ bias,
               float* __restrict__ C)
{
    __shared__ __align__(16) unsigned short Ah[128][24];   // 24 = 16 + 8 pad
    __shared__ __align__(16) unsigned short Al[128][24];
    __shared__ __align__(16) unsigned short Bh[64][24];
    __shared__ __align__(16) unsigned short Bl[64][24];

    const int t    = threadIdx.x;
    const int lane = t & 63, wave = t >> 6;
    const int wr   = wave >> 1, wc = wave & 1;
    const int r0   = blockIdx.y * 128, c0 = blockIdx.x * 64;
    const int fr   = lane & 31, g5 = lane >> 5;

    const int arow = t >> 1, aka = (t & 1) * 8;
    const int bsel = t >> 7;                 // waves 0,1: hi; waves 2,3: lo
    const int brow = (t & 127) >> 1, bkb = (t & 1) * 8;
    const unsigned short* wsrc = bsel ? wtlo : wthi;

    f32x16 acc0 = {0.f,0.f,0.f,0.f,0.f,0.f,0.f,0.f,0.f,0.f,0.f,0.f,0.f,0.f,0.f,0.f};
    f32x16 acc1 = {0.f,0.f,0.f,0.f,0.f,0.f,0.f,0.f,0.f,0.f,0.f,0.f,0.f,0.f,0.f,0.f};

    for (int k0 = 0; k0 < cE; k0 += 16) {
        const float4 x0 = *(const float4*)&A[(size_t)(r0 + arow) * cE + k0 + aka];
        const float4 x1 = *(const float4*)&A[(size_t)(r0 + arow) * cE + k0 + aka + 4];
        const float xf[8] = {x0.x, x0.y, x0.z, x0.w, x1.x, x1.y, x1.z, x1.w};
        unsigned int hw[4], lw[4];
        #pragma unroll
        for (int p = 0; p < 4; ++p) {
            unsigned short hh[2], ll[2];
            #pragma unroll
            for (int j = 0; j < 2; ++j) {
                const float f = xf[p * 2 + j];
                const _Float16 h = (_Float16)f;
                hh[j] = h2u(h);
                ll[j] = h2u((_Float16)(f - (float)h));
            }
            hw[p] = (unsigned int)hh[0] | ((unsigned int)hh[1] << 16);
            lw[p] = (unsigned int)ll[0] | ((unsigned int)ll[1] << 16);
        }
        uint4 hv, lv;
        hv.x = hw[0]; hv.y = hw[1]; hv.z = hw[2]; hv.w = hw[3];
        lv.x = lw[0]; lv.y = lw[1]; lv.z = lw[2]; lv.w = lw[3];
        *(uint4*)&Ah[arow][aka] = hv;
        *(uint4*)&Al[arow][aka] = lv;

        const uint4 wv = *(const uint4*)&wsrc[(size_t)(c0 + brow) * cE + k0 + bkb];
        if (bsel) *(uint4*)&Bl[brow][bkb] = wv;
        else      *(uint4*)&Bh[brow][bkb] = wv;
        __syncthreads();

        const half8 a0h = ld_half8(&Ah[wr * 64 + fr][g5 * 8]);
        const half8 a0l = ld_half8(&Al[wr * 64 + fr][g5 * 8]);
        const half8 a1h = ld_half8(&Ah[wr * 64 + 32 + fr][g5 * 8]);
        const half8 a1l = ld_half8(&Al[wr * 64 + 32 + fr][g5 * 8]);
        const half8 bh  = ld_half8(&Bh[wc * 32 + fr][g5 * 8]);
        const half8 bl  = ld_half8(&Bl[wc * 32 + fr][g5 * 8]);

        acc0 = __builtin_amdgcn_mfma_f32_32x32x16_f16(a0l, bh, acc0, 0, 0, 0);
        acc0 = __builtin_amdgcn_mfma_f32_32x32x16_f16(a0h, bl, acc0, 0, 0, 0);
        acc0 = __builtin_amdgcn_mfma_f32_32x32x16_f16(a0h, bh, acc0, 0, 0, 0);
        acc1 = __builtin_amdgcn_mfma_f32_32x32x16_f16(a1l, bh, acc1, 0, 0, 0);
        acc1 = __builtin_amdgcn_mfma_f32_32x32x16_f16(a1h, bl, acc1, 0, 0, 0);
        acc1 = __builtin_amdgcn_mfma_f32_32x32x16_f16(a1h, bh, acc1, 0, 0, 0);
        __syncthreads();
    }

    const int col = c0 + wc * 32 + fr;
    const float bv = bias ? bias[col] : 0.f;
    #pragma unroll
    for (int rg = 0; rg < 16; ++rg) {
        const int row = r0 + wr * 64 + (rg & 3) + 8 * (rg >> 2) + 4 * g5;
        C[(size_t)row * cE + col] = acc0[rg] + bv;
    }
    #pragma unroll
    for (int rg = 0; rg < 16; ++rg) {
        const int row = r0 + wr * 64 + 32 + (rg & 3) + 8 * (rg >> 2) + 4 * g5;
        C[(size_t)row * cE + col] = acc1[rg] + bv;
    }
}

// ---------------------------------------------------------------------------
// Fused output GEMM, hi/lo MFMA (unchanged).
// ---------------------------------------------------------------------------
__global__ __launch_bounds__(256)
void out_gemm_hilo(const float* __restrict__ As_, const float* __restrict__ Ap_,
                   const unsigned short* __restrict__ w1hi,
                   const unsigned short* __restrict__ w1lo,
                   const unsigned short* __restrict__ w2hi,
                   const unsigned short* __restrict__ w2lo,
                   const float* __restrict__ bos, const float* __restrict__ bop,
                   const float* __restrict__ gates, float* __restrict__ out)
{
    __shared__ __align__(16) unsigned short A1h[128][24], A1l[128][24];
    __shared__ __align__(16) unsigned short A2h[128][24], A2l[128][24];
    __shared__ __align__(16) unsigned short B1h[64][24],  B1l[64][24];
    __shared__ __align__(16) unsigned short B2h[64][24],  B2l[64][24];

    const int t    = threadIdx.x;
    const int lane = t & 63, wave = t >> 6;
    const int wr   = wave >> 1, wc = wave & 1;
    const int r0   = blockIdx.y * 128, c0 = blockIdx.x * 64;
    const int fr   = lane & 31, g5 = lane >> 5;
    const int b    = r0 >> 11;
    const float gs = gates[b * 2 + 0], gp = gates[b * 2 + 1];

    const int arow = t >> 1, aka = (t & 1) * 8;
    const int bsel = t >> 7;
    const int brow = (t & 127) >> 1, bkb = (t & 1) * 8;
    const unsigned short* s1 = bsel ? w1lo : w1hi;
    const unsigned short* s2 = bsel ? w2lo : w2hi;

    f32x16 acc0 = {0.f,0.f,0.f,0.f,0.f,0.f,0.f,0.f,0.f,0.f,0.f,0.f,0.f,0.f,0.f,0.f};
    f32x16 acc1 = {0.f,0.f,0.f,0.f,0.f,0.f,0.f,0.f,0.f,0.f,0.f,0.f,0.f,0.f,0.f,0.f};

    for (int k0 = 0; k0 < cE; k0 += 16) {
        {
            const float4 x0 = *(const float4*)&As_[(size_t)(r0 + arow) * cE + k0 + aka];
            const float4 x1 = *(const float4*)&As_[(size_t)(r0 + arow) * cE + k0 + aka + 4];
            const float xf[8] = {x0.x * gs, x0.y * gs, x0.z * gs, x0.w * gs,
                                 x1.x * gs, x1.y * gs, x1.z * gs, x1.w * gs};
            unsigned int hw[4], lw[4];
            #pragma unroll
            for (int p = 0; p < 4; ++p) {
                unsigned short hh[2], ll[2];
                #pragma unroll
                for (int j = 0; j < 2; ++j) {
                    const float f = xf[p * 2 + j];
                    const _Float16 h = (_Float16)f;
                    hh[j] = h2u(h);
                    ll[j] = h2u((_Float16)(f - (float)h));
                }
                hw[p] = (unsigned int)hh[0] | ((unsigned int)hh[1] << 16);
                lw[p] = (unsigned int)ll[0] | ((unsigned int)ll[1] << 16);
            }
            uint4 hv, lv;
            hv.x = hw[0]; hv.y = hw[1]; hv.z = hw[2]; hv.w = hw[3];
            lv.x = lw[0]; lv.y = lw[1]; lv.z = lw[2]; lv.w = lw[3];
            *(uint4*)&A1h[arow][aka] = hv;
            *(uint4*)&A1l[arow][aka] = lv;
        }
        {
            const float4 x0 = *(const float4*)&Ap_[(size_t)(r0 + arow) * cE + k0 + aka];
            const float4 x1 = *(const float4*)&Ap_[(size_t)(r0 + arow) * cE + k0 + aka + 4];
            const float xf[8] = {x0.x * gp, x0.y * gp, x0.z * gp, x0.w * gp,
                                 x1.x * gp, x1.y * gp, x1.z * gp, x1.w * gp};
            unsigned int hw[4], lw[4];
            #pragma unroll
            for (int p = 0; p < 4; ++p) {
                unsigned short hh[2], ll[2];
                #pragma unroll
                for (int j = 0; j < 2; ++j) {
                    const float f = xf[p * 2 + j];
                    const _Float16 h = (_Float16)f;
                    hh[j] = h2u(h);
                    ll[j] = h2u((_Float16)(f - (float)h));
                }
                hw[p] = (unsigned int)hh[0] | ((unsigned int)hh[1] << 16);
                lw[p] = (unsigned int)ll[0] | ((unsigned int)ll[1] << 16);
            }
            uint4 hv, lv;
            hv.x = hw[0]; hv.y = hw[1]; hv.z = hw[2]; hv.w = hw[3];
            lv.x = lw[0]; lv.y = lw[1]; lv.z = lw[2]; lv.w = lw[3];
            *(uint4*)&A2h[arow][aka] = hv;
            *(uint4*)&A2l[arow][aka] = lv;
        }
        {
            const uint4 w1 = *(const uint4*)&s1[(size_t)(c0 + brow) * cE + k0 + bkb];
            if (bsel) *(uint4*)&B1l[brow][bkb] = w1;
            else      *(uint4*)&B1h[brow][bkb] = w1;
            const uint4 w2 = *(const uint4*)&s2[(size_t)(c0 + brow) * cE + k0 + bkb];
            if (bsel) *(uint4*)&B2l[brow][bkb] = w2;
            else      *(uint4*)&B2h[brow][bkb] = w2;
        }
        __syncthreads();

        const half8 b1h = ld_half8(&B1h[wc * 32 + fr][g5 * 8]);
        const half8 b1l = ld_half8(&B1l[wc * 32 + fr][g5 * 8]);
        const half8 b2h = ld_half8(&B2h[wc * 32 + fr][g5 * 8]);
        const half8 b2l = ld_half8(&B2l[wc * 32 + fr][g5 * 8]);
        {
            const half8 a1h = ld_half8(&A1h[wr * 64 + fr][g5 * 8]);
            const half8 a1l = ld_half8(&A1l[wr * 64 + fr][g5 * 8]);
            const half8 a2h = ld_half8(&A2h[wr * 64 + fr][g5 * 8]);
            const half8 a2l = ld_half8(&A2l[wr * 64 + fr][g5 * 8]);
            acc0 = __builtin_amdgcn_mfma_f32_32x32x16_f16(a1l, b1h, acc0, 0, 0, 0);
            acc0 = __builtin_amdgcn_mfma_f32_32x32x16_f16(a1h, b1l, acc0, 0, 0, 0);
            acc0 = __builtin_amdgcn_mfma_f32_32x32x16_f16(a1h, b1h, acc0, 0, 0, 0);
            acc0 = __builtin_amdgcn_mfma_f32_32x32x16_f16(a2l, b2h, acc0, 0, 0, 0);
            acc0 = __builtin_amdgcn_mfma_f32_32x32x16_f16(a2h, b2l, acc0, 0, 0, 0);
            acc0 = __builtin_amdgcn_mfma_f32_32x32x16_f16(a2h, b2h, acc0, 0, 0, 0);
        }
        {
            const half8 a1h = ld_half8(&A1h[wr * 64 + 32 + fr][g5 * 8]);
            const half8 a1l = ld_half8(&A1l[wr * 64 + 32 + fr][g5 * 8]);
            const half8 a2h = ld_half8(&A2h[wr * 64 + 32 + fr][g5 * 8]);
            const half8 a2l = ld_half8(&A2l[wr * 64 + 32 + fr][g5 * 8]);
            acc1 = __builtin_amdgcn_mfma_f32_32x32x16_f16(a1l, b1h, acc1, 0, 0, 0);
            acc1 = __builtin_amdgcn_mfma_f32_32x32x16_f16(a1h, b1l, acc1, 0, 0, 0);
            acc1 = __builtin_amdgcn_mfma_f32_32x32x16_f16(a1h, b1h, acc1, 0, 0, 0);
            acc1 = __builtin_amdgcn_mfma_f32_32x32x16_f16(a2l, b2h, acc1, 0, 0, 0);
            acc1 = __builtin_amdgcn_mfma_f32_32x32x16_f16(a2h, b2l, acc1, 0, 0, 0);
            acc1 = __builtin_amdgcn_mfma_f32_32x32x16_f16(a2h, b2h, acc1, 0, 0, 0);
        }
        __syncthreads();
    }

    const int col = c0 + wc * 32 + fr;
    const float bv = gs * bos[col] + gp * bop[col];
    #pragma unroll
    for (int rg = 0; rg < 16; ++rg) {
        const int row = r0 + wr * 64 + (rg & 3) + 8 * (rg >> 2) + 4 * g5;
        out[(size_t)row * cE + col] = acc0[rg] + bv;
    }
    #pragma unroll
    for (int rg = 0; rg < 16; ++rg) {
        const int row = r0 + wr * 64 + 32 + (rg & 3) + 8 * (rg >> 2) + 4 * g5;
        out[(size_t)row * cE + col] = acc1[rg] + bv;
    }
}

// ---------------------------------------------------------------------------
// Sparse selection, QBLK=16, 512 threads, dual-copy histogram to halve
// same-address LDS atomic serialization. Scan sums both copies => identical
// thresholds and candidates.
// ---------------------------------------------------------------------------
__global__ __launch_bounds__(512, 4)
void sparse_sel(const float* __restrict__ Q,
                const unsigned short* __restrict__ Khi,
                unsigned short* __restrict__ gcidx,
                int* __restrict__ gcnt)
{
    __shared__ __align__(16) unsigned short Qhi[16][72];  // 2.25 KB
    __shared__ unsigned int hist[2][16][257];             // 32.9 KB
    __shared__ int cnt[16];
    __shared__ int t16hi[16], rem[16], t16[16];

    const int t   = threadIdx.x;
    const int bh  = blockIdx.y;
    const int b   = bh >> 4;
    const int h64 = (bh & 15) * 64;
    const int q0  = blockIdx.x * 16;
    const size_t rid0 = (size_t)bh * 2048 + q0;           // linear row id base

    if (t < 256) {
        const int r = t >> 4, c4 = (t & 15) * 4;
        const float4 v =
            *(const float4*)&Q[((size_t)(b * cS + q0 + r)) * cE + h64 + c4];
        const float f[4] = {v.x, v.y, v.z, v.w};
        #pragma unroll
        for (int i = 0; i < 4; ++i)
            Qhi[r][c4 + i] = h2u((_Float16)f[i]);
    }
    for (int i = t; i < 2 * 16 * 257; i += 512) (&hist[0][0][0])[i] = 0u;
    if (t < 16) cnt[t] = 0;
    __syncthreads();                                               // B1

    const int lane = t & 63;
    const int wv   = t >> 6;            // 0..7, each wave covers 256 keys
    const int col  = lane & 31;
    const int g5   = lane >> 5;
    const int cp   = (lane >> 4) & 1;   // histogram copy (quarter-wave split)
    const int base0 = 4 * g5;           // rows from acc regs 0..3
    const int base1 = 8 + 4 * g5;       // rows from acc regs 4..7

    // ---- phase A: single-product f16 MFMA scores, keys wv*256 .. +256 ----
    half8 ahi[4];
    {
        const int arow = col & 15;      // 16 valid Q rows (dup x2 over 32)
        #pragma unroll
        for (int ks = 0; ks < 4; ++ks)
            ahi[ks] = ld_half8(&Qhi[arow][g5 * 8 + ks * 16]);
    }
    unsigned int su[8][4];              // u16 keys, 8 rows x 8 tiles
    {
        const size_t kbase = ((size_t)(b * cS + wv * 256 + col)) * cE + h64;
        #pragma unroll
        for (int tl = 0; tl < 8; ++tl) {
            const unsigned short* kh = Khi + kbase + (size_t)tl * 32 * cE;
            f32x16 acc = {0.f,0.f,0.f,0.f,0.f,0.f,0.f,0.f,
                          0.f,0.f,0.f,0.f,0.f,0.f,0.f,0.f};
            #pragma unroll
            for (int ks = 0; ks < 4; ++ks) {
                const half8 bh8 = ld_half8(kh + g5 * 8 + ks * 16);
                acc = __builtin_amdgcn_mfma_f32_32x32x16_f16(ahi[ks], bh8, acc, 0, 0, 0);
            }
            unsigned int k[8];
            #pragma unroll
            for (int r = 0; r < 8; ++r)
                k[r] = f2key(acc[r] * 0.125f) >> 16;
            su[tl][0] = k[0] | (k[1] << 16);
            su[tl][1] = k[2] | (k[3] << 16);
            su[tl][2] = k[4] | (k[5] << 16);
            su[tl][3] = k[6] | (k[7] << 16);
            atomicAdd(&hist[cp][base0 + 0][k[0] >> 8], 1u);
            atomicAdd(&hist[cp][base0 + 1][k[1] >> 8], 1u);
            atomicAdd(&hist[cp][base0 + 2][k[2] >> 8], 1u);
            atomicAdd(&hist[cp][base0 + 3][k[3] >> 8], 1u);
            atomicAdd(&hist[cp][base1 + 0][k[4] >> 8], 1u);
            atomicAdd(&hist[cp][base1 + 1][k[5] >> 8], 1u);
            atomicAdd(&hist[cp][base1 + 2][k[6] >> 8], 1u);
            atomicAdd(&hist[cp][base1 + 3][k[7] >> 8], 1u);
        }
    }
    __syncthreads();                                               // B2
    if (t < 16) {
        int need = cKTOP + 1;   // 65
        int hb = 0;
        for (int bin = 255; bin >= 0; --bin) {
            const int c = (int)(hist[0][t][bin] + hist[1][t][bin]);
            if (c >= need) { hb = bin; break; }
            need -= c;
        }
        t16hi[t] = hb;
        rem[t] = need;
    }
    __syncthreads();                                               // B3
    for (int i = t; i < 2 * 16 * 257; i += 512) (&hist[0][0][0])[i] = 0u;  // pass 2
    __syncthreads();                                               // B3b
    #pragma unroll
    for (int tl = 0; tl < 8; ++tl)
        #pragma unroll
        for (int w = 0; w < 4; ++w) {
            const unsigned int u = su[tl][w];
            const int rlo = (w < 2 ? base0 : base1) + (w & 1) * 2;
            const int rhi = rlo + 1;
            const unsigned int vlo = u & 0xFFFFu;
            const unsigned int vhi = u >> 16;
            if ((int)(vlo >> 8) == t16hi[rlo]) atomicAdd(&hist[cp][rlo][vlo & 255u], 1u);
            if ((int)(vhi >> 8) == t16hi[rhi]) atomicAdd(&hist[cp][rhi][vhi & 255u], 1u);
        }
    __syncthreads();                                               // B4
    if (t < 16) {
        int need = rem[t];
        int lb = 0;
        for (int bin = 255; bin >= 0; --bin) {
            const int c = (int)(hist[0][t][bin] + hist[1][t][bin]);
            if (c >= need) { lb = bin; break; }
            need -= c;
        }
        t16[t] = (t16hi[t] << 8) | lb;
    }
    __syncthreads();                                               // B5

    // ---- candidate scan: u16 >= T16 - 3; write straight to global ----
    #pragma unroll
    for (int tl = 0; tl < 8; ++tl) {
        const int key = wv * 256 + tl * 32 + col;
        #pragma unroll
        for (int w = 0; w < 4; ++w) {
            const unsigned int u = su[tl][w];
            const int rlo = (w < 2 ? base0 : base1) + (w & 1) * 2;
            const int rhi = rlo + 1;
            const int v0 = (int)(u & 0xFFFFu);
            const int v1 = (int)(u >> 16);
            if (v0 >= max(t16[rlo] - 3, 0)) {
                const int slot = atomicAdd(&cnt[rlo], 1);
                if (slot < 128) gcidx[(rid0 + rlo) * 128 + slot] = (unsigned short)key;
            }
            if (v1 >= max(t16[rhi] - 3, 0)) {
                const int slot = atomicAdd(&cnt[rhi], 1);
                if (slot < 128) gcidx[(rid0 + rhi) * 128 + slot] = (unsigned short)key;
            }
        }
    }
    __syncthreads();                                               // B6
    if (t < 16) gcnt[rid0 + t] = cnt[t];
}

// ---------------------------------------------------------------------------
// Sparse attention (phases C/D, unchanged): fp64 recompute, ranking, hedge
// weights, unroll-8 PV gather. __launch_bounds__(256,8).
// ---------------------------------------------------------------------------
__global__ __launch_bounds__(256, 8)
void sparse_att(const float* __restrict__ Q,
                const unsigned short* __restrict__ gcidx,
                const int* __restrict__ gcnt,
                const float* __restrict__ Ks, const float* __restrict__ V,
                float* __restrict__ O)
{
    __shared__ float QfT[64][8];                 // 2 KB  (Q transposed)
    __shared__ unsigned short cidx[8][128];      // 2 KB
    __shared__ double cval[8][128];              // 8 KB
    __shared__ float cw[8][128];                 // 4 KB
    __shared__ int cnt[8];
    __shared__ double T64s[8], s65s[8], rowm[8];

    const int t   = threadIdx.x;
    const int bh  = blockIdx.y;
    const int b   = bh >> 4;
    const int h64 = (bh & 15) * 64;
    const int q0  = blockIdx.x * 8;
    const size_t rid0 = ((size_t)bh * 256 + blockIdx.x) * 8;

    if (t < 128) {
        const int r = t >> 4, c4 = (t & 15) * 4;
        const float4 v =
            *(const float4*)&Q[((size_t)(b * cS + q0 + r)) * cE + h64 + c4];
        QfT[c4 + 0][r] = v.x; QfT[c4 + 1][r] = v.y;
        QfT[c4 + 2][r] = v.z; QfT[c4 + 3][r] = v.w;
    }
    // 8 rows x 128 u16 are contiguous in gcidx -> one ushort4 per thread
    ((ushort4*)&cidx[0][0])[t] = ((const ushort4*)&gcidx[rid0 * 128])[t];
    if (t < 8) cnt[t] = gcnt[rid0 + t];
    __syncthreads();                                               // B6'

    const int wv = t >> 6, lane = t & 63;

    // ---- phase C: fp64 recompute, lane = candidate (2 rows per wave) ----
    #pragma unroll
    for (int rx = 0; rx < 2; ++rx) {
        const int rr = wv * 2 + rx;
        const int n = min(cnt[rr], 128);
        for (int c = lane; c < n; c += 64) {
            const int key = cidx[rr][c];
            const float* kp = Ks + ((size_t)(b * cS + key)) * cE + h64;
            double a = 0.0;
            #pragma unroll 4
            for (int d4 = 0; d4 < 64; d4 += 4) {
                const float4 kv = *(const float4*)&kp[d4];
                a = fma((double)QfT[d4 + 0][rr], (double)kv.x, a);
                a = fma((double)QfT[d4 + 1][rr], (double)kv.y, a);
                a = fma((double)QfT[d4 + 2][rr], (double)kv.z, a);
                a = fma((double)QfT[d4 + 3][rr], (double)kv.w, a);
            }
            cval[rr][c] = a * 0.125;
        }
    }
    __syncthreads();                                               // B7

    // ---- ranking: T64 (rank 63), s65 (rank 64), m (rank 0) ----
    #pragma unroll
    for (int rx = 0; rx < 2; ++rx) {
        const int rr = wv * 2 + rx;
        const int n = min(cnt[rr], 128);
        for (int c = lane; c < n; c += 64) {
            const double v = cval[rr][c];
            int rank = 0;
            for (int i = 0; i < n; ++i) rank += (cval[rr][i] > v) ? 1 : 0;
            if (rank == 0)  rowm[rr] = v;
            if (rank == 63) T64s[rr] = v;
            if (rank == 64) s65s[rr] = v;
        }
    }
    __syncthreads();                                               // B8

    // ---- weights: hedge formula (unchanged) ----
    #pragma unroll
    for (int rx = 0; rx < 2; ++rx) {
        const int rr = wv * 2 + rx;
        const int n = min(cnt[rr], 128);
        const double T64 = T64s[rr], s65 = s65s[rr], m = rowm[rr];
        float za = 0.f;
        for (int c = lane; c < n; c += 64) {
            const double v = cval[rr][c];
            if (v >= T64) za += expf((float)(v - m));
        }
        #pragma unroll
        for (int off = 32; off >= 1; off >>= 1)
            za += __shfl_xor(za, off);
        const float g   = (float)(T64 - s65);
        const float gm  = fmaxf(g - 5e-7f, 0.f);
        const float wB  = 0.5f * erfcf(gm * (1.0f / 2.2e-6f));
        const float wA  = 1.f - wB;
        const float e64 = expf((float)(T64 - m));
        const float e65 = expf((float)(s65 - m));
        const float ZB  = za - e64 + e65;
        const float cIn = wA / za + wB / ZB;
        const float c64 = wA / za;
        const float c65 = wB / ZB;
        for (int c = lane; c < n; c += 64) {
            const double v = cval[rr][c];
            float cc = 0.f;
            if (v > T64)       cc = cIn;
            else if (v == T64) cc = c64;
            else if (v == s65) cc = c65;
            cw[rr][c] = (cc != 0.f) ? cc * expf((float)(v - m)) : 0.f;
        }
    }
    __syncthreads();                                               // B9

    // ---- phase D: sparse PV gather, unroll-8 pipelined (same sum order) ----
    #pragma unroll
    for (int rx = 0; rx < 2; ++rx) {
        const int rr = wv * 2 + rx;
        const int n = min(cnt[rr], 128);
        float o = 0.f;
        int j = 0;
        for (; j + 8 <= n; j += 8) {
            float wreg[8];
            int   kreg[8];
            #pragma unroll
            for (int u = 0; u < 8; ++u) {
                wreg[u] = cw[rr][j + u];
                kreg[u] = cidx[rr][j + u];
            }
            float vreg[8];
            #pragma unroll
            for (int u = 0; u < 8; ++u)
                vreg[u] = V[((size_t)(b * cS + kreg[u])) * cE + h64 + lane];
            #pragma unroll
            for (int u = 0; u < 8; ++u)
                o = fmaf(wreg[u], vreg[u], o);
        }
        for (; j < n; ++j)
            o = fmaf(cw[rr][j],
                     V[((size_t)(b * cS + cidx[rr][j])) * cE + h64 + lane], o);
        O[((size_t)(b * cS + q0 + rr)) * cE + h64 + lane] = o;
    }
}

// ---------------------------------------------------------------------------
// Performer kv (unchanged)
// ---------------------------------------------------------------------------
__global__ __launch_bounds__(256)
void perf_kv(const float* __restrict__ Kp, const float* __restrict__ Vp,
             const float* __restrict__ Wfeat,
             float* __restrict__ kvpart, float* __restrict__ zpart)
{
    __shared__ __align__(16) float Wf[64][68];
    __shared__ __align__(16) float Kt[64][68];
    __shared__ __align__(16) float Vt[64][68];
    __shared__ __align__(16) float Ph[64][68];
    const int t    = threadIdx.x;
    const int mc   = blockIdx.x & 3;
    const int sc   = blockIdx.x >> 2;          // 0 or 1
    const int bh   = blockIdx.y;
    const int b    = bh >> 4;
    const int h64  = (bh & 15) * 64;
    const int m0   = mc * 64;
    const int sbase = sc * 1024;

    #pragma unroll
    for (int i = 0; i < 4; ++i) {
        const int lin = t + 256 * i;
        const int d   = lin >> 4;
        const int m4  = (lin & 15) * 4;
        *(float4*)&Wf[d][m4] = *(const float4*)&Wfeat[d * cM + m0 + m4];
    }

    const int tm = t >> 4, tn = t & 15;
    const int sr = tm * 4;
    const int cn = tn * 4;
    float akv[4][4] = {};
    float az = 0.f;

    for (int st = 0; st < 16; ++st) {
        const int s0g = sbase + st * 64;
        __syncthreads();
        #pragma unroll
        for (int i = 0; i < 4; ++i) {
            const int row = tm + 16 * i;
            const size_t base = ((size_t)(b * cS + s0g + row)) * cE + h64 + cn;
            *(float4*)&Kt[row][cn] = *(const float4*)&Kp[base];
            *(float4*)&Vt[row][cn] = *(const float4*)&Vp[base];
        }
        __syncthreads();
        float4 p0 = {0,0,0,0}, p1 = {0,0,0,0}, p2 = {0,0,0,0}, p3 = {0,0,0,0};
        #pragma unroll 8
        for (int d = 0; d < 64; ++d) {
            const float4 wv = *(const float4*)&Wf[d][cn];
            const float k0 = Kt[sr + 0][d], k1 = Kt[sr + 1][d];
            const float k2 = Kt[sr + 2][d], k3 = Kt[sr + 3][d];
            p0.x = fmaf(k0, wv.x, p0.x); p0.y = fmaf(k0, wv.y, p0.y);
            p0.z = fmaf(k0, wv.z, p0.z); p0.w = fmaf(k0, wv.w, p0.w);
            p1.x = fmaf(k1, wv.x, p1.x); p1.y = fmaf(k1, wv.y, p1.y);
            p1.z = fmaf(k1, wv.z, p1.z); p1.w = fmaf(k1, wv.w, p1.w);
            p2.x = fmaf(k2, wv.x, p2.x); p2.y = fmaf(k2, wv.y, p2.y);
            p2.z = fmaf(k2, wv.z, p2.z); p2.w = fmaf(k2, wv.w, p2.w);
            p3.x = fmaf(k3, wv.x, p3.x); p3.y = fmaf(k3, wv.y, p3.y);
            p3.z = fmaf(k3, wv.z, p3.z); p3.w = fmaf(k3, wv.w, p3.w);
        }
        p0.x = fmaxf(p0.x, 0.f) + cEPS; p0.y = fmaxf(p0.y, 0.f) + cEPS;
        p0.z = fmaxf(p0.z, 0.f) + cEPS; p0.w = fmaxf(p0.w, 0.f) + cEPS;
        p1.x = fmaxf(p1.x, 0.f) + cEPS; p1.y = fmaxf(p1.y, 0.f) + cEPS;
        p1.z = fmaxf(p1.z, 0.f) + cEPS; p1.w = fmaxf(p1.w, 0.f) + cEPS;
        p2.x = fmaxf(p2.x, 0.f) + cEPS; p2.y = fmaxf(p2.y, 0.f) + cEPS;
        p2.z = fmaxf(p2.z, 0.f) + cEPS; p2.w = fmaxf(p2.w, 0.f) + cEPS;
        p3.x = fmaxf(p3.x, 0.f) + cEPS; p3.y = fmaxf(p3.y, 0.f) + cEPS;
        p3.z = fmaxf(p3.z, 0.f) + cEPS; p3.w = fmaxf(p3.w, 0.f) + cEPS;
        *(float4*)&Ph[sr + 0][cn] = p0;
        *(float4*)&Ph[sr + 1][cn] = p1;
        *(float4*)&Ph[sr + 2][cn] = p2;
        *(float4*)&Ph[sr + 3][cn] = p3;
        __syncthreads();
        #pragma unroll 8
        for (int ss = 0; ss < 64; ++ss) {
            const float4 pv = *(const float4*)&Ph[ss][sr];
            const float4 vv = *(const float4*)&Vt[ss][cn];
            akv[0][0] = fmaf(pv.x, vv.x, akv[0][0]); akv[0][1] = fmaf(pv.x, vv.y, akv[0][1]);
            akv[0][2] = fmaf(pv.x, vv.z, akv[0][2]); akv[0][3] = fmaf(pv.x, vv.w, akv[0][3]);
            akv[1][0] = fmaf(pv.y, vv.x, akv[1][0]); akv[1][1] = fmaf(pv.y, vv.y, akv[1][1]);
            akv[1][2] = fmaf(pv.y, vv.z, akv[1][2]); akv[1][3] = fmaf(pv.y, vv.w, akv[1][3]);
            akv[2][0] = fmaf(pv.z, vv.x, akv[2][0]); akv[2][1] = fmaf(pv.z, vv.y, akv[2][1]);
            akv[2][2] = fmaf(pv.z, vv.z, akv[2][2]); akv[2][3] = fmaf(pv.z, vv.w, akv[2][3]);
            akv[3][0] = fmaf(pv.w, vv.x, akv[3][0]); akv[3][1] = fmaf(pv.w, vv.y, akv[3][1]);
            akv[3][2] = fmaf(pv.w, vv.z, akv[3][2]); akv[3][3] = fmaf(pv.w, vv.w, akv[3][3]);
        }
        if (t < 64) {
            float a = 0.f;
            #pragma unroll 8
            for (int ss = 0; ss < 64; ++ss) a += Ph[ss][t];
            az += a;
        }
    }
    const size_t obase = ((size_t)(sc * 32 + bh)) * cM + m0;
    #pragma unroll
    for (int i = 0; i < 4; ++i) {
        float4 v; v.x = akv[i][0]; v.y = akv[i][1]; v.z = akv[i][2]; v.w = akv[i][3];
        *(float4*)&kvpart[(obase + sr + i) * cD + cn] = v;
    }
    if (t < 64) zpart[obase + t] = az;
}

// ---------------------------------------------------------------------------
// Performer num/den (unchanged)
// ---------------------------------------------------------------------------
__global__ __launch_bounds__(256)
void perf_numden(const float* __restrict__ Qp, const float* __restrict__ Wfeat,
                 const float* __restrict__ kvpart, const float* __restrict__ zpart,
                 float* __restrict__ Ap)
{
    __shared__ __align__(16) float Wf[64][68];
    __shared__ __align__(16) float Qt[64][68];
    __shared__ __align__(16) float KV[64][68];
    __shared__ __align__(16) float Ph[64][68];
    __shared__ __align__(16) float zl[64];
    __shared__ float den[64];
    const int t   = threadIdx.x;
    const int stb = blockIdx.x;
    const int bh  = blockIdx.y;
    const int b   = bh >> 4;
    const int h64 = (bh & 15) * 64;
    const int s0  = stb * 64;
    const int tm  = t >> 4, tn = t & 15;
    const int sr  = tm * 4, cn = tn * 4;

    #pragma unroll
    for (int i = 0; i < 4; ++i) {
        const int row = tm + 16 * i;
        *(float4*)&Qt[row][cn] =
            *(const float4*)&Qp[((size_t)(b * cS + s0 + row)) * cE + h64 + cn];
    }

    float num[4][4] = {};
    float dacc = 0.f;

    for (int mc = 0; mc < 4; ++mc) {
        const int m0 = mc * 64;
        __syncthreads();
        #pragma unroll
        for (int i = 0; i < 4; ++i) {
            const int lin = t + 256 * i;
            const int d   = lin >> 4;
            const int m4  = (lin & 15) * 4;
            *(float4*)&Wf[d][m4] = *(const float4*)&Wfeat[d * cM + m0 + m4];
        }
        #pragma unroll
        for (int i = 0; i < 4; ++i) {
            const int row = tm + 16 * i;
            const size_t o0 = ((size_t)bh * cM + m0 + row) * cD + cn;
            const size_t o1 = ((size_t)(32 + bh) * cM + m0 + row) * cD + cn;
            const float4 a = *(const float4*)&kvpart[o0];
            const float4 c = *(const float4*)&kvpart[o1];
            float4 v; v.x = a.x + c.x; v.y = a.y + c.y; v.z = a.z + c.z; v.w = a.w + c.w;
            *(float4*)&KV[row][cn] = v;
        }
        if (t < 64)
            zl[t] = zpart[(size_t)bh * cM + m0 + t] + zpart[(size_t)(32 + bh) * cM + m0 + t];
        __syncthreads();
        float4 p0 = {0,0,0,0}, p1 = {0,0,0,0}, p2 = {0,0,0,0}, p3 = {0,0,0,0};
        #pragma unroll 8
        for (int d = 0; d < 64; ++d) {
            const float4 wv = *(const float4*)&Wf[d][cn];
            const float q0 = Qt[sr + 0][d], q1 = Qt[sr + 1][d];
            const float q2 = Qt[sr + 2][d], q3 = Qt[sr + 3][d];
            p0.x = fmaf(q0, wv.x, p0.x); p0.y = fmaf(q0, wv.y, p0.y);
            p0.z = fmaf(q0, wv.z, p0.z); p0.w = fmaf(q0, wv.w, p0.w);
            p1.x = fmaf(q1, wv.x, p1.x); p1.y = fmaf(q1, wv.y, p1.y);
            p1.z = fmaf(q1, wv.z, p1.z); p1.w = fmaf(q1, wv.w, p1.w);
            p2.x = fmaf(q2, wv.x, p2.x); p2.y = fmaf(q2, wv.y, p2.y);
            p2.z = fmaf(q2, wv.z, p2.z); p2.w = fmaf(q2, wv.w, p2.w);
            p3.x = fmaf(q3, wv.x, p3.x); p3.y = fmaf(q3, wv.y, p3.y);
            p3.z = fmaf(q3, wv.z, p3.z); p3.w = fmaf(q3, wv.w, p3.w);
        }
        p0.x = fmaxf(p0.x, 0.f) + cEPS; p0.y = fmaxf(p0.y, 0.f) + cEPS;
        p0.z = fmaxf(p0.z, 0.f) + cEPS; p0.w = fmaxf(p0.w, 0.f) + cEPS;
        p1.x = fmaxf(p1.x, 0.f) + cEPS; p1.y = fmaxf(p1.y, 0.f) + cEPS;
        p1.z = fmaxf(p1.z, 0.f) + cEPS; p1.w = fmaxf(p1.w, 0.f) + cEPS;
        p2.x = fmaxf(p2.x, 0.f) + cEPS; p2.y = fmaxf(p2.y, 0.f) + cEPS;
        p2.z = fmaxf(p2.z, 0.f) + cEPS; p2.w = fmaxf(p2.w, 0.f) + cEPS;
        p3.x = fmaxf(p3.x, 0.f) + cEPS; p3.y = fmaxf(p3.y, 0.f) + cEPS;
        p3.z = fmaxf(p3.z, 0.f) + cEPS; p3.w = fmaxf(p3.w, 0.f) + cEPS;
        *(float4*)&Ph[sr + 0][cn] = p0;
        *(float4*)&Ph[sr + 1][cn] = p1;
        *(float4*)&Ph[sr + 2][cn] = p2;
        *(float4*)&Ph[sr + 3][cn] = p3;
        __syncthreads();
        #pragma unroll 8
        for (int mm = 0; mm < 64; ++mm) {
            const float4 kvv = *(const float4*)&KV[mm][cn];
            const float a0 = Ph[sr + 0][mm], a1 = Ph[sr + 1][mm];
            const float a2 = Ph[sr + 2][mm], a3 = Ph[sr + 3][mm];
            num[0][0] = fmaf(a0, kvv.x, num[0][0]); num[0][1] = fmaf(a0, kvv.y, num[0][1]);
            num[0][2] = fmaf(a0, kvv.z, num[0][2]); num[0][3] = fmaf(a0, kvv.w, num[0][3]);
            num[1][0] = fmaf(a1, kvv.x, num[1][0]); num[1][1] = fmaf(a1, kvv.y, num[1][1]);
            num[1][2] = fmaf(a1, kvv.z, num[1][2]); num[1][3] = fmaf(a1, kvv.w, num[1][3]);
            num[2][0] = fmaf(a2, kvv.x, num[2][0]); num[2][1] = fmaf(a2, kvv.y, num[2][1]);
            num[2][2] = fmaf(a2, kvv.z, num[2][2]); num[2][3] = fmaf(a2, kvv.w, num[2][3]);
            num[3][0] = fmaf(a3, kvv.x, num[3][0]); num[3][1] = fmaf(a3, kvv.y, num[3][1]);
            num[3][2] = fmaf(a3, kvv.z, num[3][2]); num[3][3] = fmaf(a3, kvv.w, num[3][3]);
        }
        if (t < 64) {
            float a = 0.f;
            #pragma unroll
            for (int m4 = 0; m4 < 64; m4 += 4) {
                const float4 ph = *(const float4*)&Ph[t][m4];
                const float4 zz = *(const float4*)&zl[m4];
                a = fmaf(ph.x, zz.x, a); a = fmaf(ph.y, zz.y, a);
                a = fmaf(ph.z, zz.z, a); a = fmaf(ph.w, zz.w, a);
            }
            dacc += a;
        }
    }
    __syncthreads();
    if (t < 64) den[t] = dacc + cEPS;
    __syncthreads();
    #pragma unroll
    for (int i = 0; i < 4; ++i) {
        const float di = 1.f / den[sr + i];
        float4 v;
        v.x = num[i][0] * di; v.y = num[i][1] * di;
        v.z = num[i][2] * di; v.w = num[i][3] * di;
        *(float4*)&Ap[((size_t)(b * cS + s0 + sr + i)) * cE + h64 + cn] = v;
    }
}

// ---------------------------------------------------------------------------
// Gate (unchanged)
// ---------------------------------------------------------------------------
__global__ __launch_bounds__(256)
void gate_avg(const float* __restrict__ x, double* __restrict__ avgpart)
{
    const int i  = blockIdx.x * 256 + threadIdx.x;    // 0..2047: (b,e)
    const int sc = blockIdx.y;                        // 0..15
    const int b  = i >> 10, e = i & 1023;
    double acc = 0.0;
    const int sEnd = sc * 128 + 128;
    for (int s = sc * 128; s < sEnd; ++s)
        acc += (double)x[((size_t)(b * cS + s)) * cE + e];
    avgpart[(size_t)sc * 2048 + i] = acc;
}

__global__ void gate_final(const double* __restrict__ avgpart, const float* __restrict__ Wg,
                           const float* __restrict__ bg, float* __restrict__ gates)
{
    const int t = threadIdx.x;
    const int b = t >> 6, lane = t & 63;
    float l0 = 0.f, l1 = 0.f;
    for (int e = lane; e < cE; e += 64) {
        double s = 0.0;
        #pragma unroll
        for (int sc = 0; sc < 16; ++sc)
            s += avgpart[(size_t)sc * 2048 + b * 1024 + e];
        const float a = (float)(s / (double)cS);
        l0 = fmaf(a, Wg[e * 2 + 0], l0);
        l1 = fmaf(a, Wg[e * 2 + 1], l1);
    }
    for (int off = 32; off >= 1; off >>= 1) {
        l0 += __shfl_down(l0, off);
        l1 += __shfl_down(l1, off);
    }
    if (lane == 0) {
        l0 += bg[0]; l1 += bg[1];
        const float m = fmaxf(l0, l1);
        const float e0 = expf(l0 - m), e1 = expf(l1 - m);
        const float s = e0 + e1;
        gates[b * 2 + 0] = e0 / s;
        gates[b * 2 + 1] = e1 / s;
    }
}

// ---------------------------------------------------------------------------
extern "C" void kernel_launch(void* const* d_in, const int* in_sizes, int n_in,
                              void* d_out, int out_size, void* d_ws, size_t ws_size,
                              hipStream_t stream)
{
    (void)in_sizes; (void)n_in; (void)out_size; (void)ws_size;
    const float* x     = (const float*)d_in[0];
    const float* Wq_s  = (const float*)d_in[1];
    const float* Wk_s  = (const float*)d_in[2];
    const float* Wv_s  = (const float*)d_in[3];
    const float* Wo_s  = (const float*)d_in[4];
    const float* bq_s  = (const float*)d_in[5];
    const float* bk_s  = (const float*)d_in[6];
    const float* bv_s  = (const float*)d_in[7];
    const float* bo_s  = (const float*)d_in[8];
    const float* Wq_p  = (const float*)d_in[9];
    const float* Wk_p  = (const float*)d_in[10];
    const float* Wv_p  = (const float*)d_in[11];
    const float* Wo_p  = (const float*)d_in[12];
    const float* bo_p  = (const float*)d_in[13];
    const float* Wfeat = (const float*)d_in[14];
    const float* Wg    = (const float*)d_in[15];
    const float* bg    = (const float*)d_in[16];

    float* ws = (float*)d_ws;
    const size_t NRE = (size_t)cB * cS * cE;
    float* Qs    = ws;              // later: Qp
    float* Ks    = Qs + NRE;        // later: Kp
    float* KsT   = Ks + NRE;        // sparse: Khi (u16); later: Apout
    float* Vs    = KsT + NRE;       // later: Vp
    float* Asout = Vs + NRE;
    float* kvpart = Asout + NRE;                           // 2*32*256*64
    float* zpart  = kvpart + (size_t)2 * 32 * cM * cD;     // 2*32*256
    double* avgpart = (double*)(zpart + (size_t)2 * 32 * cM);  // 16*2048 doubles
    float* gates = (float*)(avgpart + (size_t)16 * 2048);  // 4
    unsigned short* wthi  = (unsigned short*)(gates + 16); // 1M ushorts (scratch, reused)
    unsigned short* wtlo  = wthi + (size_t)cE * cE;
    unsigned short* wo1hi = wtlo + (size_t)cE * cE;        // Wo_s split (persistent)
    unsigned short* wo1lo = wo1hi + (size_t)cE * cE;
    unsigned short* wo2hi = wo1lo + (size_t)cE * cE;       // Wo_p split (persistent)
    unsigned short* wo2lo = wo2hi + (size_t)cE * cE;
    unsigned short* gcidx = wo2lo + (size_t)cE * cE;       // 65536 rows * 128 u16 = 16 MB
    int* gcnt = (int*)(gcidx + (size_t)65536 * 128);       // 65536 ints

    unsigned short* Khi = (unsigned short*)KsT;            // NRE ushorts (8 MB)

    // ---- output-weight splits (independent of everything else) ----
    conv_wT<<<dim3(16, 16), 256, 0, stream>>>(Wo_s, wo1hi, wo1lo);
    conv_wT<<<dim3(16, 16), 256, 0, stream>>>(Wo_p, wo2hi, wo2lo);

    // ---- sparse branch: fused BLAS-mimic fp32 Q+K (+Khi), MFMA V ----
    gemm_qk2_blas<<<dim3(16, 64), 256, 0, stream>>>(x, Wq_s, Wk_s, bq_s, bk_s,
                                                    Qs, Ks, Khi, cE, cE);
    conv_wT<<<dim3(16, 16), 256, 0, stream>>>(Wv_s, wthi, wtlo);
    gemm_hilo<<<dim3(16, 32), 256, 0, stream>>>(x, wthi, wtlo, bv_s, Vs);
    sparse_sel<<<dim3(128, 32), 512, 0, stream>>>(Qs, Khi, gcidx, gcnt);
    sparse_att<<<dim3(256, 32), 256, 0, stream>>>(Qs, gcidx, gcnt, Ks, Vs, Asout);

    // ---- performer branch (reuses buffers) ----
    float* Qp    = Qs;
    float* Kp    = Ks;
    float* Vp    = Vs;
    float* Apout = KsT;
    conv_wT<<<dim3(16, 16), 256, 0, stream>>>(Wq_p, wthi, wtlo);
    gemm_hilo<<<dim3(16, 32), 256, 0, stream>>>(x, wthi, wtlo, nullptr, Qp);
    conv_wT<<<dim3(16, 16), 256, 0, stream>>>(Wk_p, wthi, wtlo);
    gemm_hilo<<<dim3(16, 32), 256, 0, stream>>>(x, wthi, wtlo, nullptr, Kp);
    conv_wT<<<dim3(16, 16), 256, 0, stream>>>(Wv_p, wthi, wtlo);
    gemm_hilo<<<dim3(16, 32), 256, 0, stream>>>(x, wthi, wtlo, nullptr, Vp);
    perf_kv<<<dim3(8, 32), 256, 0, stream>>>(Kp, Vp, Wfeat, kvpart, zpart);
    perf_numden<<<dim3(32, 32), 256, 0, stream>>>(Qp, Wfeat, kvpart, zpart, Apout);

    // ---- gate + fused MFMA output ----
    gate_avg<<<dim3(8, 16), 256, 0, stream>>>(x, avgpart);
    gate_final<<<dim3(1), 128, 0, stream>>>(avgpart, Wg, bg, gates);
    out_gemm_hilo<<<dim3(16, 32), 256, 0, stream>>>(Asout, Apout,
                                                    wo1hi, wo1lo, wo2hi, wo2lo,
                                                    bo_s, bo_p, gates,
                                                    (float*)d_out);
}

// Round 16
// 1356.195 us; speedup vs baseline: 1.0141x; 1.0114x over previous
//
#include <hip/hip_runtime.h>

// ---------------------------------------------------------------------------
// HybridThoughtAwareAttention  (B=2,S=2048,E=1024,H=16,D=64,K_TOP=64,M=256)
// FINAL (round 23): byte-identical resubmit of the round-20 kernel — the
// session's best measured configuration (1349.7 us vs 2171 us baseline).
// Rounds 21 (spill fix: 1375) and 22 (dual-copy histogram: 1372, conflicts
// halved but no speedup) both measured slower; the round-20 spill is fully
// latency-hidden. Structure: fused bit-exact Q+K BLAS GEMM (+f16 K copy);
// sparse selection via single-product f16 MFMA (QBLK=16) + radix select;
// split fp64 recompute/hedge/gather kernel at 8 blocks/CU; f16 hi/lo
// 3-product MFMA for all smooth GEMMs; fused gated output GEMM.
// ---------------------------------------------------------------------------

constexpr int cB = 2, cS = 2048, cE = 1024, cH = 16, cD = 64, cKTOP = 64, cM = 256;
constexpr float cEPS = 1e-6f;

typedef _Float16 half8 __attribute__((ext_vector_type(8)));
typedef float f32x16 __attribute__((ext_vector_type(16)));

__device__ __forceinline__ unsigned int f2key(float f) {    // monotone f32->u32
    unsigned int u = __float_as_uint(f);
    return (u & 0x80000000u) ? ~u : (u | 0x80000000u);
}

__device__ __forceinline__ unsigned short h2u(_Float16 h) {
    union { _Float16 h; unsigned short u; } x; x.h = h; return x.u;
}

__device__ __forceinline__ half8 ld_half8(const unsigned short* p) {
    union { uint4 u; half8 h; } x;
    x.u = *(const uint4*)p;
    return x.h;
}

// ---------------------------------------------------------------------------
// Fused OpenBLAS-mimicking fp32 GEMM for Qs AND Ks (bit-exact selection path).
// ---------------------------------------------------------------------------
__global__ __launch_bounds__(256)
void gemm_qk2_blas(const float* __restrict__ A,
                   const float* __restrict__ Wq,
                   const float* __restrict__ Wk,
                   const float* __restrict__ bq,
                   const float* __restrict__ bk_,
                   float* __restrict__ Cq,
                   float* __restrict__ Ck,
                   unsigned short* __restrict__ khi,
                   int K, int N)
{
    __shared__ __align__(16) float As[16][68];
    __shared__ __align__(16) float Bq[16][68];
    __shared__ __align__(16) float Bk[16][68];
    const int t  = threadIdx.x;
    const int r0 = blockIdx.y * 64;
    const int c0 = blockIdx.x * 64;
    const int tm = t >> 4, tn = t & 15;
    float paccQ[4][4] = {};
    float caccQ[4][4] = {};
    float paccK[4][4] = {};
    float caccK[4][4] = {};

    const int ar = t >> 2, ak = (t & 3) * 4;
    const int bk = t >> 4, bc = (t & 15) * 4;

    for (int k0 = 0; k0 < K; k0 += 16) {
        const float4 av  = *(const float4*)(A  + (size_t)(r0 + ar) * K + (k0 + ak));
        const float4 bqv = *(const float4*)(Wq + (size_t)(k0 + bk) * N + (c0 + bc));
        const float4 bkv = *(const float4*)(Wk + (size_t)(k0 + bk) * N + (c0 + bc));
        As[ak + 0][ar] = av.x;
        As[ak + 1][ar] = av.y;
        As[ak + 2][ar] = av.z;
        As[ak + 3][ar] = av.w;
        *(float4*)&Bq[bk][bc] = bqv;
        *(float4*)&Bk[bk][bc] = bkv;
        __syncthreads();
        #pragma unroll
        for (int kk = 0; kk < 16; ++kk) {
            const float4 a4  = *(const float4*)&As[kk][tm * 4];
            const float4 q4  = *(const float4*)&Bq[kk][tn * 4];
            const float4 k4  = *(const float4*)&Bk[kk][tn * 4];
            const float a[4]  = {a4.x, a4.y, a4.z, a4.w};
            const float bqr[4] = {q4.x, q4.y, q4.z, q4.w};
            const float bkr[4] = {k4.x, k4.y, k4.z, k4.w};
            #pragma unroll
            for (int i = 0; i < 4; ++i)
                #pragma unroll
                for (int j = 0; j < 4; ++j) {
                    paccQ[i][j] = fmaf(a[i], bqr[j], paccQ[i][j]);
                    paccK[i][j] = fmaf(a[i], bkr[j], paccK[i][j]);
                }
        }
        __syncthreads();
        const int kn = k0 + 16;
        if (kn == 384 || kn == 768 || kn == K) {   // OpenBLAS KC=384 panel flush
            #pragma unroll
            for (int i = 0; i < 4; ++i)
                #pragma unroll
                for (int j = 0; j < 4; ++j) {
                    caccQ[i][j] = caccQ[i][j] + paccQ[i][j];
                    paccQ[i][j] = 0.f;
                    caccK[i][j] = caccK[i][j] + paccK[i][j];
                    paccK[i][j] = 0.f;
                }
        }
    }
    #pragma unroll
    for (int i = 0; i < 4; ++i) {
        const int r = r0 + tm * 4 + i;
        const int c = c0 + tn * 4;
        float4 vq;
        vq.x = caccQ[i][0] + bq[c + 0];
        vq.y = caccQ[i][1] + bq[c + 1];
        vq.z = caccQ[i][2] + bq[c + 2];
        vq.w = caccQ[i][3] + bq[c + 3];
        *(float4*)&Cq[(size_t)r * N + c] = vq;
        float4 vk;
        vk.x = caccK[i][0] + bk_[c + 0];
        vk.y = caccK[i][1] + bk_[c + 1];
        vk.z = caccK[i][2] + bk_[c + 2];
        vk.w = caccK[i][3] + bk_[c + 3];
        *(float4*)&Ck[(size_t)r * N + c] = vk;
        ushort4 hs;
        hs.x = h2u((_Float16)vk.x);
        hs.y = h2u((_Float16)vk.y);
        hs.z = h2u((_Float16)vk.z);
        hs.w = h2u((_Float16)vk.w);
        *(ushort4*)&khi[(size_t)r * N + c] = hs;
    }
}

// ---------------------------------------------------------------------------
// Weight prep for hi/lo MFMA GEMM: W (K x N, fp32) -> WT hi/lo (N x K, f16).
// ---------------------------------------------------------------------------
__global__ __launch_bounds__(256)
void conv_wT(const float* __restrict__ W,
             unsigned short* __restrict__ wthi,
             unsigned short* __restrict__ wtlo)
{
    __shared__ float tile[64][68];
    const int t  = threadIdx.x;
    const int k0 = blockIdx.y * 64;
    const int n0 = blockIdx.x * 64;
    const int r  = t >> 4, c4 = (t & 15) * 4;
    #pragma unroll
    for (int i = 0; i < 4; ++i) {
        const int k = r + 16 * i;
        const float4 v = *(const float4*)&W[(size_t)(k0 + k) * cE + n0 + c4];
        tile[k][c4 + 0] = v.x; tile[k][c4 + 1] = v.y;
        tile[k][c4 + 2] = v.z; tile[k][c4 + 3] = v.w;
    }
    __syncthreads();
    #pragma unroll
    for (int i = 0; i < 4; ++i) {
        const int n = r + 16 * i;
        unsigned int hp[2], lp[2];
        #pragma unroll
        for (int p = 0; p < 2; ++p) {
            unsigned short hh[2], ll[2];
            #pragma unroll
            for (int j = 0; j < 2; ++j) {
                const float f = tile[c4 + p * 2 + j][n];
                const _Float16 h = (_Float16)f;
                hh[j] = h2u(h);
                ll[j] = h2u((_Float16)(f - (float)h));
            }
            hp[p] = (unsigned int)hh[0] | ((unsigned int)hh[1] << 16);
            lp[p] = (unsigned int)ll[0] | ((unsigned int)ll[1] << 16);
        }
        uint2 hv, lv;
        hv.x = hp[0]; hv.y = hp[1];
        lv.x = lp[0]; lv.y = lp[1];
        *(uint2*)&wthi[(size_t)(n0 + n) * cE + k0 + c4] = hv;
        *(uint2*)&wtlo[(size_t)(n0 + n) * cE + k0 + c4] = lv;
    }
}

// ---------------------------------------------------------------------------
// f16 hi/lo 3-product MFMA GEMM (fp32-equivalent precision, smooth paths).
// Tile 128x64, BK=16, 4 waves 2x2.
// ---------------------------------------------------------------------------
__global__ __launch_bounds__(256)
void gemm_hilo(const float* __restrict__ A,
               const unsigned short* __restrict__ wthi,
               const unsigned short* __restrict__ wtlo,
               const float* __restrict__ bias,
               float* __restrict__ C)
{
    __shared__ __align__(16) unsigned short Ah[128][24];   // 24 = 16 + 8 pad
    __shared__ __align__(16) unsigned short Al[128][24];
    __shared__ __align__(16) unsigned short Bh[64][24];
    __shared__ __align__(16) unsigned short Bl[64][24];

    const int t    = threadIdx.x;
    const int lane = t & 63, wave = t >> 6;
    const int wr   = wave >> 1, wc = wave & 1;
    const int r0   = blockIdx.y * 128, c0 = blockIdx.x * 64;
    const int fr   = lane & 31, g5 = lane >> 5;

    const int arow = t >> 1, aka = (t & 1) * 8;
    const int bsel = t >> 7;                 // waves 0,1: hi; waves 2,3: lo
    const int brow = (t & 127) >> 1, bkb = (t & 1) * 8;
    const unsigned short* wsrc = bsel ? wtlo : wthi;

    f32x16 acc0 = {0.f,0.f,0.f,0.f,0.f,0.f,0.f,0.f,0.f,0.f,0.f,0.f,0.f,0.f,0.f,0.f};
    f32x16 acc1 = {0.f,0.f,0.f,0.f,0.f,0.f,0.f,0.f,0.f,0.f,0.f,0.f,0.f,0.f,0.f,0.f};

    for (int k0 = 0; k0 < cE; k0 += 16) {
        const float4 x0 = *(const float4*)&A[(size_t)(r0 + arow) * cE + k0 + aka];
        const float4 x1 = *(const float4*)&A[(size_t)(r0 + arow) * cE + k0 + aka + 4];
        const float xf[8] = {x0.x, x0.y, x0.z, x0.w, x1.x, x1.y, x1.z, x1.w};
        unsigned int hw[4], lw[4];
        #pragma unroll
        for (int p = 0; p < 4; ++p) {
            unsigned short hh[2], ll[2];
            #pragma unroll
            for (int j = 0; j < 2; ++j) {
                const float f = xf[p * 2 + j];
                const _Float16 h = (_Float16)f;
                hh[j] = h2u(h);
                ll[j] = h2u((_Float16)(f - (float)h));
            }
            hw[p] = (unsigned int)hh[0] | ((unsigned int)hh[1] << 16);
            lw[p] = (unsigned int)ll[0] | ((unsigned int)ll[1] << 16);
        }
        uint4 hv, lv;
        hv.x = hw[0]; hv.y = hw[1]; hv.z = hw[2]; hv.w = hw[3];
        lv.x = lw[0]; lv.y = lw[1]; lv.z = lw[2]; lv.w = lw[3];
        *(uint4*)&Ah[arow][aka] = hv;
        *(uint4*)&Al[arow][aka] = lv;

        const uint4 wv = *(const uint4*)&wsrc[(size_t)(c0 + brow) * cE + k0 + bkb];
        if (bsel) *(uint4*)&Bl[brow][bkb] = wv;
        else      *(uint4*)&Bh[brow][bkb] = wv;
        __syncthreads();

        const half8 a0h = ld_half8(&Ah[wr * 64 + fr][g5 * 8]);
        const half8 a0l = ld_half8(&Al[wr * 64 + fr][g5 * 8]);
        const half8 a1h = ld_half8(&Ah[wr * 64 + 32 + fr][g5 * 8]);
        const half8 a1l = ld_half8(&Al[wr * 64 + 32 + fr][g5 * 8]);
        const half8 bh  = ld_half8(&Bh[wc * 32 + fr][g5 * 8]);
        const half8 bl  = ld_half8(&Bl[wc * 32 + fr][g5 * 8]);

        acc0 = __builtin_amdgcn_mfma_f32_32x32x16_f16(a0l, bh, acc0, 0, 0, 0);
        acc0 = __builtin_amdgcn_mfma_f32_32x32x16_f16(a0h, bl, acc0, 0, 0, 0);
        acc0 = __builtin_amdgcn_mfma_f32_32x32x16_f16(a0h, bh, acc0, 0, 0, 0);
        acc1 = __builtin_amdgcn_mfma_f32_32x32x16_f16(a1l, bh, acc1, 0, 0, 0);
        acc1 = __builtin_amdgcn_mfma_f32_32x32x16_f16(a1h, bl, acc1, 0, 0, 0);
        acc1 = __builtin_amdgcn_mfma_f32_32x32x16_f16(a1h, bh, acc1, 0, 0, 0);
        __syncthreads();
    }

    const int col = c0 + wc * 32 + fr;
    const float bv = bias ? bias[col] : 0.f;
    #pragma unroll
    for (int rg = 0; rg < 16; ++rg) {
        const int row = r0 + wr * 64 + (rg & 3) + 8 * (rg >> 2) + 4 * g5;
        C[(size_t)row * cE + col] = acc0[rg] + bv;
    }
    #pragma unroll
    for (int rg = 0; rg < 16; ++rg) {
        const int row = r0 + wr * 64 + 32 + (rg & 3) + 8 * (rg >> 2) + 4 * g5;
        C[(size_t)row * cE + col] = acc1[rg] + bv;
    }
}

// ---------------------------------------------------------------------------
// Fused output GEMM, hi/lo MFMA: out = gs*As@Wos + gp*Ap@Wop + gated bias.
// ---------------------------------------------------------------------------
__global__ __launch_bounds__(256)
void out_gemm_hilo(const float* __restrict__ As_, const float* __restrict__ Ap_,
                   const unsigned short* __restrict__ w1hi,
                   const unsigned short* __restrict__ w1lo,
                   const unsigned short* __restrict__ w2hi,
                   const unsigned short* __restrict__ w2lo,
                   const float* __restrict__ bos, const float* __restrict__ bop,
                   const float* __restrict__ gates, float* __restrict__ out)
{
    __shared__ __align__(16) unsigned short A1h[128][24], A1l[128][24];
    __shared__ __align__(16) unsigned short A2h[128][24], A2l[128][24];
    __shared__ __align__(16) unsigned short B1h[64][24],  B1l[64][24];
    __shared__ __align__(16) unsigned short B2h[64][24],  B2l[64][24];

    const int t    = threadIdx.x;
    const int lane = t & 63, wave = t >> 6;
    const int wr   = wave >> 1, wc = wave & 1;
    const int r0   = blockIdx.y * 128, c0 = blockIdx.x * 64;
    const int fr   = lane & 31, g5 = lane >> 5;
    const int b    = r0 >> 11;
    const float gs = gates[b * 2 + 0], gp = gates[b * 2 + 1];

    const int arow = t >> 1, aka = (t & 1) * 8;
    const int bsel = t >> 7;
    const int brow = (t & 127) >> 1, bkb = (t & 1) * 8;
    const unsigned short* s1 = bsel ? w1lo : w1hi;
    const unsigned short* s2 = bsel ? w2lo : w2hi;

    f32x16 acc0 = {0.f,0.f,0.f,0.f,0.f,0.f,0.f,0.f,0.f,0.f,0.f,0.f,0.f,0.f,0.f,0.f};
    f32x16 acc1 = {0.f,0.f,0.f,0.f,0.f,0.f,0.f,0.f,0.f,0.f,0.f,0.f,0.f,0.f,0.f,0.f};

    for (int k0 = 0; k0 < cE; k0 += 16) {
        {
            const float4 x0 = *(const float4*)&As_[(size_t)(r0 + arow) * cE + k0 + aka];
            const float4 x1 = *(const float4*)&As_[(size_t)(r0 + arow) * cE + k0 + aka + 4];
            const float xf[8] = {x0.x * gs, x0.y * gs, x0.z * gs, x0.w * gs,
                                 x1.x * gs, x1.y * gs, x1.z * gs, x1.w * gs};
            unsigned int hw[4], lw[4];
            #pragma unroll
            for (int p = 0; p < 4; ++p) {
                unsigned short hh[2], ll[2];
                #pragma unroll
                for (int j = 0; j < 2; ++j) {
                    const float f = xf[p * 2 + j];
                    const _Float16 h = (_Float16)f;
                    hh[j] = h2u(h);
                    ll[j] = h2u((_Float16)(f - (float)h));
                }
                hw[p] = (unsigned int)hh[0] | ((unsigned int)hh[1] << 16);
                lw[p] = (unsigned int)ll[0] | ((unsigned int)ll[1] << 16);
            }
            uint4 hv, lv;
            hv.x = hw[0]; hv.y = hw[1]; hv.z = hw[2]; hv.w = hw[3];
            lv.x = lw[0]; lv.y = lw[1]; lv.z = lw[2]; lv.w = lw[3];
            *(uint4*)&A1h[arow][aka] = hv;
            *(uint4*)&A1l[arow][aka] = lv;
        }
        {
            const float4 x0 = *(const float4*)&Ap_[(size_t)(r0 + arow) * cE + k0 + aka];
            const float4 x1 = *(const float4*)&Ap_[(size_t)(r0 + arow) * cE + k0 + aka + 4];
            const float xf[8] = {x0.x * gp, x0.y * gp, x0.z * gp, x0.w * gp,
                                 x1.x * gp, x1.y * gp, x1.z * gp, x1.w * gp};
            unsigned int hw[4], lw[4];
            #pragma unroll
            for (int p = 0; p < 4; ++p) {
                unsigned short hh[2], ll[2];
                #pragma unroll
                for (int j = 0; j < 2; ++j) {
                    const float f = xf[p * 2 + j];
                    const _Float16 h = (_Float16)f;
                    hh[j] = h2u(h);
                    ll[j] = h2u((_Float16)(f - (float)h));
                }
                hw[p] = (unsigned int)hh[0] | ((unsigned int)hh[1] << 16);
                lw[p] = (unsigned int)ll[0] | ((unsigned int)ll[1] << 16);
            }
            uint4 hv, lv;
            hv.x = hw[0]; hv.y = hw[1]; hv.z = hw[2]; hv.w = hw[3];
            lv.x = lw[0]; lv.y = lw[1]; lv.z = lw[2]; lv.w = lw[3];
            *(uint4*)&A2h[arow][aka] = hv;
            *(uint4*)&A2l[arow][aka] = lv;
        }
        {
            const uint4 w1 = *(const uint4*)&s1[(size_t)(c0 + brow) * cE + k0 + bkb];
            if (bsel) *(uint4*)&B1l[brow][bkb] = w1;
            else      *(uint4*)&B1h[brow][bkb] = w1;
            const uint4 w2 = *(const uint4*)&s2[(size_t)(c0 + brow) * cE + k0 + bkb];
            if (bsel) *(uint4*)&B2l[brow][bkb] = w2;
            else      *(uint4*)&B2h[brow][bkb] = w2;
        }
        __syncthreads();

        const half8 b1h = ld_half8(&B1h[wc * 32 + fr][g5 * 8]);
        const half8 b1l = ld_half8(&B1l[wc * 32 + fr][g5 * 8]);
        const half8 b2h = ld_half8(&B2h[wc * 32 + fr][g5 * 8]);
        const half8 b2l = ld_half8(&B2l[wc * 32 + fr][g5 * 8]);
        {
            const half8 a1h = ld_half8(&A1h[wr * 64 + fr][g5 * 8]);
            const half8 a1l = ld_half8(&A1l[wr * 64 + fr][g5 * 8]);
            const half8 a2h = ld_half8(&A2h[wr * 64 + fr][g5 * 8]);
            const half8 a2l = ld_half8(&A2l[wr * 64 + fr][g5 * 8]);
            acc0 = __builtin_amdgcn_mfma_f32_32x32x16_f16(a1l, b1h, acc0, 0, 0, 0);
            acc0 = __builtin_amdgcn_mfma_f32_32x32x16_f16(a1h, b1l, acc0, 0, 0, 0);
            acc0 = __builtin_amdgcn_mfma_f32_32x32x16_f16(a1h, b1h, acc0, 0, 0, 0);
            acc0 = __builtin_amdgcn_mfma_f32_32x32x16_f16(a2l, b2h, acc0, 0, 0, 0);
            acc0 = __builtin_amdgcn_mfma_f32_32x32x16_f16(a2h, b2l, acc0, 0, 0, 0);
            acc0 = __builtin_amdgcn_mfma_f32_32x32x16_f16(a2h, b2h, acc0, 0, 0, 0);
        }
        {
            const half8 a1h = ld_half8(&A1h[wr * 64 + 32 + fr][g5 * 8]);
            const half8 a1l = ld_half8(&A1l[wr * 64 + 32 + fr][g5 * 8]);
            const half8 a2h = ld_half8(&A2h[wr * 64 + 32 + fr][g5 * 8]);
            const half8 a2l = ld_half8(&A2l[wr * 64 + 32 + fr][g5 * 8]);
            acc1 = __builtin_amdgcn_mfma_f32_32x32x16_f16(a1l, b1h, acc1, 0, 0, 0);
            acc1 = __builtin_amdgcn_mfma_f32_32x32x16_f16(a1h, b1l, acc1, 0, 0, 0);
            acc1 = __builtin_amdgcn_mfma_f32_32x32x16_f16(a1h, b1h, acc1, 0, 0, 0);
            acc1 = __builtin_amdgcn_mfma_f32_32x32x16_f16(a2l, b2h, acc1, 0, 0, 0);
            acc1 = __builtin_amdgcn_mfma_f32_32x32x16_f16(a2h, b2l, acc1, 0, 0, 0);
            acc1 = __builtin_amdgcn_mfma_f32_32x32x16_f16(a2h, b2h, acc1, 0, 0, 0);
        }
        __syncthreads();
    }

    const int col = c0 + wc * 32 + fr;
    const float bv = gs * bos[col] + gp * bop[col];
    #pragma unroll
    for (int rg = 0; rg < 16; ++rg) {
        const int row = r0 + wr * 64 + (rg & 3) + 8 * (rg >> 2) + 4 * g5;
        out[(size_t)row * cE + col] = acc0[rg] + bv;
    }
    #pragma unroll
    for (int rg = 0; rg < 16; ++rg) {
        const int row = r0 + wr * 64 + 32 + (rg & 3) + 8 * (rg >> 2) + 4 * g5;
        out[(size_t)row * cE + col] = acc1[rg] + bv;
    }
}

// ---------------------------------------------------------------------------
// Sparse selection, QBLK=16: 16 valid MFMA rows (regs 0..7 of the 32x32
// C-layout cover rows 0..15). Radix select + candidate scan to global.
// ---------------------------------------------------------------------------
__global__ __launch_bounds__(256, 4)
void sparse_sel(const float* __restrict__ Q,
                const unsigned short* __restrict__ Khi,
                unsigned short* __restrict__ gcidx,
                int* __restrict__ gcnt)
{
    __shared__ __align__(16) unsigned short Qhi[16][72];  // 2.25 KB
    __shared__ unsigned int hist[16][257];                // 16.4 KB
    __shared__ int cnt[16];
    __shared__ int t16hi[16], rem[16], t16[16];

    const int t   = threadIdx.x;
    const int bh  = blockIdx.y;
    const int b   = bh >> 4;
    const int h64 = (bh & 15) * 64;
    const int q0  = blockIdx.x * 16;
    const size_t rid0 = (size_t)bh * 2048 + q0;           // linear row id base

    {
        const int r = t >> 4, c4 = (t & 15) * 4;
        const float4 v =
            *(const float4*)&Q[((size_t)(b * cS + q0 + r)) * cE + h64 + c4];
        const float f[4] = {v.x, v.y, v.z, v.w};
        #pragma unroll
        for (int i = 0; i < 4; ++i)
            Qhi[r][c4 + i] = h2u((_Float16)f[i]);
    }
    for (int i = t; i < 16 * 257; i += 256) (&hist[0][0])[i] = 0u;
    if (t < 16) cnt[t] = 0;
    __syncthreads();                                               // B1

    const int lane = t & 63;
    const int wv   = t >> 6;
    const int col  = lane & 31;
    const int g5   = lane >> 5;
    const int base0 = 4 * g5;          // rows from acc regs 0..3
    const int base1 = 8 + 4 * g5;      // rows from acc regs 4..7

    // ---- phase A: single-product f16 MFMA scores, keys wv*512 .. +512 ----
    half8 ahi[4];
    {
        const int arow = col & 15;     // 16 valid Q rows (dup x2 over 32)
        #pragma unroll
        for (int ks = 0; ks < 4; ++ks)
            ahi[ks] = ld_half8(&Qhi[arow][g5 * 8 + ks * 16]);
    }
    unsigned int su[16][4];            // u16 keys, 8 rows x 16 tiles
    {
        const size_t kbase = ((size_t)(b * cS + wv * 512 + col)) * cE + h64;
        #pragma unroll
        for (int tl = 0; tl < 16; ++tl) {
            const unsigned short* kh = Khi + kbase + (size_t)tl * 32 * cE;
            f32x16 acc = {0.f,0.f,0.f,0.f,0.f,0.f,0.f,0.f,
                          0.f,0.f,0.f,0.f,0.f,0.f,0.f,0.f};
            #pragma unroll
            for (int ks = 0; ks < 4; ++ks) {
                const half8 bh8 = ld_half8(kh + g5 * 8 + ks * 16);
                acc = __builtin_amdgcn_mfma_f32_32x32x16_f16(ahi[ks], bh8, acc, 0, 0, 0);
            }
            unsigned int k[8];
            #pragma unroll
            for (int r = 0; r < 8; ++r)
                k[r] = f2key(acc[r] * 0.125f) >> 16;
            su[tl][0] = k[0] | (k[1] << 16);
            su[tl][1] = k[2] | (k[3] << 16);
            su[tl][2] = k[4] | (k[5] << 16);
            su[tl][3] = k[6] | (k[7] << 16);
            atomicAdd(&hist[base0 + 0][k[0] >> 8], 1u);
            atomicAdd(&hist[base0 + 1][k[1] >> 8], 1u);
            atomicAdd(&hist[base0 + 2][k[2] >> 8], 1u);
            atomicAdd(&hist[base0 + 3][k[3] >> 8], 1u);
            atomicAdd(&hist[base1 + 0][k[4] >> 8], 1u);
            atomicAdd(&hist[base1 + 1][k[5] >> 8], 1u);
            atomicAdd(&hist[base1 + 2][k[6] >> 8], 1u);
            atomicAdd(&hist[base1 + 3][k[7] >> 8], 1u);
        }
    }
    __syncthreads();                                               // B2
    if (t < 16) {
        int need = cKTOP + 1;   // 65
        int hb = 0;
        for (int bin = 255; bin >= 0; --bin) {
            const int c = (int)hist[t][bin];
            if (c >= need) { hb = bin; break; }
            need -= c;
        }
        t16hi[t] = hb;
        rem[t] = need;
    }
    __syncthreads();                                               // B3
    for (int i = t; i < 16 * 257; i += 256) (&hist[0][0])[i] = 0u;  // pass 2
    __syncthreads();                                               // B3b
    #pragma unroll
    for (int tl = 0; tl < 16; ++tl)
        #pragma unroll
        for (int w = 0; w < 4; ++w) {
            const unsigned int u = su[tl][w];
            const int rlo = (w < 2 ? base0 : base1) + (w & 1) * 2;
            const int rhi = rlo + 1;
            const unsigned int vlo = u & 0xFFFFu;
            const unsigned int vhi = u >> 16;
            if ((int)(vlo >> 8) == t16hi[rlo]) atomicAdd(&hist[rlo][vlo & 255u], 1u);
            if ((int)(vhi >> 8) == t16hi[rhi]) atomicAdd(&hist[rhi][vhi & 255u], 1u);
        }
    __syncthreads();                                               // B4
    if (t < 16) {
        int need = rem[t];
        int lb = 0;
        for (int bin = 255; bin >= 0; --bin) {
            const int c = (int)hist[t][bin];
            if (c >= need) { lb = bin; break; }
            need -= c;
        }
        t16[t] = (t16hi[t] << 8) | lb;
    }
    __syncthreads();                                               // B5

    // ---- candidate scan: u16 >= T16 - 3; write straight to global ----
    #pragma unroll
    for (int tl = 0; tl < 16; ++tl) {
        const int key = wv * 512 + tl * 32 + col;
        #pragma unroll
        for (int w = 0; w < 4; ++w) {
            const unsigned int u = su[tl][w];
            const int rlo = (w < 2 ? base0 : base1) + (w & 1) * 2;
            const int rhi = rlo + 1;
            const int v0 = (int)(u & 0xFFFFu);
            const int v1 = (int)(u >> 16);
            if (v0 >= max(t16[rlo] - 3, 0)) {
                const int slot = atomicAdd(&cnt[rlo], 1);
                if (slot < 128) gcidx[(rid0 + rlo) * 128 + slot] = (unsigned short)key;
            }
            if (v1 >= max(t16[rhi] - 3, 0)) {
                const int slot = atomicAdd(&cnt[rhi], 1);
                if (slot < 128) gcidx[(rid0 + rhi) * 128 + slot] = (unsigned short)key;
            }
        }
    }
    __syncthreads();                                               // B6
    if (t < 16) gcnt[rid0 + t] = cnt[t];
}

// ---------------------------------------------------------------------------
// Sparse attention (phases C/D): fp64 recompute, ranking, hedge weights,
// unroll-8 PV gather. __launch_bounds__(256,8) => 8 blocks/CU.
// ---------------------------------------------------------------------------
__global__ __launch_bounds__(256, 8)
void sparse_att(const float* __restrict__ Q,
                const unsigned short* __restrict__ gcidx,
                const int* __restrict__ gcnt,
                const float* __restrict__ Ks, const float* __restrict__ V,
                float* __restrict__ O)
{
    __shared__ float QfT[64][8];                 // 2 KB  (Q transposed)
    __shared__ unsigned short cidx[8][128];      // 2 KB
    __shared__ double cval[8][128];              // 8 KB
    __shared__ float cw[8][128];                 // 4 KB
    __shared__ int cnt[8];
    __shared__ double T64s[8], s65s[8], rowm[8];

    const int t   = threadIdx.x;
    const int bh  = blockIdx.y;
    const int b   = bh >> 4;
    const int h64 = (bh & 15) * 64;
    const int q0  = blockIdx.x * 8;
    const size_t rid0 = ((size_t)bh * 256 + blockIdx.x) * 8;

    if (t < 128) {
        const int r = t >> 4, c4 = (t & 15) * 4;
        const float4 v =
            *(const float4*)&Q[((size_t)(b * cS + q0 + r)) * cE + h64 + c4];
        QfT[c4 + 0][r] = v.x; QfT[c4 + 1][r] = v.y;
        QfT[c4 + 2][r] = v.z; QfT[c4 + 3][r] = v.w;
    }
    // 8 rows x 128 u16 are contiguous in gcidx -> one ushort4 per thread
    ((ushort4*)&cidx[0][0])[t] = ((const ushort4*)&gcidx[rid0 * 128])[t];
    if (t < 8) cnt[t] = gcnt[rid0 + t];
    __syncthreads();                                               // B6'

    const int wv = t >> 6, lane = t & 63;

    // ---- phase C: fp64 recompute, lane = candidate (2 rows per wave) ----
    #pragma unroll
    for (int rx = 0; rx < 2; ++rx) {
        const int rr = wv * 2 + rx;
        const int n = min(cnt[rr], 128);
        for (int c = lane; c < n; c += 64) {
            const int key = cidx[rr][c];
            const float* kp = Ks + ((size_t)(b * cS + key)) * cE + h64;
            double a = 0.0;
            #pragma unroll 4
            for (int d4 = 0; d4 < 64; d4 += 4) {
                const float4 kv = *(const float4*)&kp[d4];
                a = fma((double)QfT[d4 + 0][rr], (double)kv.x, a);
                a = fma((double)QfT[d4 + 1][rr], (double)kv.y, a);
                a = fma((double)QfT[d4 + 2][rr], (double)kv.z, a);
                a = fma((double)QfT[d4 + 3][rr], (double)kv.w, a);
            }
            cval[rr][c] = a * 0.125;
        }
    }
    __syncthreads();                                               // B7

    // ---- ranking: T64 (rank 63), s65 (rank 64), m (rank 0) ----
    #pragma unroll
    for (int rx = 0; rx < 2; ++rx) {
        const int rr = wv * 2 + rx;
        const int n = min(cnt[rr], 128);
        for (int c = lane; c < n; c += 64) {
            const double v = cval[rr][c];
            int rank = 0;
            for (int i = 0; i < n; ++i) rank += (cval[rr][i] > v) ? 1 : 0;
            if (rank == 0)  rowm[rr] = v;
            if (rank == 63) T64s[rr] = v;
            if (rank == 64) s65s[rr] = v;
        }
    }
    __syncthreads();                                               // B8

    // ---- weights: hedge formula (unchanged) ----
    #pragma unroll
    for (int rx = 0; rx < 2; ++rx) {
        const int rr = wv * 2 + rx;
        const int n = min(cnt[rr], 128);
        const double T64 = T64s[rr], s65 = s65s[rr], m = rowm[rr];
        float za = 0.f;
        for (int c = lane; c < n; c += 64) {
            const double v = cval[rr][c];
            if (v >= T64) za += expf((float)(v - m));
        }
        #pragma unroll
        for (int off = 32; off >= 1; off >>= 1)
            za += __shfl_xor(za, off);
        const float g   = (float)(T64 - s65);
        const float gm  = fmaxf(g - 5e-7f, 0.f);
        const float wB  = 0.5f * erfcf(gm * (1.0f / 2.2e-6f));
        const float wA  = 1.f - wB;
        const float e64 = expf((float)(T64 - m));
        const float e65 = expf((float)(s65 - m));
        const float ZB  = za - e64 + e65;
        const float cIn = wA / za + wB / ZB;
        const float c64 = wA / za;
        const float c65 = wB / ZB;
        for (int c = lane; c < n; c += 64) {
            const double v = cval[rr][c];
            float cc = 0.f;
            if (v > T64)       cc = cIn;
            else if (v == T64) cc = c64;
            else if (v == s65) cc = c65;
            cw[rr][c] = (cc != 0.f) ? cc * expf((float)(v - m)) : 0.f;
        }
    }
    __syncthreads();                                               // B9

    // ---- phase D: sparse PV gather, unroll-8 pipelined (same sum order) ----
    #pragma unroll
    for (int rx = 0; rx < 2; ++rx) {
        const int rr = wv * 2 + rx;
        const int n = min(cnt[rr], 128);
        float o = 0.f;
        int j = 0;
        for (; j + 8 <= n; j += 8) {
            float wreg[8];
            int   kreg[8];
            #pragma unroll
            for (int u = 0; u < 8; ++u) {
                wreg[u] = cw[rr][j + u];
                kreg[u] = cidx[rr][j + u];
            }
            float vreg[8];
            #pragma unroll
            for (int u = 0; u < 8; ++u)
                vreg[u] = V[((size_t)(b * cS + kreg[u])) * cE + h64 + lane];
            #pragma unroll
            for (int u = 0; u < 8; ++u)
                o = fmaf(wreg[u], vreg[u], o);
        }
        for (; j < n; ++j)
            o = fmaf(cw[rr][j],
                     V[((size_t)(b * cS + cidx[rr][j])) * cE + h64 + lane], o);
        O[((size_t)(b * cS + q0 + rr)) * cE + h64 + lane] = o;
    }
}

// ---------------------------------------------------------------------------
// Performer kv (unchanged)
// ---------------------------------------------------------------------------
__global__ __launch_bounds__(256)
void perf_kv(const float* __restrict__ Kp, const float* __restrict__ Vp,
             const float* __restrict__ Wfeat,
             float* __restrict__ kvpart, float* __restrict__ zpart)
{
    __shared__ __align__(16) float Wf[64][68];
    __shared__ __align__(16) float Kt[64][68];
    __shared__ __align__(16) float Vt[64][68];
    __shared__ __align__(16) float Ph[64][68];
    const int t    = threadIdx.x;
    const int mc   = blockIdx.x & 3;
    const int sc   = blockIdx.x >> 2;          // 0 or 1
    const int bh   = blockIdx.y;
    const int b    = bh >> 4;
    const int h64  = (bh & 15) * 64;
    const int m0   = mc * 64;
    const int sbase = sc * 1024;

    #pragma unroll
    for (int i = 0; i < 4; ++i) {
        const int lin = t + 256 * i;
        const int d   = lin >> 4;
        const int m4  = (lin & 15) * 4;
        *(float4*)&Wf[d][m4] = *(const float4*)&Wfeat[d * cM + m0 + m4];
    }

    const int tm = t >> 4, tn = t & 15;
    const int sr = tm * 4;
    const int cn = tn * 4;
    float akv[4][4] = {};
    float az = 0.f;

    for (int st = 0; st < 16; ++st) {
        const int s0g = sbase + st * 64;
        __syncthreads();
        #pragma unroll
        for (int i = 0; i < 4; ++i) {
            const int row = tm + 16 * i;
            const size_t base = ((size_t)(b * cS + s0g + row)) * cE + h64 + cn;
            *(float4*)&Kt[row][cn] = *(const float4*)&Kp[base];
            *(float4*)&Vt[row][cn] = *(const float4*)&Vp[base];
        }
        __syncthreads();
        float4 p0 = {0,0,0,0}, p1 = {0,0,0,0}, p2 = {0,0,0,0}, p3 = {0,0,0,0};
        #pragma unroll 8
        for (int d = 0; d < 64; ++d) {
            const float4 wv = *(const float4*)&Wf[d][cn];
            const float k0 = Kt[sr + 0][d], k1 = Kt[sr + 1][d];
            const float k2 = Kt[sr + 2][d], k3 = Kt[sr + 3][d];
            p0.x = fmaf(k0, wv.x, p0.x); p0.y = fmaf(k0, wv.y, p0.y);
            p0.z = fmaf(k0, wv.z, p0.z); p0.w = fmaf(k0, wv.w, p0.w);
            p1.x = fmaf(k1, wv.x, p1.x); p1.y = fmaf(k1, wv.y, p1.y);
            p1.z = fmaf(k1, wv.z, p1.z); p1.w = fmaf(k1, wv.w, p1.w);
            p2.x = fmaf(k2, wv.x, p2.x); p2.y = fmaf(k2, wv.y, p2.y);
            p2.z = fmaf(k2, wv.z, p2.z); p2.w = fmaf(k2, wv.w, p2.w);
            p3.x = fmaf(k3, wv.x, p3.x); p3.y = fmaf(k3, wv.y, p3.y);
            p3.z = fmaf(k3, wv.z, p3.z); p3.w = fmaf(k3, wv.w, p3.w);
        }
        p0.x = fmaxf(p0.x, 0.f) + cEPS; p0.y = fmaxf(p0.y, 0.f) + cEPS;
        p0.z = fmaxf(p0.z, 0.f) + cEPS; p0.w = fmaxf(p0.w, 0.f) + cEPS;
        p1.x = fmaxf(p1.x, 0.f) + cEPS; p1.y = fmaxf(p1.y, 0.f) + cEPS;
        p1.z = fmaxf(p1.z, 0.f) + cEPS; p1.w = fmaxf(p1.w, 0.f) + cEPS;
        p2.x = fmaxf(p2.x, 0.f) + cEPS; p2.y = fmaxf(p2.y, 0.f) + cEPS;
        p2.z = fmaxf(p2.z, 0.f) + cEPS; p2.w = fmaxf(p2.w, 0.f) + cEPS;
        p3.x = fmaxf(p3.x, 0.f) + cEPS; p3.y = fmaxf(p3.y, 0.f) + cEPS;
        p3.z = fmaxf(p3.z, 0.f) + cEPS; p3.w = fmaxf(p3.w, 0.f) + cEPS;
        *(float4*)&Ph[sr + 0][cn] = p0;
        *(float4*)&Ph[sr + 1][cn] = p1;
        *(float4*)&Ph[sr + 2][cn] = p2;
        *(float4*)&Ph[sr + 3][cn] = p3;
        __syncthreads();
        #pragma unroll 8
        for (int ss = 0; ss < 64; ++ss) {
            const float4 pv = *(const float4*)&Ph[ss][sr];
            const float4 vv = *(const float4*)&Vt[ss][cn];
            akv[0][0] = fmaf(pv.x, vv.x, akv[0][0]); akv[0][1] = fmaf(pv.x, vv.y, akv[0][1]);
            akv[0][2] = fmaf(pv.x, vv.z, akv[0][2]); akv[0][3] = fmaf(pv.x, vv.w, akv[0][3]);
            akv[1][0] = fmaf(pv.y, vv.x, akv[1][0]); akv[1][1] = fmaf(pv.y, vv.y, akv[1][1]);
            akv[1][2] = fmaf(pv.y, vv.z, akv[1][2]); akv[1][3] = fmaf(pv.y, vv.w, akv[1][3]);
            akv[2][0] = fmaf(pv.z, vv.x, akv[2][0]); akv[2][1] = fmaf(pv.z, vv.y, akv[2][1]);
            akv[2][2] = fmaf(pv.z, vv.z, akv[2][2]); akv[2][3] = fmaf(pv.z, vv.w, akv[2][3]);
            akv[3][0] = fmaf(pv.w, vv.x, akv[3][0]); akv[3][1] = fmaf(pv.w, vv.y, akv[3][1]);
            akv[3][2] = fmaf(pv.w, vv.z, akv[3][2]); akv[3][3] = fmaf(pv.w, vv.w, akv[3][3]);
        }
        if (t < 64) {
            float a = 0.f;
            #pragma unroll 8
            for (int ss = 0; ss < 64; ++ss) a += Ph[ss][t];
            az += a;
        }
    }
    const size_t obase = ((size_t)(sc * 32 + bh)) * cM + m0;
    #pragma unroll
    for (int i = 0; i < 4; ++i) {
        float4 v; v.x = akv[i][0]; v.y = akv[i][1]; v.z = akv[i][2]; v.w = akv[i][3];
        *(float4*)&kvpart[(obase + sr + i) * cD + cn] = v;
    }
    if (t < 64) zpart[obase + t] = az;
}

// ---------------------------------------------------------------------------
// Performer num/den (unchanged)
// ---------------------------------------------------------------------------
__global__ __launch_bounds__(256)
void perf_numden(const float* __restrict__ Qp, const float* __restrict__ Wfeat,
                 const float* __restrict__ kvpart, const float* __restrict__ zpart,
                 float* __restrict__ Ap)
{
    __shared__ __align__(16) float Wf[64][68];
    __shared__ __align__(16) float Qt[64][68];
    __shared__ __align__(16) float KV[64][68];
    __shared__ __align__(16) float Ph[64][68];
    __shared__ __align__(16) float zl[64];
    __shared__ float den[64];
    const int t   = threadIdx.x;
    const int stb = blockIdx.x;
    const int bh  = blockIdx.y;
    const int b   = bh >> 4;
    const int h64 = (bh & 15) * 64;
    const int s0  = stb * 64;
    const int tm  = t >> 4, tn = t & 15;
    const int sr  = tm * 4, cn = tn * 4;

    #pragma unroll
    for (int i = 0; i < 4; ++i) {
        const int row = tm + 16 * i;
        *(float4*)&Qt[row][cn] =
            *(const float4*)&Qp[((size_t)(b * cS + s0 + row)) * cE + h64 + cn];
    }

    float num[4][4] = {};
    float dacc = 0.f;

    for (int mc = 0; mc < 4; ++mc) {
        const int m0 = mc * 64;
        __syncthreads();
        #pragma unroll
        for (int i = 0; i < 4; ++i) {
            const int lin = t + 256 * i;
            const int d   = lin >> 4;
            const int m4  = (lin & 15) * 4;
            *(float4*)&Wf[d][m4] = *(const float4*)&Wfeat[d * cM + m0 + m4];
        }
        #pragma unroll
        for (int i = 0; i < 4; ++i) {
            const int row = tm + 16 * i;
            const size_t o0 = ((size_t)bh * cM + m0 + row) * cD + cn;
            const size_t o1 = ((size_t)(32 + bh) * cM + m0 + row) * cD + cn;
            const float4 a = *(const float4*)&kvpart[o0];
            const float4 c = *(const float4*)&kvpart[o1];
            float4 v; v.x = a.x + c.x; v.y = a.y + c.y; v.z = a.z + c.z; v.w = a.w + c.w;
            *(float4*)&KV[row][cn] = v;
        }
        if (t < 64)
            zl[t] = zpart[(size_t)bh * cM + m0 + t] + zpart[(size_t)(32 + bh) * cM + m0 + t];
        __syncthreads();
        float4 p0 = {0,0,0,0}, p1 = {0,0,0,0}, p2 = {0,0,0,0}, p3 = {0,0,0,0};
        #pragma unroll 8
        for (int d = 0; d < 64; ++d) {
            const float4 wv = *(const float4*)&Wf[d][cn];
            const float q0 = Qt[sr + 0][d], q1 = Qt[sr + 1][d];
            const float q2 = Qt[sr + 2][d], q3 = Qt[sr + 3][d];
            p0.x = fmaf(q0, wv.x, p0.x); p0.y = fmaf(q0, wv.y, p0.y);
            p0.z = fmaf(q0, wv.z, p0.z); p0.w = fmaf(q0, wv.w, p0.w);
            p1.x = fmaf(q1, wv.x, p1.x); p1.y = fmaf(q1, wv.y, p1.y);
            p1.z = fmaf(q1, wv.z, p1.z); p1.w = fmaf(q1, wv.w, p1.w);
            p2.x = fmaf(q2, wv.x, p2.x); p2.y = fmaf(q2, wv.y, p2.y);
            p2.z = fmaf(q2, wv.z, p2.z); p2.w = fmaf(q2, wv.w, p2.w);
            p3.x = fmaf(q3, wv.x, p3.x); p3.y = fmaf(q3, wv.y, p3.y);
            p3.z = fmaf(q3, wv.z, p3.z); p3.w = fmaf(q3, wv.w, p3.w);
        }
        p0.x = fmaxf(p0.x, 0.f) + cEPS; p0.y = fmaxf(p0.y, 0.f) + cEPS;
        p0.z = fmaxf(p0.z, 0.f) + cEPS; p0.w = fmaxf(p0.w, 0.f) + cEPS;
        p1.x = fmaxf(p1.x, 0.f) + cEPS; p1.y = fmaxf(p1.y, 0.f) + cEPS;
        p1.z = fmaxf(p1.z, 0.f) + cEPS; p1.w = fmaxf(p1.w, 0.f) + cEPS;
        p2.x = fmaxf(p2.x, 0.f) + cEPS; p2.y = fmaxf(p2.y, 0.f) + cEPS;
        p2.z = fmaxf(p2.z, 0.f) + cEPS; p2.w = fmaxf(p2.w, 0.f) + cEPS;
        p3.x = fmaxf(p3.x, 0.f) + cEPS; p3.y = fmaxf(p3.y, 0.f) + cEPS;
        p3.z = fmaxf(p3.z, 0.f) + cEPS; p3.w = fmaxf(p3.w, 0.f) + cEPS;
        *(float4*)&Ph[sr + 0][cn] = p0;
        *(float4*)&Ph[sr + 1][cn] = p1;
        *(float4*)&Ph[sr + 2][cn] = p2;
        *(float4*)&Ph[sr + 3][cn] = p3;
        __syncthreads();
        #pragma unroll 8
        for (int mm = 0; mm < 64; ++mm) {
            const float4 kvv = *(const float4*)&KV[mm][cn];
            const float a0 = Ph[sr + 0][mm], a1 = Ph[sr + 1][mm];
            const float a2 = Ph[sr + 2][mm], a3 = Ph[sr + 3][mm];
            num[0][0] = fmaf(a0, kvv.x, num[0][0]); num[0][1] = fmaf(a0, kvv.y, num[0][1]);
            num[0][2] = fmaf(a0, kvv.z, num[0][2]); num[0][3] = fmaf(a0, kvv.w, num[0][3]);
            num[1][0] = fmaf(a1, kvv.x, num[1][0]); num[1][1] = fmaf(a1, kvv.y, num[1][1]);
            num[1][2] = fmaf(a1, kvv.z, num[1][2]); num[1][3] = fmaf(a1, kvv.w, num[1][3]);
            num[2][0] = fmaf(a2, kvv.x, num[2][0]); num[2][1] = fmaf(a2, kvv.y, num[2][1]);
            num[2][2] = fmaf(a2, kvv.z, num[2][2]); num[2][3] = fmaf(a2, kvv.w, num[2][3]);
            num[3][0] = fmaf(a3, kvv.x, num[3][0]); num[3][1] = fmaf(a3, kvv.y, num[3][1]);
            num[3][2] = fmaf(a3, kvv.z, num[3][2]); num[3][3] = fmaf(a3, kvv.w, num[3][3]);
        }
        if (t < 64) {
            float a = 0.f;
            #pragma unroll
            for (int m4 = 0; m4 < 64; m4 += 4) {
                const float4 ph = *(const float4*)&Ph[t][m4];
                const float4 zz = *(const float4*)&zl[m4];
                a = fmaf(ph.x, zz.x, a); a = fmaf(ph.y, zz.y, a);
                a = fmaf(ph.z, zz.z, a); a = fmaf(ph.w, zz.w, a);
            }
            dacc += a;
        }
    }
    __syncthreads();
    if (t < 64) den[t] = dacc + cEPS;
    __syncthreads();
    #pragma unroll
    for (int i = 0; i < 4; ++i) {
        const float di = 1.f / den[sr + i];
        float4 v;
        v.x = num[i][0] * di; v.y = num[i][1] * di;
        v.z = num[i][2] * di; v.w = num[i][3] * di;
        *(float4*)&Ap[((size_t)(b * cS + s0 + sr + i)) * cE + h64 + cn] = v;
    }
}

// ---------------------------------------------------------------------------
// Gate (unchanged)
// ---------------------------------------------------------------------------
__global__ __launch_bounds__(256)
void gate_avg(const float* __restrict__ x, double* __restrict__ avgpart)
{
    const int i  = blockIdx.x * 256 + threadIdx.x;    // 0..2047: (b,e)
    const int sc = blockIdx.y;                        // 0..15
    const int b  = i >> 10, e = i & 1023;
    double acc = 0.0;
    const int sEnd = sc * 128 + 128;
    for (int s = sc * 128; s < sEnd; ++s)
        acc += (double)x[((size_t)(b * cS + s)) * cE + e];
    avgpart[(size_t)sc * 2048 + i] = acc;
}

__global__ void gate_final(const double* __restrict__ avgpart, const float* __restrict__ Wg,
                           const float* __restrict__ bg, float* __restrict__ gates)
{
    const int t = threadIdx.x;
    const int b = t >> 6, lane = t & 63;
    float l0 = 0.f, l1 = 0.f;
    for (int e = lane; e < cE; e += 64) {
        double s = 0.0;
        #pragma unroll
        for (int sc = 0; sc < 16; ++sc)
            s += avgpart[(size_t)sc * 2048 + b * 1024 + e];
        const float a = (float)(s / (double)cS);
        l0 = fmaf(a, Wg[e * 2 + 0], l0);
        l1 = fmaf(a, Wg[e * 2 + 1], l1);
    }
    for (int off = 32; off >= 1; off >>= 1) {
        l0 += __shfl_down(l0, off);
        l1 += __shfl_down(l1, off);
    }
    if (lane == 0) {
        l0 += bg[0]; l1 += bg[1];
        const float m = fmaxf(l0, l1);
        const float e0 = expf(l0 - m), e1 = expf(l1 - m);
        const float s = e0 + e1;
        gates[b * 2 + 0] = e0 / s;
        gates[b * 2 + 1] = e1 / s;
    }
}

// ---------------------------------------------------------------------------
extern "C" void kernel_launch(void* const* d_in, const int* in_sizes, int n_in,
                              void* d_out, int out_size, void* d_ws, size_t ws_size,
                              hipStream_t stream)
{
    (void)in_sizes; (void)n_in; (void)out_size; (void)ws_size;
    const float* x     = (const float*)d_in[0];
    const float* Wq_s  = (const float*)d_in[1];
    const float* Wk_s  = (const float*)d_in[2];
    const float* Wv_s  = (const float*)d_in[3];
    const float* Wo_s  = (const float*)d_in[4];
    const float* bq_s  = (const float*)d_in[5];
    const float* bk_s  = (const float*)d_in[6];
    const float* bv_s  = (const float*)d_in[7];
    const float* bo_s  = (const float*)d_in[8];
    const float* Wq_p  = (const float*)d_in[9];
    const float* Wk_p  = (const float*)d_in[10];
    const float* Wv_p  = (const float*)d_in[11];
    const float* Wo_p  = (const float*)d_in[12];
    const float* bo_p  = (const float*)d_in[13];
    const float* Wfeat = (const float*)d_in[14];
    const float* Wg    = (const float*)d_in[15];
    const float* bg    = (const float*)d_in[16];

    float* ws = (float*)d_ws;
    const size_t NRE = (size_t)cB * cS * cE;
    float* Qs    = ws;              // later: Qp
    float* Ks    = Qs + NRE;        // later: Kp
    float* KsT   = Ks + NRE;        // sparse: Khi (u16); later: Apout
    float* Vs    = KsT + NRE;       // later: Vp
    float* Asout = Vs + NRE;
    float* kvpart = Asout + NRE;                           // 2*32*256*64
    float* zpart  = kvpart + (size_t)2 * 32 * cM * cD;     // 2*32*256
    double* avgpart = (double*)(zpart + (size_t)2 * 32 * cM);  // 16*2048 doubles
    float* gates = (float*)(avgpart + (size_t)16 * 2048);  // 4
    unsigned short* wthi  = (unsigned short*)(gates + 16); // 1M ushorts (scratch, reused)
    unsigned short* wtlo  = wthi + (size_t)cE * cE;
    unsigned short* wo1hi = wtlo + (size_t)cE * cE;        // Wo_s split (persistent)
    unsigned short* wo1lo = wo1hi + (size_t)cE * cE;
    unsigned short* wo2hi = wo1lo + (size_t)cE * cE;       // Wo_p split (persistent)
    unsigned short* wo2lo = wo2hi + (size_t)cE * cE;
    unsigned short* gcidx = wo2lo + (size_t)cE * cE;       // 65536 rows * 128 u16 = 16 MB
    int* gcnt = (int*)(gcidx + (size_t)65536 * 128);       // 65536 ints

    unsigned short* Khi = (unsigned short*)KsT;            // NRE ushorts (8 MB)

    // ---- output-weight splits (independent of everything else) ----
    conv_wT<<<dim3(16, 16), 256, 0, stream>>>(Wo_s, wo1hi, wo1lo);
    conv_wT<<<dim3(16, 16), 256, 0, stream>>>(Wo_p, wo2hi, wo2lo);

    // ---- sparse branch: fused BLAS-mimic fp32 Q+K (+Khi), MFMA V ----
    gemm_qk2_blas<<<dim3(16, 64), 256, 0, stream>>>(x, Wq_s, Wk_s, bq_s, bk_s,
                                                    Qs, Ks, Khi, cE, cE);
    conv_wT<<<dim3(16, 16), 256, 0, stream>>>(Wv_s, wthi, wtlo);
    gemm_hilo<<<dim3(16, 32), 256, 0, stream>>>(x, wthi, wtlo, bv_s, Vs);
    sparse_sel<<<dim3(128, 32), 256, 0, stream>>>(Qs, Khi, gcidx, gcnt);
    sparse_att<<<dim3(256, 32), 256, 0, stream>>>(Qs, gcidx, gcnt, Ks, Vs, Asout);

    // ---- performer branch (reuses buffers) ----
    float* Qp    = Qs;
    float* Kp    = Ks;
    float* Vp    = Vs;
    float* Apout = KsT;
    conv_wT<<<dim3(16, 16), 256, 0, stream>>>(Wq_p, wthi, wtlo);
    gemm_hilo<<<dim3(16, 32), 256, 0, stream>>>(x, wthi, wtlo, nullptr, Qp);
    conv_wT<<<dim3(16, 16), 256, 0, stream>>>(Wk_p, wthi, wtlo);
    gemm_hilo<<<dim3(16, 32), 256, 0, stream>>>(x, wthi, wtlo, nullptr, Kp);
    conv_wT<<<dim3(16, 16), 256, 0, stream>>>(Wv_p, wthi, wtlo);
    gemm_hilo<<<dim3(16, 32), 256, 0, stream>>>(x, wthi, wtlo, nullptr, Vp);
    perf_kv<<<dim3(8, 32), 256, 0, stream>>>(Kp, Vp, Wfeat, kvpart, zpart);
    perf_numden<<<dim3(32, 32), 256, 0, stream>>>(Qp, Wfeat, kvpart, zpart, Apout);

    // ---- gate + fused MFMA output ----
    gate_avg<<<dim3(8, 16), 256, 0, stream>>>(x, avgpart);
    gate_final<<<dim3(1), 128, 0, stream>>>(avgpart, Wg, bg, gates);
    out_gemm_hilo<<<dim3(16, 32), 256, 0, stream>>>(Asout, Apout,
                                                    wo1hi, wo1lo, wo2hi, wo2lo,
                                                    bo_s, bo_p, gates,
                                                    (float*)d_out);
}

// Round 17
// 1347.329 us; speedup vs baseline: 1.0207x; 1.0066x over previous
//
#include <hip/hip_runtime.h>

// ---------------------------------------------------------------------------
// HybridThoughtAwareAttention  (B=2,S=2048,E=1024,H=16,D=64,K_TOP=64,M=256)
// Round 24: wave-parallel radix-select scans in sparse_sel. The two serial
// t<16 scans (256-iter dependent loops, ~16 us/block while 240 threads wait)
// are the cost invariant across all five prior sparse_sel interventions.
// Replaced with an exact-equivalent per-wave suffix-scan:
//   hb = max{bin : T(bin) >= need},  rem = need - (T(hb) - hist[hb]),
// computed via 6-step shfl_down suffix sum + 6-step max reduce (~1 us).
// Same histogram contents => identical thresholds => identical output.
// Everything else byte-identical to the confirmed-best round-20 kernel.
// ---------------------------------------------------------------------------

constexpr int cB = 2, cS = 2048, cE = 1024, cH = 16, cD = 64, cKTOP = 64, cM = 256;
constexpr float cEPS = 1e-6f;

typedef _Float16 half8 __attribute__((ext_vector_type(8)));
typedef float f32x16 __attribute__((ext_vector_type(16)));

__device__ __forceinline__ unsigned int f2key(float f) {    // monotone f32->u32
    unsigned int u = __float_as_uint(f);
    return (u & 0x80000000u) ? ~u : (u | 0x80000000u);
}

__device__ __forceinline__ unsigned short h2u(_Float16 h) {
    union { _Float16 h; unsigned short u; } x; x.h = h; return x.u;
}

__device__ __forceinline__ half8 ld_half8(const unsigned short* p) {
    union { uint4 u; half8 h; } x;
    x.u = *(const uint4*)p;
    return x.h;
}

// ---------------------------------------------------------------------------
// Fused OpenBLAS-mimicking fp32 GEMM for Qs AND Ks (unchanged).
// ---------------------------------------------------------------------------
__global__ __launch_bounds__(256)
void gemm_qk2_blas(const float* __restrict__ A,
                   const float* __restrict__ Wq,
                   const float* __restrict__ Wk,
                   const float* __restrict__ bq,
                   const float* __restrict__ bk_,
                   float* __restrict__ Cq,
                   float* __restrict__ Ck,
                   unsigned short* __restrict__ khi,
                   int K, int N)
{
    __shared__ __align__(16) float As[16][68];
    __shared__ __align__(16) float Bq[16][68];
    __shared__ __align__(16) float Bk[16][68];
    const int t  = threadIdx.x;
    const int r0 = blockIdx.y * 64;
    const int c0 = blockIdx.x * 64;
    const int tm = t >> 4, tn = t & 15;
    float paccQ[4][4] = {};
    float caccQ[4][4] = {};
    float paccK[4][4] = {};
    float caccK[4][4] = {};

    const int ar = t >> 2, ak = (t & 3) * 4;
    const int bk = t >> 4, bc = (t & 15) * 4;

    for (int k0 = 0; k0 < K; k0 += 16) {
        const float4 av  = *(const float4*)(A  + (size_t)(r0 + ar) * K + (k0 + ak));
        const float4 bqv = *(const float4*)(Wq + (size_t)(k0 + bk) * N + (c0 + bc));
        const float4 bkv = *(const float4*)(Wk + (size_t)(k0 + bk) * N + (c0 + bc));
        As[ak + 0][ar] = av.x;
        As[ak + 1][ar] = av.y;
        As[ak + 2][ar] = av.z;
        As[ak + 3][ar] = av.w;
        *(float4*)&Bq[bk][bc] = bqv;
        *(float4*)&Bk[bk][bc] = bkv;
        __syncthreads();
        #pragma unroll
        for (int kk = 0; kk < 16; ++kk) {
            const float4 a4  = *(const float4*)&As[kk][tm * 4];
            const float4 q4  = *(const float4*)&Bq[kk][tn * 4];
            const float4 k4  = *(const float4*)&Bk[kk][tn * 4];
            const float a[4]  = {a4.x, a4.y, a4.z, a4.w};
            const float bqr[4] = {q4.x, q4.y, q4.z, q4.w};
            const float bkr[4] = {k4.x, k4.y, k4.z, k4.w};
            #pragma unroll
            for (int i = 0; i < 4; ++i)
                #pragma unroll
                for (int j = 0; j < 4; ++j) {
                    paccQ[i][j] = fmaf(a[i], bqr[j], paccQ[i][j]);
                    paccK[i][j] = fmaf(a[i], bkr[j], paccK[i][j]);
                }
        }
        __syncthreads();
        const int kn = k0 + 16;
        if (kn == 384 || kn == 768 || kn == K) {   // OpenBLAS KC=384 panel flush
            #pragma unroll
            for (int i = 0; i < 4; ++i)
                #pragma unroll
                for (int j = 0; j < 4; ++j) {
                    caccQ[i][j] = caccQ[i][j] + paccQ[i][j];
                    paccQ[i][j] = 0.f;
                    caccK[i][j] = caccK[i][j] + paccK[i][j];
                    paccK[i][j] = 0.f;
                }
        }
    }
    #pragma unroll
    for (int i = 0; i < 4; ++i) {
        const int r = r0 + tm * 4 + i;
        const int c = c0 + tn * 4;
        float4 vq;
        vq.x = caccQ[i][0] + bq[c + 0];
        vq.y = caccQ[i][1] + bq[c + 1];
        vq.z = caccQ[i][2] + bq[c + 2];
        vq.w = caccQ[i][3] + bq[c + 3];
        *(float4*)&Cq[(size_t)r * N + c] = vq;
        float4 vk;
        vk.x = caccK[i][0] + bk_[c + 0];
        vk.y = caccK[i][1] + bk_[c + 1];
        vk.z = caccK[i][2] + bk_[c + 2];
        vk.w = caccK[i][3] + bk_[c + 3];
        *(float4*)&Ck[(size_t)r * N + c] = vk;
        ushort4 hs;
        hs.x = h2u((_Float16)vk.x);
        hs.y = h2u((_Float16)vk.y);
        hs.z = h2u((_Float16)vk.z);
        hs.w = h2u((_Float16)vk.w);
        *(ushort4*)&khi[(size_t)r * N + c] = hs;
    }
}

// ---------------------------------------------------------------------------
// Weight prep for hi/lo MFMA GEMM: W (K x N, fp32) -> WT hi/lo (N x K, f16).
// ---------------------------------------------------------------------------
__global__ __launch_bounds__(256)
void conv_wT(const float* __restrict__ W,
             unsigned short* __restrict__ wthi,
             unsigned short* __restrict__ wtlo)
{
    __shared__ float tile[64][68];
    const int t  = threadIdx.x;
    const int k0 = blockIdx.y * 64;
    const int n0 = blockIdx.x * 64;
    const int r  = t >> 4, c4 = (t & 15) * 4;
    #pragma unroll
    for (int i = 0; i < 4; ++i) {
        const int k = r + 16 * i;
        const float4 v = *(const float4*)&W[(size_t)(k0 + k) * cE + n0 + c4];
        tile[k][c4 + 0] = v.x; tile[k][c4 + 1] = v.y;
        tile[k][c4 + 2] = v.z; tile[k][c4 + 3] = v.w;
    }
    __syncthreads();
    #pragma unroll
    for (int i = 0; i < 4; ++i) {
        const int n = r + 16 * i;
        unsigned int hp[2], lp[2];
        #pragma unroll
        for (int p = 0; p < 2; ++p) {
            unsigned short hh[2], ll[2];
            #pragma unroll
            for (int j = 0; j < 2; ++j) {
                const float f = tile[c4 + p * 2 + j][n];
                const _Float16 h = (_Float16)f;
                hh[j] = h2u(h);
                ll[j] = h2u((_Float16)(f - (float)h));
            }
            hp[p] = (unsigned int)hh[0] | ((unsigned int)hh[1] << 16);
            lp[p] = (unsigned int)ll[0] | ((unsigned int)ll[1] << 16);
        }
        uint2 hv, lv;
        hv.x = hp[0]; hv.y = hp[1];
        lv.x = lp[0]; lv.y = lp[1];
        *(uint2*)&wthi[(size_t)(n0 + n) * cE + k0 + c4] = hv;
        *(uint2*)&wtlo[(size_t)(n0 + n) * cE + k0 + c4] = lv;
    }
}

// ---------------------------------------------------------------------------
// f16 hi/lo 3-product MFMA GEMM (unchanged).
// ---------------------------------------------------------------------------
__global__ __launch_bounds__(256)
void gemm_hilo(const float* __restrict__ A,
               const unsigned short* __restrict__ wthi,
               const unsigned short* __restrict__ wtlo,
               const float* __restrict__ bias,
               float* __restrict__ C)
{
    __shared__ __align__(16) unsigned short Ah[128][24];   // 24 = 16 + 8 pad
    __shared__ __align__(16) unsigned short Al[128][24];
    __shared__ __align__(16) unsigned short Bh[64][24];
    __shared__ __align__(16) unsigned short Bl[64][24];

    const int t    = threadIdx.x;
    const int lane = t & 63, wave = t >> 6;
    const int wr   = wave >> 1, wc = wave & 1;
    const int r0   = blockIdx.y * 128, c0 = blockIdx.x * 64;
    const int fr   = lane & 31, g5 = lane >> 5;

    const int arow = t >> 1, aka = (t & 1) * 8;
    const int bsel = t >> 7;                 // waves 0,1: hi; waves 2,3: lo
    const int brow = (t & 127) >> 1, bkb = (t & 1) * 8;
    const unsigned short* wsrc = bsel ? wtlo : wthi;

    f32x16 acc0 = {0.f,0.f,0.f,0.f,0.f,0.f,0.f,0.f,0.f,0.f,0.f,0.f,0.f,0.f,0.f,0.f};
    f32x16 acc1 = {0.f,0.f,0.f,0.f,0.f,0.f,0.f,0.f,0.f,0.f,0.f,0.f,0.f,0.f,0.f,0.f};

    for (int k0 = 0; k0 < cE; k0 += 16) {
        const float4 x0 = *(const float4*)&A[(size_t)(r0 + arow) * cE + k0 + aka];
        const float4 x1 = *(const float4*)&A[(size_t)(r0 + arow) * cE + k0 + aka + 4];
        const float xf[8] = {x0.x, x0.y, x0.z, x0.w, x1.x, x1.y, x1.z, x1.w};
        unsigned int hw[4], lw[4];
        #pragma unroll
        for (int p = 0; p < 4; ++p) {
            unsigned short hh[2], ll[2];
            #pragma unroll
            for (int j = 0; j < 2; ++j) {
                const float f = xf[p * 2 + j];
                const _Float16 h = (_Float16)f;
                hh[j] = h2u(h);
                ll[j] = h2u((_Float16)(f - (float)h));
            }
            hw[p] = (unsigned int)hh[0] | ((unsigned int)hh[1] << 16);
            lw[p] = (unsigned int)ll[0] | ((unsigned int)ll[1] << 16);
        }
        uint4 hv, lv;
        hv.x = hw[0]; hv.y = hw[1]; hv.z = hw[2]; hv.w = hw[3];
        lv.x = lw[0]; lv.y = lw[1]; lv.z = lw[2]; lv.w = lw[3];
        *(uint4*)&Ah[arow][aka] = hv;
        *(uint4*)&Al[arow][aka] = lv;

        const uint4 wv = *(const uint4*)&wsrc[(size_t)(c0 + brow) * cE + k0 + bkb];
        if (bsel) *(uint4*)&Bl[brow][bkb] = wv;
        else      *(uint4*)&Bh[brow][bkb] = wv;
        __syncthreads();

        const half8 a0h = ld_half8(&Ah[wr * 64 + fr][g5 * 8]);
        const half8 a0l = ld_half8(&Al[wr * 64 + fr][g5 * 8]);
        const half8 a1h = ld_half8(&Ah[wr * 64 + 32 + fr][g5 * 8]);
        const half8 a1l = ld_half8(&Al[wr * 64 + 32 + fr][g5 * 8]);
        const half8 bh  = ld_half8(&Bh[wc * 32 + fr][g5 * 8]);
        const half8 bl  = ld_half8(&Bl[wc * 32 + fr][g5 * 8]);

        acc0 = __builtin_amdgcn_mfma_f32_32x32x16_f16(a0l, bh, acc0, 0, 0, 0);
        acc0 = __builtin_amdgcn_mfma_f32_32x32x16_f16(a0h, bl, acc0, 0, 0, 0);
        acc0 = __builtin_amdgcn_mfma_f32_32x32x16_f16(a0h, bh, acc0, 0, 0, 0);
        acc1 = __builtin_amdgcn_mfma_f32_32x32x16_f16(a1l, bh, acc1, 0, 0, 0);
        acc1 = __builtin_amdgcn_mfma_f32_32x32x16_f16(a1h, bl, acc1, 0, 0, 0);
        acc1 = __builtin_amdgcn_mfma_f32_32x32x16_f16(a1h, bh, acc1, 0, 0, 0);
        __syncthreads();
    }

    const int col = c0 + wc * 32 + fr;
    const float bv = bias ? bias[col] : 0.f;
    #pragma unroll
    for (int rg = 0; rg < 16; ++rg) {
        const int row = r0 + wr * 64 + (rg & 3) + 8 * (rg >> 2) + 4 * g5;
        C[(size_t)row * cE + col] = acc0[rg] + bv;
    }
    #pragma unroll
    for (int rg = 0; rg < 16; ++rg) {
        const int row = r0 + wr * 64 + 32 + (rg & 3) + 8 * (rg >> 2) + 4 * g5;
        C[(size_t)row * cE + col] = acc1[rg] + bv;
    }
}

// ---------------------------------------------------------------------------
// Fused output GEMM, hi/lo MFMA (unchanged).
// ---------------------------------------------------------------------------
__global__ __launch_bounds__(256)
void out_gemm_hilo(const float* __restrict__ As_, const float* __restrict__ Ap_,
                   const unsigned short* __restrict__ w1hi,
                   const unsigned short* __restrict__ w1lo,
                   const unsigned short* __restrict__ w2hi,
                   const unsigned short* __restrict__ w2lo,
                   const float* __restrict__ bos, const float* __restrict__ bop,
                   const float* __restrict__ gates, float* __restrict__ out)
{
    __shared__ __align__(16) unsigned short A1h[128][24], A1l[128][24];
    __shared__ __align__(16) unsigned short A2h[128][24], A2l[128][24];
    __shared__ __align__(16) unsigned short B1h[64][24],  B1l[64][24];
    __shared__ __align__(16) unsigned short B2h[64][24],  B2l[64][24];

    const int t    = threadIdx.x;
    const int lane = t & 63, wave = t >> 6;
    const int wr   = wave >> 1, wc = wave & 1;
    const int r0   = blockIdx.y * 128, c0 = blockIdx.x * 64;
    const int fr   = lane & 31, g5 = lane >> 5;
    const int b    = r0 >> 11;
    const float gs = gates[b * 2 + 0], gp = gates[b * 2 + 1];

    const int arow = t >> 1, aka = (t & 1) * 8;
    const int bsel = t >> 7;
    const int brow = (t & 127) >> 1, bkb = (t & 1) * 8;
    const unsigned short* s1 = bsel ? w1lo : w1hi;
    const unsigned short* s2 = bsel ? w2lo : w2hi;

    f32x16 acc0 = {0.f,0.f,0.f,0.f,0.f,0.f,0.f,0.f,0.f,0.f,0.f,0.f,0.f,0.f,0.f,0.f};
    f32x16 acc1 = {0.f,0.f,0.f,0.f,0.f,0.f,0.f,0.f,0.f,0.f,0.f,0.f,0.f,0.f,0.f,0.f};

    for (int k0 = 0; k0 < cE; k0 += 16) {
        {
            const float4 x0 = *(const float4*)&As_[(size_t)(r0 + arow) * cE + k0 + aka];
            const float4 x1 = *(const float4*)&As_[(size_t)(r0 + arow) * cE + k0 + aka + 4];
            const float xf[8] = {x0.x * gs, x0.y * gs, x0.z * gs, x0.w * gs,
                                 x1.x * gs, x1.y * gs, x1.z * gs, x1.w * gs};
            unsigned int hw[4], lw[4];
            #pragma unroll
            for (int p = 0; p < 4; ++p) {
                unsigned short hh[2], ll[2];
                #pragma unroll
                for (int j = 0; j < 2; ++j) {
                    const float f = xf[p * 2 + j];
                    const _Float16 h = (_Float16)f;
                    hh[j] = h2u(h);
                    ll[j] = h2u((_Float16)(f - (float)h));
                }
                hw[p] = (unsigned int)hh[0] | ((unsigned int)hh[1] << 16);
                lw[p] = (unsigned int)ll[0] | ((unsigned int)ll[1] << 16);
            }
            uint4 hv, lv;
            hv.x = hw[0]; hv.y = hw[1]; hv.z = hw[2]; hv.w = hw[3];
            lv.x = lw[0]; lv.y = lw[1]; lv.z = lw[2]; lv.w = lw[3];
            *(uint4*)&A1h[arow][aka] = hv;
            *(uint4*)&A1l[arow][aka] = lv;
        }
        {
            const float4 x0 = *(const float4*)&Ap_[(size_t)(r0 + arow) * cE + k0 + aka];
            const float4 x1 = *(const float4*)&Ap_[(size_t)(r0 + arow) * cE + k0 + aka + 4];
            const float xf[8] = {x0.x * gp, x0.y * gp, x0.z * gp, x0.w * gp,
                                 x1.x * gp, x1.y * gp, x1.z * gp, x1.w * gp};
            unsigned int hw[4], lw[4];
            #pragma unroll
            for (int p = 0; p < 4; ++p) {
                unsigned short hh[2], ll[2];
                #pragma unroll
                for (int j = 0; j < 2; ++j) {
                    const float f = xf[p * 2 + j];
                    const _Float16 h = (_Float16)f;
                    hh[j] = h2u(h);
                    ll[j] = h2u((_Float16)(f - (float)h));
                }
                hw[p] = (unsigned int)hh[0] | ((unsigned int)hh[1] << 16);
                lw[p] = (unsigned int)ll[0] | ((unsigned int)ll[1] << 16);
            }
            uint4 hv, lv;
            hv.x = hw[0]; hv.y = hw[1]; hv.z = hw[2]; hv.w = hw[3];
            lv.x = lw[0]; lv.y = lw[1]; lv.z = lw[2]; lv.w = lw[3];
            *(uint4*)&A2h[arow][aka] = hv;
            *(uint4*)&A2l[arow][aka] = lv;
        }
        {
            const uint4 w1 = *(const uint4*)&s1[(size_t)(c0 + brow) * cE + k0 + bkb];
            if (bsel) *(uint4*)&B1l[brow][bkb] = w1;
            else      *(uint4*)&B1h[brow][bkb] = w1;
            const uint4 w2 = *(const uint4*)&s2[(size_t)(c0 + brow) * cE + k0 + bkb];
            if (bsel) *(uint4*)&B2l[brow][bkb] = w2;
            else      *(uint4*)&B2h[brow][bkb] = w2;
        }
        __syncthreads();

        const half8 b1h = ld_half8(&B1h[wc * 32 + fr][g5 * 8]);
        const half8 b1l = ld_half8(&B1l[wc * 32 + fr][g5 * 8]);
        const half8 b2h = ld_half8(&B2h[wc * 32 + fr][g5 * 8]);
        const half8 b2l = ld_half8(&B2l[wc * 32 + fr][g5 * 8]);
        {
            const half8 a1h = ld_half8(&A1h[wr * 64 + fr][g5 * 8]);
            const half8 a1l = ld_half8(&A1l[wr * 64 + fr][g5 * 8]);
            const half8 a2h = ld_half8(&A2h[wr * 64 + fr][g5 * 8]);
            const half8 a2l = ld_half8(&A2l[wr * 64 + fr][g5 * 8]);
            acc0 = __builtin_amdgcn_mfma_f32_32x32x16_f16(a1l, b1h, acc0, 0, 0, 0);
            acc0 = __builtin_amdgcn_mfma_f32_32x32x16_f16(a1h, b1l, acc0, 0, 0, 0);
            acc0 = __builtin_amdgcn_mfma_f32_32x32x16_f16(a1h, b1h, acc0, 0, 0, 0);
            acc0 = __builtin_amdgcn_mfma_f32_32x32x16_f16(a2l, b2h, acc0, 0, 0, 0);
            acc0 = __builtin_amdgcn_mfma_f32_32x32x16_f16(a2h, b2l, acc0, 0, 0, 0);
            acc0 = __builtin_amdgcn_mfma_f32_32x32x16_f16(a2h, b2h, acc0, 0, 0, 0);
        }
        {
            const half8 a1h = ld_half8(&A1h[wr * 64 + 32 + fr][g5 * 8]);
            const half8 a1l = ld_half8(&A1l[wr * 64 + 32 + fr][g5 * 8]);
            const half8 a2h = ld_half8(&A2h[wr * 64 + 32 + fr][g5 * 8]);
            const half8 a2l = ld_half8(&A2l[wr * 64 + 32 + fr][g5 * 8]);
            acc1 = __builtin_amdgcn_mfma_f32_32x32x16_f16(a1l, b1h, acc1, 0, 0, 0);
            acc1 = __builtin_amdgcn_mfma_f32_32x32x16_f16(a1h, b1l, acc1, 0, 0, 0);
            acc1 = __builtin_amdgcn_mfma_f32_32x32x16_f16(a1h, b1h, acc1, 0, 0, 0);
            acc1 = __builtin_amdgcn_mfma_f32_32x32x16_f16(a2l, b2h, acc1, 0, 0, 0);
            acc1 = __builtin_amdgcn_mfma_f32_32x32x16_f16(a2h, b2l, acc1, 0, 0, 0);
            acc1 = __builtin_amdgcn_mfma_f32_32x32x16_f16(a2h, b2h, acc1, 0, 0, 0);
        }
        __syncthreads();
    }

    const int col = c0 + wc * 32 + fr;
    const float bv = gs * bos[col] + gp * bop[col];
    #pragma unroll
    for (int rg = 0; rg < 16; ++rg) {
        const int row = r0 + wr * 64 + (rg & 3) + 8 * (rg >> 2) + 4 * g5;
        out[(size_t)row * cE + col] = acc0[rg] + bv;
    }
    #pragma unroll
    for (int rg = 0; rg < 16; ++rg) {
        const int row = r0 + wr * 64 + 32 + (rg & 3) + 8 * (rg >> 2) + 4 * g5;
        out[(size_t)row * cE + col] = acc1[rg] + bv;
    }
}

// ---------------------------------------------------------------------------
// Sparse selection, QBLK=16, wave-parallel radix select. Phase A identical
// to round 20. The two threshold scans use a per-wave suffix-scan that is
// exactly equivalent to the serial loop:
//   hb = max{bin : T(bin) >= need}, rem = need - (T(hb) - hist[hb])
// where T is the inclusive suffix sum of hist from bin 255 downward.
// ---------------------------------------------------------------------------
__global__ __launch_bounds__(256, 4)
void sparse_sel(const float* __restrict__ Q,
                const unsigned short* __restrict__ Khi,
                unsigned short* __restrict__ gcidx,
                int* __restrict__ gcnt)
{
    __shared__ __align__(16) unsigned short Qhi[16][72];  // 2.25 KB
    __shared__ unsigned int hist[16][257];                // 16.4 KB
    __shared__ int cnt[16];
    __shared__ int t16hi[16], rem[16], t16[16];

    const int t   = threadIdx.x;
    const int bh  = blockIdx.y;
    const int b   = bh >> 4;
    const int h64 = (bh & 15) * 64;
    const int q0  = blockIdx.x * 16;
    const size_t rid0 = (size_t)bh * 2048 + q0;           // linear row id base

    {
        const int r = t >> 4, c4 = (t & 15) * 4;
        const float4 v =
            *(const float4*)&Q[((size_t)(b * cS + q0 + r)) * cE + h64 + c4];
        const float f[4] = {v.x, v.y, v.z, v.w};
        #pragma unroll
        for (int i = 0; i < 4; ++i)
            Qhi[r][c4 + i] = h2u((_Float16)f[i]);
    }
    for (int i = t; i < 16 * 257; i += 256) (&hist[0][0])[i] = 0u;
    if (t < 16) cnt[t] = 0;
    __syncthreads();                                               // B1

    const int lane = t & 63;
    const int wv   = t >> 6;
    const int col  = lane & 31;
    const int g5   = lane >> 5;
    const int base0 = 4 * g5;          // rows from acc regs 0..3
    const int base1 = 8 + 4 * g5;      // rows from acc regs 4..7

    // ---- phase A: single-product f16 MFMA scores, keys wv*512 .. +512 ----
    half8 ahi[4];
    {
        const int arow = col & 15;     // 16 valid Q rows (dup x2 over 32)
        #pragma unroll
        for (int ks = 0; ks < 4; ++ks)
            ahi[ks] = ld_half8(&Qhi[arow][g5 * 8 + ks * 16]);
    }
    unsigned int su[16][4];            // u16 keys, 8 rows x 16 tiles
    {
        const size_t kbase = ((size_t)(b * cS + wv * 512 + col)) * cE + h64;
        #pragma unroll
        for (int tl = 0; tl < 16; ++tl) {
            const unsigned short* kh = Khi + kbase + (size_t)tl * 32 * cE;
            f32x16 acc = {0.f,0.f,0.f,0.f,0.f,0.f,0.f,0.f,
                          0.f,0.f,0.f,0.f,0.f,0.f,0.f,0.f};
            #pragma unroll
            for (int ks = 0; ks < 4; ++ks) {
                const half8 bh8 = ld_half8(kh + g5 * 8 + ks * 16);
                acc = __builtin_amdgcn_mfma_f32_32x32x16_f16(ahi[ks], bh8, acc, 0, 0, 0);
            }
            unsigned int k[8];
            #pragma unroll
            for (int r = 0; r < 8; ++r)
                k[r] = f2key(acc[r] * 0.125f) >> 16;
            su[tl][0] = k[0] | (k[1] << 16);
            su[tl][1] = k[2] | (k[3] << 16);
            su[tl][2] = k[4] | (k[5] << 16);
            su[tl][3] = k[6] | (k[7] << 16);
            atomicAdd(&hist[base0 + 0][k[0] >> 8], 1u);
            atomicAdd(&hist[base0 + 1][k[1] >> 8], 1u);
            atomicAdd(&hist[base0 + 2][k[2] >> 8], 1u);
            atomicAdd(&hist[base0 + 3][k[3] >> 8], 1u);
            atomicAdd(&hist[base1 + 0][k[4] >> 8], 1u);
            atomicAdd(&hist[base1 + 1][k[5] >> 8], 1u);
            atomicAdd(&hist[base1 + 2][k[6] >> 8], 1u);
            atomicAdd(&hist[base1 + 3][k[7] >> 8], 1u);
        }
    }
    __syncthreads();                                               // B2

    // ---- scan 1 (wave-parallel): wave wv owns rows 4wv..4wv+3 ----
    #pragma unroll
    for (int rx = 0; rx < 4; ++rx) {
        const int r  = wv * 4 + rx;
        const int b0 = lane * 4;
        const int h0 = (int)hist[r][b0 + 0];
        const int h1 = (int)hist[r][b0 + 1];
        const int h2 = (int)hist[r][b0 + 2];
        const int h3 = (int)hist[r][b0 + 3];
        const int local = h0 + h1 + h2 + h3;
        int s = local;                       // inclusive suffix over lanes
        #pragma unroll
        for (int off = 1; off < 64; off <<= 1) {
            const int v = __shfl_down(s, off);
            if (lane + off < 64) s += v;
        }
        const int above = s - local;         // sum of lanes > lane
        const int T3 = above + h3;
        const int T2 = T3 + h2;
        const int T1 = T2 + h1;
        const int T0 = T1 + h0;
        int cand = -1, candT = 0, candH = 0;
        if      (T3 >= 65) { cand = b0 + 3; candT = T3; candH = h3; }
        else if (T2 >= 65) { cand = b0 + 2; candT = T2; candH = h2; }
        else if (T1 >= 65) { cand = b0 + 1; candT = T1; candH = h1; }
        else if (T0 >= 65) { cand = b0 + 0; candT = T0; candH = h0; }
        int mx = cand;
        #pragma unroll
        for (int off = 32; off >= 1; off >>= 1)
            mx = max(mx, __shfl_xor(mx, off));
        if (cand >= 0 && cand == mx) {
            t16hi[r] = cand;
            rem[r]   = 65 - (candT - candH);
        }
    }
    __syncthreads();                                               // B3
    for (int i = t; i < 16 * 257; i += 256) (&hist[0][0])[i] = 0u;  // pass 2
    __syncthreads();                                               // B3b
    #pragma unroll
    for (int tl = 0; tl < 16; ++tl)
        #pragma unroll
        for (int w = 0; w < 4; ++w) {
            const unsigned int u = su[tl][w];
            const int rlo = (w < 2 ? base0 : base1) + (w & 1) * 2;
            const int rhi = rlo + 1;
            const unsigned int vlo = u & 0xFFFFu;
            const unsigned int vhi = u >> 16;
            if ((int)(vlo >> 8) == t16hi[rlo]) atomicAdd(&hist[rlo][vlo & 255u], 1u);
            if ((int)(vhi >> 8) == t16hi[rhi]) atomicAdd(&hist[rhi][vhi & 255u], 1u);
        }
    __syncthreads();                                               // B4

    // ---- scan 2 (wave-parallel, need = rem[r]) ----
    #pragma unroll
    for (int rx = 0; rx < 4; ++rx) {
        const int r    = wv * 4 + rx;
        const int need = rem[r];
        const int b0   = lane * 4;
        const int h0 = (int)hist[r][b0 + 0];
        const int h1 = (int)hist[r][b0 + 1];
        const int h2 = (int)hist[r][b0 + 2];
        const int h3 = (int)hist[r][b0 + 3];
        const int local = h0 + h1 + h2 + h3;
        int s = local;
        #pragma unroll
        for (int off = 1; off < 64; off <<= 1) {
            const int v = __shfl_down(s, off);
            if (lane + off < 64) s += v;
        }
        const int above = s - local;
        const int T3 = above + h3;
        const int T2 = T3 + h2;
        const int T1 = T2 + h1;
        const int T0 = T1 + h0;
        int cand = -1;
        if      (T3 >= need) cand = b0 + 3;
        else if (T2 >= need) cand = b0 + 2;
        else if (T1 >= need) cand = b0 + 1;
        else if (T0 >= need) cand = b0 + 0;
        int mx = cand;
        #pragma unroll
        for (int off = 32; off >= 1; off >>= 1)
            mx = max(mx, __shfl_xor(mx, off));
        if (cand >= 0 && cand == mx)
            t16[r] = (t16hi[r] << 8) | cand;
    }
    __syncthreads();                                               // B5

    // ---- candidate scan: u16 >= T16 - 3; write straight to global ----
    #pragma unroll
    for (int tl = 0; tl < 16; ++tl) {
        const int key = wv * 512 + tl * 32 + col;
        #pragma unroll
        for (int w = 0; w < 4; ++w) {
            const unsigned int u = su[tl][w];
            const int rlo = (w < 2 ? base0 : base1) + (w & 1) * 2;
            const int rhi = rlo + 1;
            const int v0 = (int)(u & 0xFFFFu);
            const int v1 = (int)(u >> 16);
            if (v0 >= max(t16[rlo] - 3, 0)) {
                const int slot = atomicAdd(&cnt[rlo], 1);
                if (slot < 128) gcidx[(rid0 + rlo) * 128 + slot] = (unsigned short)key;
            }
            if (v1 >= max(t16[rhi] - 3, 0)) {
                const int slot = atomicAdd(&cnt[rhi], 1);
                if (slot < 128) gcidx[(rid0 + rhi) * 128 + slot] = (unsigned short)key;
            }
        }
    }
    __syncthreads();                                               // B6
    if (t < 16) gcnt[rid0 + t] = cnt[t];
}

// ---------------------------------------------------------------------------
// Sparse attention (phases C/D, unchanged): fp64 recompute, ranking, hedge
// weights, unroll-8 PV gather. __launch_bounds__(256,8).
// ---------------------------------------------------------------------------
__global__ __launch_bounds__(256, 8)
void sparse_att(const float* __restrict__ Q,
                const unsigned short* __restrict__ gcidx,
                const int* __restrict__ gcnt,
                const float* __restrict__ Ks, const float* __restrict__ V,
                float* __restrict__ O)
{
    __shared__ float QfT[64][8];                 // 2 KB  (Q transposed)
    __shared__ unsigned short cidx[8][128];      // 2 KB
    __shared__ double cval[8][128];              // 8 KB
    __shared__ float cw[8][128];                 // 4 KB
    __shared__ int cnt[8];
    __shared__ double T64s[8], s65s[8], rowm[8];

    const int t   = threadIdx.x;
    const int bh  = blockIdx.y;
    const int b   = bh >> 4;
    const int h64 = (bh & 15) * 64;
    const int q0  = blockIdx.x * 8;
    const size_t rid0 = ((size_t)bh * 256 + blockIdx.x) * 8;

    if (t < 128) {
        const int r = t >> 4, c4 = (t & 15) * 4;
        const float4 v =
            *(const float4*)&Q[((size_t)(b * cS + q0 + r)) * cE + h64 + c4];
        QfT[c4 + 0][r] = v.x; QfT[c4 + 1][r] = v.y;
        QfT[c4 + 2][r] = v.z; QfT[c4 + 3][r] = v.w;
    }
    // 8 rows x 128 u16 are contiguous in gcidx -> one ushort4 per thread
    ((ushort4*)&cidx[0][0])[t] = ((const ushort4*)&gcidx[rid0 * 128])[t];
    if (t < 8) cnt[t] = gcnt[rid0 + t];
    __syncthreads();                                               // B6'

    const int wv = t >> 6, lane = t & 63;

    // ---- phase C: fp64 recompute, lane = candidate (2 rows per wave) ----
    #pragma unroll
    for (int rx = 0; rx < 2; ++rx) {
        const int rr = wv * 2 + rx;
        const int n = min(cnt[rr], 128);
        for (int c = lane; c < n; c += 64) {
            const int key = cidx[rr][c];
            const float* kp = Ks + ((size_t)(b * cS + key)) * cE + h64;
            double a = 0.0;
            #pragma unroll 4
            for (int d4 = 0; d4 < 64; d4 += 4) {
                const float4 kv = *(const float4*)&kp[d4];
                a = fma((double)QfT[d4 + 0][rr], (double)kv.x, a);
                a = fma((double)QfT[d4 + 1][rr], (double)kv.y, a);
                a = fma((double)QfT[d4 + 2][rr], (double)kv.z, a);
                a = fma((double)QfT[d4 + 3][rr], (double)kv.w, a);
            }
            cval[rr][c] = a * 0.125;
        }
    }
    __syncthreads();                                               // B7

    // ---- ranking: T64 (rank 63), s65 (rank 64), m (rank 0) ----
    #pragma unroll
    for (int rx = 0; rx < 2; ++rx) {
        const int rr = wv * 2 + rx;
        const int n = min(cnt[rr], 128);
        for (int c = lane; c < n; c += 64) {
            const double v = cval[rr][c];
            int rank = 0;
            for (int i = 0; i < n; ++i) rank += (cval[rr][i] > v) ? 1 : 0;
            if (rank == 0)  rowm[rr] = v;
            if (rank == 63) T64s[rr] = v;
            if (rank == 64) s65s[rr] = v;
        }
    }
    __syncthreads();                                               // B8

    // ---- weights: hedge formula (unchanged) ----
    #pragma unroll
    for (int rx = 0; rx < 2; ++rx) {
        const int rr = wv * 2 + rx;
        const int n = min(cnt[rr], 128);
        const double T64 = T64s[rr], s65 = s65s[rr], m = rowm[rr];
        float za = 0.f;
        for (int c = lane; c < n; c += 64) {
            const double v = cval[rr][c];
            if (v >= T64) za += expf((float)(v - m));
        }
        #pragma unroll
        for (int off = 32; off >= 1; off >>= 1)
            za += __shfl_xor(za, off);
        const float g   = (float)(T64 - s65);
        const float gm  = fmaxf(g - 5e-7f, 0.f);
        const float wB  = 0.5f * erfcf(gm * (1.0f / 2.2e-6f));
        const float wA  = 1.f - wB;
        const float e64 = expf((float)(T64 - m));
        const float e65 = expf((float)(s65 - m));
        const float ZB  = za - e64 + e65;
        const float cIn = wA / za + wB / ZB;
        const float c64 = wA / za;
        const float c65 = wB / ZB;
        for (int c = lane; c < n; c += 64) {
            const double v = cval[rr][c];
            float cc = 0.f;
            if (v > T64)       cc = cIn;
            else if (v == T64) cc = c64;
            else if (v == s65) cc = c65;
            cw[rr][c] = (cc != 0.f) ? cc * expf((float)(v - m)) : 0.f;
        }
    }
    __syncthreads();                                               // B9

    // ---- phase D: sparse PV gather, unroll-8 pipelined (same sum order) ----
    #pragma unroll
    for (int rx = 0; rx < 2; ++rx) {
        const int rr = wv * 2 + rx;
        const int n = min(cnt[rr], 128);
        float o = 0.f;
        int j = 0;
        for (; j + 8 <= n; j += 8) {
            float wreg[8];
            int   kreg[8];
            #pragma unroll
            for (int u = 0; u < 8; ++u) {
                wreg[u] = cw[rr][j + u];
                kreg[u] = cidx[rr][j + u];
            }
            float vreg[8];
            #pragma unroll
            for (int u = 0; u < 8; ++u)
                vreg[u] = V[((size_t)(b * cS + kreg[u])) * cE + h64 + lane];
            #pragma unroll
            for (int u = 0; u < 8; ++u)
                o = fmaf(wreg[u], vreg[u], o);
        }
        for (; j < n; ++j)
            o = fmaf(cw[rr][j],
                     V[((size_t)(b * cS + cidx[rr][j])) * cE + h64 + lane], o);
        O[((size_t)(b * cS + q0 + rr)) * cE + h64 + lane] = o;
    }
}

// ---------------------------------------------------------------------------
// Performer kv (unchanged)
// ---------------------------------------------------------------------------
__global__ __launch_bounds__(256)
void perf_kv(const float* __restrict__ Kp, const float* __restrict__ Vp,
             const float* __restrict__ Wfeat,
             float* __restrict__ kvpart, float* __restrict__ zpart)
{
    __shared__ __align__(16) float Wf[64][68];
    __shared__ __align__(16) float Kt[64][68];
    __shared__ __align__(16) float Vt[64][68];
    __shared__ __align__(16) float Ph[64][68];
    const int t    = threadIdx.x;
    const int mc   = blockIdx.x & 3;
    const int sc   = blockIdx.x >> 2;          // 0 or 1
    const int bh   = blockIdx.y;
    const int b    = bh >> 4;
    const int h64  = (bh & 15) * 64;
    const int m0   = mc * 64;
    const int sbase = sc * 1024;

    #pragma unroll
    for (int i = 0; i < 4; ++i) {
        const int lin = t + 256 * i;
        const int d   = lin >> 4;
        const int m4  = (lin & 15) * 4;
        *(float4*)&Wf[d][m4] = *(const float4*)&Wfeat[d * cM + m0 + m4];
    }

    const int tm = t >> 4, tn = t & 15;
    const int sr = tm * 4;
    const int cn = tn * 4;
    float akv[4][4] = {};
    float az = 0.f;

    for (int st = 0; st < 16; ++st) {
        const int s0g = sbase + st * 64;
        __syncthreads();
        #pragma unroll
        for (int i = 0; i < 4; ++i) {
            const int row = tm + 16 * i;
            const size_t base = ((size_t)(b * cS + s0g + row)) * cE + h64 + cn;
            *(float4*)&Kt[row][cn] = *(const float4*)&Kp[base];
            *(float4*)&Vt[row][cn] = *(const float4*)&Vp[base];
        }
        __syncthreads();
        float4 p0 = {0,0,0,0}, p1 = {0,0,0,0}, p2 = {0,0,0,0}, p3 = {0,0,0,0};
        #pragma unroll 8
        for (int d = 0; d < 64; ++d) {
            const float4 wv = *(const float4*)&Wf[d][cn];
            const float k0 = Kt[sr + 0][d], k1 = Kt[sr + 1][d];
            const float k2 = Kt[sr + 2][d], k3 = Kt[sr + 3][d];
            p0.x = fmaf(k0, wv.x, p0.x); p0.y = fmaf(k0, wv.y, p0.y);
            p0.z = fmaf(k0, wv.z, p0.z); p0.w = fmaf(k0, wv.w, p0.w);
            p1.x = fmaf(k1, wv.x, p1.x); p1.y = fmaf(k1, wv.y, p1.y);
            p1.z = fmaf(k1, wv.z, p1.z); p1.w = fmaf(k1, wv.w, p1.w);
            p2.x = fmaf(k2, wv.x, p2.x); p2.y = fmaf(k2, wv.y, p2.y);
            p2.z = fmaf(k2, wv.z, p2.z); p2.w = fmaf(k2, wv.w, p2.w);
            p3.x = fmaf(k3, wv.x, p3.x); p3.y = fmaf(k3, wv.y, p3.y);
            p3.z = fmaf(k3, wv.z, p3.z); p3.w = fmaf(k3, wv.w, p3.w);
        }
        p0.x = fmaxf(p0.x, 0.f) + cEPS; p0.y = fmaxf(p0.y, 0.f) + cEPS;
        p0.z = fmaxf(p0.z, 0.f) + cEPS; p0.w = fmaxf(p0.w, 0.f) + cEPS;
        p1.x = fmaxf(p1.x, 0.f) + cEPS; p1.y = fmaxf(p1.y, 0.f) + cEPS;
        p1.z = fmaxf(p1.z, 0.f) + cEPS; p1.w = fmaxf(p1.w, 0.f) + cEPS;
        p2.x = fmaxf(p2.x, 0.f) + cEPS; p2.y = fmaxf(p2.y, 0.f) + cEPS;
        p2.z = fmaxf(p2.z, 0.f) + cEPS; p2.w = fmaxf(p2.w, 0.f) + cEPS;
        p3.x = fmaxf(p3.x, 0.f) + cEPS; p3.y = fmaxf(p3.y, 0.f) + cEPS;
        p3.z = fmaxf(p3.z, 0.f) + cEPS; p3.w = fmaxf(p3.w, 0.f) + cEPS;
        *(float4*)&Ph[sr + 0][cn] = p0;
        *(float4*)&Ph[sr + 1][cn] = p1;
        *(float4*)&Ph[sr + 2][cn] = p2;
        *(float4*)&Ph[sr + 3][cn] = p3;
        __syncthreads();
        #pragma unroll 8
        for (int ss = 0; ss < 64; ++ss) {
            const float4 pv = *(const float4*)&Ph[ss][sr];
            const float4 vv = *(const float4*)&Vt[ss][cn];
            akv[0][0] = fmaf(pv.x, vv.x, akv[0][0]); akv[0][1] = fmaf(pv.x, vv.y, akv[0][1]);
            akv[0][2] = fmaf(pv.x, vv.z, akv[0][2]); akv[0][3] = fmaf(pv.x, vv.w, akv[0][3]);
            akv[1][0] = fmaf(pv.y, vv.x, akv[1][0]); akv[1][1] = fmaf(pv.y, vv.y, akv[1][1]);
            akv[1][2] = fmaf(pv.y, vv.z, akv[1][2]); akv[1][3] = fmaf(pv.y, vv.w, akv[1][3]);
            akv[2][0] = fmaf(pv.z, vv.x, akv[2][0]); akv[2][1] = fmaf(pv.z, vv.y, akv[2][1]);
            akv[2][2] = fmaf(pv.z, vv.z, akv[2][2]); akv[2][3] = fmaf(pv.z, vv.w, akv[2][3]);
            akv[3][0] = fmaf(pv.w, vv.x, akv[3][0]); akv[3][1] = fmaf(pv.w, vv.y, akv[3][1]);
            akv[3][2] = fmaf(pv.w, vv.z, akv[3][2]); akv[3][3] = fmaf(pv.w, vv.w, akv[3][3]);
        }
        if (t < 64) {
            float a = 0.f;
            #pragma unroll 8
            for (int ss = 0; ss < 64; ++ss) a += Ph[ss][t];
            az += a;
        }
    }
    const size_t obase = ((size_t)(sc * 32 + bh)) * cM + m0;
    #pragma unroll
    for (int i = 0; i < 4; ++i) {
        float4 v; v.x = akv[i][0]; v.y = akv[i][1]; v.z = akv[i][2]; v.w = akv[i][3];
        *(float4*)&kvpart[(obase + sr + i) * cD + cn] = v;
    }
    if (t < 64) zpart[obase + t] = az;
}

// ---------------------------------------------------------------------------
// Performer num/den (unchanged)
// ---------------------------------------------------------------------------
__global__ __launch_bounds__(256)
void perf_numden(const float* __restrict__ Qp, const float* __restrict__ Wfeat,
                 const float* __restrict__ kvpart, const float* __restrict__ zpart,
                 float* __restrict__ Ap)
{
    __shared__ __align__(16) float Wf[64][68];
    __shared__ __align__(16) float Qt[64][68];
    __shared__ __align__(16) float KV[64][68];
    __shared__ __align__(16) float Ph[64][68];
    __shared__ __align__(16) float zl[64];
    __shared__ float den[64];
    const int t   = threadIdx.x;
    const int stb = blockIdx.x;
    const int bh  = blockIdx.y;
    const int b   = bh >> 4;
    const int h64 = (bh & 15) * 64;
    const int s0  = stb * 64;
    const int tm  = t >> 4, tn = t & 15;
    const int sr  = tm * 4, cn = tn * 4;

    #pragma unroll
    for (int i = 0; i < 4; ++i) {
        const int row = tm + 16 * i;
        *(float4*)&Qt[row][cn] =
            *(const float4*)&Qp[((size_t)(b * cS + s0 + row)) * cE + h64 + cn];
    }

    float num[4][4] = {};
    float dacc = 0.f;

    for (int mc = 0; mc < 4; ++mc) {
        const int m0 = mc * 64;
        __syncthreads();
        #pragma unroll
        for (int i = 0; i < 4; ++i) {
            const int lin = t + 256 * i;
            const int d   = lin >> 4;
            const int m4  = (lin & 15) * 4;
            *(float4*)&Wf[d][m4] = *(const float4*)&Wfeat[d * cM + m0 + m4];
        }
        #pragma unroll
        for (int i = 0; i < 4; ++i) {
            const int row = tm + 16 * i;
            const size_t o0 = ((size_t)bh * cM + m0 + row) * cD + cn;
            const size_t o1 = ((size_t)(32 + bh) * cM + m0 + row) * cD + cn;
            const float4 a = *(const float4*)&kvpart[o0];
            const float4 c = *(const float4*)&kvpart[o1];
            float4 v; v.x = a.x + c.x; v.y = a.y + c.y; v.z = a.z + c.z; v.w = a.w + c.w;
            *(float4*)&KV[row][cn] = v;
        }
        if (t < 64)
            zl[t] = zpart[(size_t)bh * cM + m0 + t] + zpart[(size_t)(32 + bh) * cM + m0 + t];
        __syncthreads();
        float4 p0 = {0,0,0,0}, p1 = {0,0,0,0}, p2 = {0,0,0,0}, p3 = {0,0,0,0};
        #pragma unroll 8
        for (int d = 0; d < 64; ++d) {
            const float4 wv = *(const float4*)&Wf[d][cn];
            const float q0 = Qt[sr + 0][d], q1 = Qt[sr + 1][d];
            const float q2 = Qt[sr + 2][d], q3 = Qt[sr + 3][d];
            p0.x = fmaf(q0, wv.x, p0.x); p0.y = fmaf(q0, wv.y, p0.y);
            p0.z = fmaf(q0, wv.z, p0.z); p0.w = fmaf(q0, wv.w, p0.w);
            p1.x = fmaf(q1, wv.x, p1.x); p1.y = fmaf(q1, wv.y, p1.y);
            p1.z = fmaf(q1, wv.z, p1.z); p1.w = fmaf(q1, wv.w, p1.w);
            p2.x = fmaf(q2, wv.x, p2.x); p2.y = fmaf(q2, wv.y, p2.y);
            p2.z = fmaf(q2, wv.z, p2.z); p2.w = fmaf(q2, wv.w, p2.w);
            p3.x = fmaf(q3, wv.x, p3.x); p3.y = fmaf(q3, wv.y, p3.y);
            p3.z = fmaf(q3, wv.z, p3.z); p3.w = fmaf(q3, wv.w, p3.w);
        }
        p0.x = fmaxf(p0.x, 0.f) + cEPS; p0.y = fmaxf(p0.y, 0.f) + cEPS;
        p0.z = fmaxf(p0.z, 0.f) + cEPS; p0.w = fmaxf(p0.w, 0.f) + cEPS;
        p1.x = fmaxf(p1.x, 0.f) + cEPS; p1.y = fmaxf(p1.y, 0.f) + cEPS;
        p1.z = fmaxf(p1.z, 0.f) + cEPS; p1.w = fmaxf(p1.w, 0.f) + cEPS;
        p2.x = fmaxf(p2.x, 0.f) + cEPS; p2.y = fmaxf(p2.y, 0.f) + cEPS;
        p2.z = fmaxf(p2.z, 0.f) + cEPS; p2.w = fmaxf(p2.w, 0.f) + cEPS;
        p3.x = fmaxf(p3.x, 0.f) + cEPS; p3.y = fmaxf(p3.y, 0.f) + cEPS;
        p3.z = fmaxf(p3.z, 0.f) + cEPS; p3.w = fmaxf(p3.w, 0.f) + cEPS;
        *(float4*)&Ph[sr + 0][cn] = p0;
        *(float4*)&Ph[sr + 1][cn] = p1;
        *(float4*)&Ph[sr + 2][cn] = p2;
        *(float4*)&Ph[sr + 3][cn] = p3;
        __syncthreads();
        #pragma unroll 8
        for (int mm = 0; mm < 64; ++mm) {
            const float4 kvv = *(const float4*)&KV[mm][cn];
            const float a0 = Ph[sr + 0][mm], a1 = Ph[sr + 1][mm];
            const float a2 = Ph[sr + 2][mm], a3 = Ph[sr + 3][mm];
            num[0][0] = fmaf(a0, kvv.x, num[0][0]); num[0][1] = fmaf(a0, kvv.y, num[0][1]);
            num[0][2] = fmaf(a0, kvv.z, num[0][2]); num[0][3] = fmaf(a0, kvv.w, num[0][3]);
            num[1][0] = fmaf(a1, kvv.x, num[1][0]); num[1][1] = fmaf(a1, kvv.y, num[1][1]);
            num[1][2] = fmaf(a1, kvv.z, num[1][2]); num[1][3] = fmaf(a1, kvv.w, num[1][3]);
            num[2][0] = fmaf(a2, kvv.x, num[2][0]); num[2][1] = fmaf(a2, kvv.y, num[2][1]);
            num[2][2] = fmaf(a2, kvv.z, num[2][2]); num[2][3] = fmaf(a2, kvv.w, num[2][3]);
            num[3][0] = fmaf(a3, kvv.x, num[3][0]); num[3][1] = fmaf(a3, kvv.y, num[3][1]);
            num[3][2] = fmaf(a3, kvv.z, num[3][2]); num[3][3] = fmaf(a3, kvv.w, num[3][3]);
        }
        if (t < 64) {
            float a = 0.f;
            #pragma unroll
            for (int m4 = 0; m4 < 64; m4 += 4) {
                const float4 ph = *(const float4*)&Ph[t][m4];
                const float4 zz = *(const float4*)&zl[m4];
                a = fmaf(ph.x, zz.x, a); a = fmaf(ph.y, zz.y, a);
                a = fmaf(ph.z, zz.z, a); a = fmaf(ph.w, zz.w, a);
            }
            dacc += a;
        }
    }
    __syncthreads();
    if (t < 64) den[t] = dacc + cEPS;
    __syncthreads();
    #pragma unroll
    for (int i = 0; i < 4; ++i) {
        const float di = 1.f / den[sr + i];
        float4 v;
        v.x = num[i][0] * di; v.y = num[i][1] * di;
        v.z = num[i][2] * di; v.w = num[i][3] * di;
        *(float4*)&Ap[((size_t)(b * cS + s0 + sr + i)) * cE + h64 + cn] = v;
    }
}

// ---------------------------------------------------------------------------
// Gate (unchanged)
// ---------------------------------------------------------------------------
__global__ __launch_bounds__(256)
void gate_avg(const float* __restrict__ x, double* __restrict__ avgpart)
{
    const int i  = blockIdx.x * 256 + threadIdx.x;    // 0..2047: (b,e)
    const int sc = blockIdx.y;                        // 0..15
    const int b  = i >> 10, e = i & 1023;
    double acc = 0.0;
    const int sEnd = sc * 128 + 128;
    for (int s = sc * 128; s < sEnd; ++s)
        acc += (double)x[((size_t)(b * cS + s)) * cE + e];
    avgpart[(size_t)sc * 2048 + i] = acc;
}

__global__ void gate_final(const double* __restrict__ avgpart, const float* __restrict__ Wg,
                           const float* __restrict__ bg, float* __restrict__ gates)
{
    const int t = threadIdx.x;
    const int b = t >> 6, lane = t & 63;
    float l0 = 0.f, l1 = 0.f;
    for (int e = lane; e < cE; e += 64) {
        double s = 0.0;
        #pragma unroll
        for (int sc = 0; sc < 16; ++sc)
            s += avgpart[(size_t)sc * 2048 + b * 1024 + e];
        const float a = (float)(s / (double)cS);
        l0 = fmaf(a, Wg[e * 2 + 0], l0);
        l1 = fmaf(a, Wg[e * 2 + 1], l1);
    }
    for (int off = 32; off >= 1; off >>= 1) {
        l0 += __shfl_down(l0, off);
        l1 += __shfl_down(l1, off);
    }
    if (lane == 0) {
        l0 += bg[0]; l1 += bg[1];
        const float m = fmaxf(l0, l1);
        const float e0 = expf(l0 - m), e1 = expf(l1 - m);
        const float s = e0 + e1;
        gates[b * 2 + 0] = e0 / s;
        gates[b * 2 + 1] = e1 / s;
    }
}

// ---------------------------------------------------------------------------
extern "C" void kernel_launch(void* const* d_in, const int* in_sizes, int n_in,
                              void* d_out, int out_size, void* d_ws, size_t ws_size,
                              hipStream_t stream)
{
    (void)in_sizes; (void)n_in; (void)out_size; (void)ws_size;
    const float* x     = (const float*)d_in[0];
    const float* Wq_s  = (const float*)d_in[1];
    const float* Wk_s  = (const float*)d_in[2];
    const float* Wv_s  = (const float*)d_in[3];
    const float* Wo_s  = (const float*)d_in[4];
    const float* bq_s  = (const float*)d_in[5];
    const float* bk_s  = (const float*)d_in[6];
    const float* bv_s  = (const float*)d_in[7];
    const float* bo_s  = (const float*)d_in[8];
    const float* Wq_p  = (const float*)d_in[9];
    const float* Wk_p  = (const float*)d_in[10];
    const float* Wv_p  = (const float*)d_in[11];
    const float* Wo_p  = (const float*)d_in[12];
    const float* bo_p  = (const float*)d_in[13];
    const float* Wfeat = (const float*)d_in[14];
    const float* Wg    = (const float*)d_in[15];
    const float* bg    = (const float*)d_in[16];

    float* ws = (float*)d_ws;
    const size_t NRE = (size_t)cB * cS * cE;
    float* Qs    = ws;              // later: Qp
    float* Ks    = Qs + NRE;        // later: Kp
    float* KsT   = Ks + NRE;        // sparse: Khi (u16); later: Apout
    float* Vs    = KsT + NRE;       // later: Vp
    float* Asout = Vs + NRE;
    float* kvpart = Asout + NRE;                           // 2*32*256*64
    float* zpart  = kvpart + (size_t)2 * 32 * cM * cD;     // 2*32*256
    double* avgpart = (double*)(zpart + (size_t)2 * 32 * cM);  // 16*2048 doubles
    float* gates = (float*)(avgpart + (size_t)16 * 2048);  // 4
    unsigned short* wthi  = (unsigned short*)(gates + 16); // 1M ushorts (scratch, reused)
    unsigned short* wtlo  = wthi + (size_t)cE * cE;
    unsigned short* wo1hi = wtlo + (size_t)cE * cE;        // Wo_s split (persistent)
    unsigned short* wo1lo = wo1hi + (size_t)cE * cE;
    unsigned short* wo2hi = wo1lo + (size_t)cE * cE;       // Wo_p split (persistent)
    unsigned short* wo2lo = wo2hi + (size_t)cE * cE;
    unsigned short* gcidx = wo2lo + (size_t)cE * cE;       // 65536 rows * 128 u16 = 16 MB
    int* gcnt = (int*)(gcidx + (size_t)65536 * 128);       // 65536 ints

    unsigned short* Khi = (unsigned short*)KsT;            // NRE ushorts (8 MB)

    // ---- output-weight splits (independent of everything else) ----
    conv_wT<<<dim3(16, 16), 256, 0, stream>>>(Wo_s, wo1hi, wo1lo);
    conv_wT<<<dim3(16, 16), 256, 0, stream>>>(Wo_p, wo2hi, wo2lo);

    // ---- sparse branch: fused BLAS-mimic fp32 Q+K (+Khi), MFMA V ----
    gemm_qk2_blas<<<dim3(16, 64), 256, 0, stream>>>(x, Wq_s, Wk_s, bq_s, bk_s,
                                                    Qs, Ks, Khi, cE, cE);
    conv_wT<<<dim3(16, 16), 256, 0, stream>>>(Wv_s, wthi, wtlo);
    gemm_hilo<<<dim3(16, 32), 256, 0, stream>>>(x, wthi, wtlo, bv_s, Vs);
    sparse_sel<<<dim3(128, 32), 256, 0, stream>>>(Qs, Khi, gcidx, gcnt);
    sparse_att<<<dim3(256, 32), 256, 0, stream>>>(Qs, gcidx, gcnt, Ks, Vs, Asout);

    // ---- performer branch (reuses buffers) ----
    float* Qp    = Qs;
    float* Kp    = Ks;
    float* Vp    = Vs;
    float* Apout = KsT;
    conv_wT<<<dim3(16, 16), 256, 0, stream>>>(Wq_p, wthi, wtlo);
    gemm_hilo<<<dim3(16, 32), 256, 0, stream>>>(x, wthi, wtlo, nullptr, Qp);
    conv_wT<<<dim3(16, 16), 256, 0, stream>>>(Wk_p, wthi, wtlo);
    gemm_hilo<<<dim3(16, 32), 256, 0, stream>>>(x, wthi, wtlo, nullptr, Kp);
    conv_wT<<<dim3(16, 16), 256, 0, stream>>>(Wv_p, wthi, wtlo);
    gemm_hilo<<<dim3(16, 32), 256, 0, stream>>>(x, wthi, wtlo, nullptr, Vp);
    perf_kv<<<dim3(8, 32), 256, 0, stream>>>(Kp, Vp, Wfeat, kvpart, zpart);
    perf_numden<<<dim3(32, 32), 256, 0, stream>>>(Qp, Wfeat, kvpart, zpart, Apout);

    // ---- gate + fused MFMA output ----
    gate_avg<<<dim3(8, 16), 256, 0, stream>>>(x, avgpart);
    gate_final<<<dim3(1), 128, 0, stream>>>(avgpart, Wg, bg, gates);
    out_gemm_hilo<<<dim3(16, 32), 256, 0, stream>>>(Asout, Apout,
                                                    wo1hi, wo1lo, wo2hi, wo2lo,
                                                    bo_s, bo_p, gates,
                                                    (float*)d_out);
}

// Round 18
// 1258.420 us; speedup vs baseline: 1.0928x; 1.0707x over previous
//
#include <hip/hip_runtime.h>

// ---------------------------------------------------------------------------
// HybridThoughtAwareAttention  (B=2,S=2048,E=1024,H=16,D=64,K_TOP=64,M=256)
// Round 25: combine the two independently-verified sparse_sel improvements:
//   (a) 512-thread phase A (8 waves x 8 tiles, su[8][4]=32 VGPR, no scratch
//       spill — round 21, WRITE 170->10.5 MB measured), and
//   (b) wave-parallel radix-select scans (round 24, serial-scan pin removed,
//       -13 us measured).
// Round 24's counters show sparse_sel moves 337 MB at 1.0 TB/s (dur*BW =
// FETCH+WRITE) — traffic-latency bound, ~300 MB of it spill. With the scan
// pin gone, removing the spill is the remaining lever. Scans now cover 2
// rows per wave (8 waves). Identical thresholds/candidates => same output.
// All other kernels byte-identical to round 24.
// ---------------------------------------------------------------------------

constexpr int cB = 2, cS = 2048, cE = 1024, cH = 16, cD = 64, cKTOP = 64, cM = 256;
constexpr float cEPS = 1e-6f;

typedef _Float16 half8 __attribute__((ext_vector_type(8)));
typedef float f32x16 __attribute__((ext_vector_type(16)));

__device__ __forceinline__ unsigned int f2key(float f) {    // monotone f32->u32
    unsigned int u = __float_as_uint(f);
    return (u & 0x80000000u) ? ~u : (u | 0x80000000u);
}

__device__ __forceinline__ unsigned short h2u(_Float16 h) {
    union { _Float16 h; unsigned short u; } x; x.h = h; return x.u;
}

__device__ __forceinline__ half8 ld_half8(const unsigned short* p) {
    union { uint4 u; half8 h; } x;
    x.u = *(const uint4*)p;
    return x.h;
}

// ---------------------------------------------------------------------------
// Fused OpenBLAS-mimicking fp32 GEMM for Qs AND Ks (unchanged).
// ---------------------------------------------------------------------------
__global__ __launch_bounds__(256)
void gemm_qk2_blas(const float* __restrict__ A,
                   const float* __restrict__ Wq,
                   const float* __restrict__ Wk,
                   const float* __restrict__ bq,
                   const float* __restrict__ bk_,
                   float* __restrict__ Cq,
                   float* __restrict__ Ck,
                   unsigned short* __restrict__ khi,
                   int K, int N)
{
    __shared__ __align__(16) float As[16][68];
    __shared__ __align__(16) float Bq[16][68];
    __shared__ __align__(16) float Bk[16][68];
    const int t  = threadIdx.x;
    const int r0 = blockIdx.y * 64;
    const int c0 = blockIdx.x * 64;
    const int tm = t >> 4, tn = t & 15;
    float paccQ[4][4] = {};
    float caccQ[4][4] = {};
    float paccK[4][4] = {};
    float caccK[4][4] = {};

    const int ar = t >> 2, ak = (t & 3) * 4;
    const int bk = t >> 4, bc = (t & 15) * 4;

    for (int k0 = 0; k0 < K; k0 += 16) {
        const float4 av  = *(const float4*)(A  + (size_t)(r0 + ar) * K + (k0 + ak));
        const float4 bqv = *(const float4*)(Wq + (size_t)(k0 + bk) * N + (c0 + bc));
        const float4 bkv = *(const float4*)(Wk + (size_t)(k0 + bk) * N + (c0 + bc));
        As[ak + 0][ar] = av.x;
        As[ak + 1][ar] = av.y;
        As[ak + 2][ar] = av.z;
        As[ak + 3][ar] = av.w;
        *(float4*)&Bq[bk][bc] = bqv;
        *(float4*)&Bk[bk][bc] = bkv;
        __syncthreads();
        #pragma unroll
        for (int kk = 0; kk < 16; ++kk) {
            const float4 a4  = *(const float4*)&As[kk][tm * 4];
            const float4 q4  = *(const float4*)&Bq[kk][tn * 4];
            const float4 k4  = *(const float4*)&Bk[kk][tn * 4];
            const float a[4]  = {a4.x, a4.y, a4.z, a4.w};
            const float bqr[4] = {q4.x, q4.y, q4.z, q4.w};
            const float bkr[4] = {k4.x, k4.y, k4.z, k4.w};
            #pragma unroll
            for (int i = 0; i < 4; ++i)
                #pragma unroll
                for (int j = 0; j < 4; ++j) {
                    paccQ[i][j] = fmaf(a[i], bqr[j], paccQ[i][j]);
                    paccK[i][j] = fmaf(a[i], bkr[j], paccK[i][j]);
                }
        }
        __syncthreads();
        const int kn = k0 + 16;
        if (kn == 384 || kn == 768 || kn == K) {   // OpenBLAS KC=384 panel flush
            #pragma unroll
            for (int i = 0; i < 4; ++i)
                #pragma unroll
                for (int j = 0; j < 4; ++j) {
                    caccQ[i][j] = caccQ[i][j] + paccQ[i][j];
                    paccQ[i][j] = 0.f;
                    caccK[i][j] = caccK[i][j] + paccK[i][j];
                    paccK[i][j] = 0.f;
                }
        }
    }
    #pragma unroll
    for (int i = 0; i < 4; ++i) {
        const int r = r0 + tm * 4 + i;
        const int c = c0 + tn * 4;
        float4 vq;
        vq.x = caccQ[i][0] + bq[c + 0];
        vq.y = caccQ[i][1] + bq[c + 1];
        vq.z = caccQ[i][2] + bq[c + 2];
        vq.w = caccQ[i][3] + bq[c + 3];
        *(float4*)&Cq[(size_t)r * N + c] = vq;
        float4 vk;
        vk.x = caccK[i][0] + bk_[c + 0];
        vk.y = caccK[i][1] + bk_[c + 1];
        vk.z = caccK[i][2] + bk_[c + 2];
        vk.w = caccK[i][3] + bk_[c + 3];
        *(float4*)&Ck[(size_t)r * N + c] = vk;
        ushort4 hs;
        hs.x = h2u((_Float16)vk.x);
        hs.y = h2u((_Float16)vk.y);
        hs.z = h2u((_Float16)vk.z);
        hs.w = h2u((_Float16)vk.w);
        *(ushort4*)&khi[(size_t)r * N + c] = hs;
    }
}

// ---------------------------------------------------------------------------
// Weight prep for hi/lo MFMA GEMM: W (K x N, fp32) -> WT hi/lo (N x K, f16).
// ---------------------------------------------------------------------------
__global__ __launch_bounds__(256)
void conv_wT(const float* __restrict__ W,
             unsigned short* __restrict__ wthi,
             unsigned short* __restrict__ wtlo)
{
    __shared__ float tile[64][68];
    const int t  = threadIdx.x;
    const int k0 = blockIdx.y * 64;
    const int n0 = blockIdx.x * 64;
    const int r  = t >> 4, c4 = (t & 15) * 4;
    #pragma unroll
    for (int i = 0; i < 4; ++i) {
        const int k = r + 16 * i;
        const float4 v = *(const float4*)&W[(size_t)(k0 + k) * cE + n0 + c4];
        tile[k][c4 + 0] = v.x; tile[k][c4 + 1] = v.y;
        tile[k][c4 + 2] = v.z; tile[k][c4 + 3] = v.w;
    }
    __syncthreads();
    #pragma unroll
    for (int i = 0; i < 4; ++i) {
        const int n = r + 16 * i;
        unsigned int hp[2], lp[2];
        #pragma unroll
        for (int p = 0; p < 2; ++p) {
            unsigned short hh[2], ll[2];
            #pragma unroll
            for (int j = 0; j < 2; ++j) {
                const float f = tile[c4 + p * 2 + j][n];
                const _Float16 h = (_Float16)f;
                hh[j] = h2u(h);
                ll[j] = h2u((_Float16)(f - (float)h));
            }
            hp[p] = (unsigned int)hh[0] | ((unsigned int)hh[1] << 16);
            lp[p] = (unsigned int)ll[0] | ((unsigned int)ll[1] << 16);
        }
        uint2 hv, lv;
        hv.x = hp[0]; hv.y = hp[1];
        lv.x = lp[0]; lv.y = lp[1];
        *(uint2*)&wthi[(size_t)(n0 + n) * cE + k0 + c4] = hv;
        *(uint2*)&wtlo[(size_t)(n0 + n) * cE + k0 + c4] = lv;
    }
}

// ---------------------------------------------------------------------------
// f16 hi/lo 3-product MFMA GEMM (unchanged).
// ---------------------------------------------------------------------------
__global__ __launch_bounds__(256)
void gemm_hilo(const float* __restrict__ A,
               const unsigned short* __restrict__ wthi,
               const unsigned short* __restrict__ wtlo,
               const float* __restrict__ bias,
               float* __restrict__ C)
{
    __shared__ __align__(16) unsigned short Ah[128][24];   // 24 = 16 + 8 pad
    __shared__ __align__(16) unsigned short Al[128][24];
    __shared__ __align__(16) unsigned short Bh[64][24];
    __shared__ __align__(16) unsigned short Bl[64][24];

    const int t    = threadIdx.x;
    const int lane = t & 63, wave = t >> 6;
    const int wr   = wave >> 1, wc = wave & 1;
    const int r0   = blockIdx.y * 128, c0 = blockIdx.x * 64;
    const int fr   = lane & 31, g5 = lane >> 5;

    const int arow = t >> 1, aka = (t & 1) * 8;
    const int bsel = t >> 7;                 // waves 0,1: hi; waves 2,3: lo
    const int brow = (t & 127) >> 1, bkb = (t & 1) * 8;
    const unsigned short* wsrc = bsel ? wtlo : wthi;

    f32x16 acc0 = {0.f,0.f,0.f,0.f,0.f,0.f,0.f,0.f,0.f,0.f,0.f,0.f,0.f,0.f,0.f,0.f};
    f32x16 acc1 = {0.f,0.f,0.f,0.f,0.f,0.f,0.f,0.f,0.f,0.f,0.f,0.f,0.f,0.f,0.f,0.f};

    for (int k0 = 0; k0 < cE; k0 += 16) {
        const float4 x0 = *(const float4*)&A[(size_t)(r0 + arow) * cE + k0 + aka];
        const float4 x1 = *(const float4*)&A[(size_t)(r0 + arow) * cE + k0 + aka + 4];
        const float xf[8] = {x0.x, x0.y, x0.z, x0.w, x1.x, x1.y, x1.z, x1.w};
        unsigned int hw[4], lw[4];
        #pragma unroll
        for (int p = 0; p < 4; ++p) {
            unsigned short hh[2], ll[2];
            #pragma unroll
            for (int j = 0; j < 2; ++j) {
                const float f = xf[p * 2 + j];
                const _Float16 h = (_Float16)f;
                hh[j] = h2u(h);
                ll[j] = h2u((_Float16)(f - (float)h));
            }
            hw[p] = (unsigned int)hh[0] | ((unsigned int)hh[1] << 16);
            lw[p] = (unsigned int)ll[0] | ((unsigned int)ll[1] << 16);
        }
        uint4 hv, lv;
        hv.x = hw[0]; hv.y = hw[1]; hv.z = hw[2]; hv.w = hw[3];
        lv.x = lw[0]; lv.y = lw[1]; lv.z = lw[2]; lv.w = lw[3];
        *(uint4*)&Ah[arow][aka] = hv;
        *(uint4*)&Al[arow][aka] = lv;

        const uint4 wv = *(const uint4*)&wsrc[(size_t)(c0 + brow) * cE + k0 + bkb];
        if (bsel) *(uint4*)&Bl[brow][bkb] = wv;
        else      *(uint4*)&Bh[brow][bkb] = wv;
        __syncthreads();

        const half8 a0h = ld_half8(&Ah[wr * 64 + fr][g5 * 8]);
        const half8 a0l = ld_half8(&Al[wr * 64 + fr][g5 * 8]);
        const half8 a1h = ld_half8(&Ah[wr * 64 + 32 + fr][g5 * 8]);
        const half8 a1l = ld_half8(&Al[wr * 64 + 32 + fr][g5 * 8]);
        const half8 bh  = ld_half8(&Bh[wc * 32 + fr][g5 * 8]);
        const half8 bl  = ld_half8(&Bl[wc * 32 + fr][g5 * 8]);

        acc0 = __builtin_amdgcn_mfma_f32_32x32x16_f16(a0l, bh, acc0, 0, 0, 0);
        acc0 = __builtin_amdgcn_mfma_f32_32x32x16_f16(a0h, bl, acc0, 0, 0, 0);
        acc0 = __builtin_amdgcn_mfma_f32_32x32x16_f16(a0h, bh, acc0, 0, 0, 0);
        acc1 = __builtin_amdgcn_mfma_f32_32x32x16_f16(a1l, bh, acc1, 0, 0, 0);
        acc1 = __builtin_amdgcn_mfma_f32_32x32x16_f16(a1h, bl, acc1, 0, 0, 0);
        acc1 = __builtin_amdgcn_mfma_f32_32x32x16_f16(a1h, bh, acc1, 0, 0, 0);
        __syncthreads();
    }

    const int col = c0 + wc * 32 + fr;
    const float bv = bias ? bias[col] : 0.f;
    #pragma unroll
    for (int rg = 0; rg < 16; ++rg) {
        const int row = r0 + wr * 64 + (rg & 3) + 8 * (rg >> 2) + 4 * g5;
        C[(size_t)row * cE + col] = acc0[rg] + bv;
    }
    #pragma unroll
    for (int rg = 0; rg < 16; ++rg) {
        const int row = r0 + wr * 64 + 32 + (rg & 3) + 8 * (rg >> 2) + 4 * g5;
        C[(size_t)row * cE + col] = acc1[rg] + bv;
    }
}

// ---------------------------------------------------------------------------
// Fused output GEMM, hi/lo MFMA (unchanged).
// ---------------------------------------------------------------------------
__global__ __launch_bounds__(256)
void out_gemm_hilo(const float* __restrict__ As_, const float* __restrict__ Ap_,
                   const unsigned short* __restrict__ w1hi,
                   const unsigned short* __restrict__ w1lo,
                   const unsigned short* __restrict__ w2hi,
                   const unsigned short* __restrict__ w2lo,
                   const float* __restrict__ bos, const float* __restrict__ bop,
                   const float* __restrict__ gates, float* __restrict__ out)
{
    __shared__ __align__(16) unsigned short A1h[128][24], A1l[128][24];
    __shared__ __align__(16) unsigned short A2h[128][24], A2l[128][24];
    __shared__ __align__(16) unsigned short B1h[64][24],  B1l[64][24];
    __shared__ __align__(16) unsigned short B2h[64][24],  B2l[64][24];

    const int t    = threadIdx.x;
    const int lane = t & 63, wave = t >> 6;
    const int wr   = wave >> 1, wc = wave & 1;
    const int r0   = blockIdx.y * 128, c0 = blockIdx.x * 64;
    const int fr   = lane & 31, g5 = lane >> 5;
    const int b    = r0 >> 11;
    const float gs = gates[b * 2 + 0], gp = gates[b * 2 + 1];

    const int arow = t >> 1, aka = (t & 1) * 8;
    const int bsel = t >> 7;
    const int brow = (t & 127) >> 1, bkb = (t & 1) * 8;
    const unsigned short* s1 = bsel ? w1lo : w1hi;
    const unsigned short* s2 = bsel ? w2lo : w2hi;

    f32x16 acc0 = {0.f,0.f,0.f,0.f,0.f,0.f,0.f,0.f,0.f,0.f,0.f,0.f,0.f,0.f,0.f,0.f};
    f32x16 acc1 = {0.f,0.f,0.f,0.f,0.f,0.f,0.f,0.f,0.f,0.f,0.f,0.f,0.f,0.f,0.f,0.f};

    for (int k0 = 0; k0 < cE; k0 += 16) {
        {
            const float4 x0 = *(const float4*)&As_[(size_t)(r0 + arow) * cE + k0 + aka];
            const float4 x1 = *(const float4*)&As_[(size_t)(r0 + arow) * cE + k0 + aka + 4];
            const float xf[8] = {x0.x * gs, x0.y * gs, x0.z * gs, x0.w * gs,
                                 x1.x * gs, x1.y * gs, x1.z * gs, x1.w * gs};
            unsigned int hw[4], lw[4];
            #pragma unroll
            for (int p = 0; p < 4; ++p) {
                unsigned short hh[2], ll[2];
                #pragma unroll
                for (int j = 0; j < 2; ++j) {
                    const float f = xf[p * 2 + j];
                    const _Float16 h = (_Float16)f;
                    hh[j] = h2u(h);
                    ll[j] = h2u((_Float16)(f - (float)h));
                }
                hw[p] = (unsigned int)hh[0] | ((unsigned int)hh[1] << 16);
                lw[p] = (unsigned int)ll[0] | ((unsigned int)ll[1] << 16);
            }
            uint4 hv, lv;
            hv.x = hw[0]; hv.y = hw[1]; hv.z = hw[2]; hv.w = hw[3];
            lv.x = lw[0]; lv.y = lw[1]; lv.z = lw[2]; lv.w = lw[3];
            *(uint4*)&A1h[arow][aka] = hv;
            *(uint4*)&A1l[arow][aka] = lv;
        }
        {
            const float4 x0 = *(const float4*)&Ap_[(size_t)(r0 + arow) * cE + k0 + aka];
            const float4 x1 = *(const float4*)&Ap_[(size_t)(r0 + arow) * cE + k0 + aka + 4];
            const float xf[8] = {x0.x * gp, x0.y * gp, x0.z * gp, x0.w * gp,
                                 x1.x * gp, x1.y * gp, x1.z * gp, x1.w * gp};
            unsigned int hw[4], lw[4];
            #pragma unroll
            for (int p = 0; p < 4; ++p) {
                unsigned short hh[2], ll[2];
                #pragma unroll
                for (int j = 0; j < 2; ++j) {
                    const float f = xf[p * 2 + j];
                    const _Float16 h = (_Float16)f;
                    hh[j] = h2u(h);
                    ll[j] = h2u((_Float16)(f - (float)h));
                }
                hw[p] = (unsigned int)hh[0] | ((unsigned int)hh[1] << 16);
                lw[p] = (unsigned int)ll[0] | ((unsigned int)ll[1] << 16);
            }
            uint4 hv, lv;
            hv.x = hw[0]; hv.y = hw[1]; hv.z = hw[2]; hv.w = hw[3];
            lv.x = lw[0]; lv.y = lw[1]; lv.z = lw[2]; lv.w = lw[3];
            *(uint4*)&A2h[arow][aka] = hv;
            *(uint4*)&A2l[arow][aka] = lv;
        }
        {
            const uint4 w1 = *(const uint4*)&s1[(size_t)(c0 + brow) * cE + k0 + bkb];
            if (bsel) *(uint4*)&B1l[brow][bkb] = w1;
            else      *(uint4*)&B1h[brow][bkb] = w1;
            const uint4 w2 = *(const uint4*)&s2[(size_t)(c0 + brow) * cE + k0 + bkb];
            if (bsel) *(uint4*)&B2l[brow][bkb] = w2;
            else      *(uint4*)&B2h[brow][bkb] = w2;
        }
        __syncthreads();

        const half8 b1h = ld_half8(&B1h[wc * 32 + fr][g5 * 8]);
        const half8 b1l = ld_half8(&B1l[wc * 32 + fr][g5 * 8]);
        const half8 b2h = ld_half8(&B2h[wc * 32 + fr][g5 * 8]);
        const half8 b2l = ld_half8(&B2l[wc * 32 + fr][g5 * 8]);
        {
            const half8 a1h = ld_half8(&A1h[wr * 64 + fr][g5 * 8]);
            const half8 a1l = ld_half8(&A1l[wr * 64 + fr][g5 * 8]);
            const half8 a2h = ld_half8(&A2h[wr * 64 + fr][g5 * 8]);
            const half8 a2l = ld_half8(&A2l[wr * 64 + fr][g5 * 8]);
            acc0 = __builtin_amdgcn_mfma_f32_32x32x16_f16(a1l, b1h, acc0, 0, 0, 0);
            acc0 = __builtin_amdgcn_mfma_f32_32x32x16_f16(a1h, b1l, acc0, 0, 0, 0);
            acc0 = __builtin_amdgcn_mfma_f32_32x32x16_f16(a1h, b1h, acc0, 0, 0, 0);
            acc0 = __builtin_amdgcn_mfma_f32_32x32x16_f16(a2l, b2h, acc0, 0, 0, 0);
            acc0 = __builtin_amdgcn_mfma_f32_32x32x16_f16(a2h, b2l, acc0, 0, 0, 0);
            acc0 = __builtin_amdgcn_mfma_f32_32x32x16_f16(a2h, b2h, acc0, 0, 0, 0);
        }
        {
            const half8 a1h = ld_half8(&A1h[wr * 64 + 32 + fr][g5 * 8]);
            const half8 a1l = ld_half8(&A1l[wr * 64 + 32 + fr][g5 * 8]);
            const half8 a2h = ld_half8(&A2h[wr * 64 + 32 + fr][g5 * 8]);
            const half8 a2l = ld_half8(&A2l[wr * 64 + 32 + fr][g5 * 8]);
            acc1 = __builtin_amdgcn_mfma_f32_32x32x16_f16(a1l, b1h, acc1, 0, 0, 0);
            acc1 = __builtin_amdgcn_mfma_f32_32x32x16_f16(a1h, b1l, acc1, 0, 0, 0);
            acc1 = __builtin_amdgcn_mfma_f32_32x32x16_f16(a1h, b1h, acc1, 0, 0, 0);
            acc1 = __builtin_amdgcn_mfma_f32_32x32x16_f16(a2l, b2h, acc1, 0, 0, 0);
            acc1 = __builtin_amdgcn_mfma_f32_32x32x16_f16(a2h, b2l, acc1, 0, 0, 0);
            acc1 = __builtin_amdgcn_mfma_f32_32x32x16_f16(a2h, b2h, acc1, 0, 0, 0);
        }
        __syncthreads();
    }

    const int col = c0 + wc * 32 + fr;
    const float bv = gs * bos[col] + gp * bop[col];
    #pragma unroll
    for (int rg = 0; rg < 16; ++rg) {
        const int row = r0 + wr * 64 + (rg & 3) + 8 * (rg >> 2) + 4 * g5;
        out[(size_t)row * cE + col] = acc0[rg] + bv;
    }
    #pragma unroll
    for (int rg = 0; rg < 16; ++rg) {
        const int row = r0 + wr * 64 + 32 + (rg & 3) + 8 * (rg >> 2) + 4 * g5;
        out[(size_t)row * cE + col] = acc1[rg] + bv;
    }
}

// ---------------------------------------------------------------------------
// Sparse selection: QBLK=16, 512 threads (8 waves x 8 tiles, su[8][4]=32
// VGPR -> no spill), wave-parallel radix-select scans (2 rows per wave).
// Identical thresholds/candidates to all prior variants.
// ---------------------------------------------------------------------------
__global__ __launch_bounds__(512, 4)
void sparse_sel(const float* __restrict__ Q,
                const unsigned short* __restrict__ Khi,
                unsigned short* __restrict__ gcidx,
                int* __restrict__ gcnt)
{
    __shared__ __align__(16) unsigned short Qhi[16][72];  // 2.25 KB
    __shared__ unsigned int hist[16][257];                // 16.4 KB
    __shared__ int cnt[16];
    __shared__ int t16hi[16], rem[16], t16[16];

    const int t   = threadIdx.x;
    const int bh  = blockIdx.y;
    const int b   = bh >> 4;
    const int h64 = (bh & 15) * 64;
    const int q0  = blockIdx.x * 16;
    const size_t rid0 = (size_t)bh * 2048 + q0;           // linear row id base

    if (t < 256) {
        const int r = t >> 4, c4 = (t & 15) * 4;
        const float4 v =
            *(const float4*)&Q[((size_t)(b * cS + q0 + r)) * cE + h64 + c4];
        const float f[4] = {v.x, v.y, v.z, v.w};
        #pragma unroll
        for (int i = 0; i < 4; ++i)
            Qhi[r][c4 + i] = h2u((_Float16)f[i]);
    }
    for (int i = t; i < 16 * 257; i += 512) (&hist[0][0])[i] = 0u;
    if (t < 16) cnt[t] = 0;
    __syncthreads();                                               // B1

    const int lane = t & 63;
    const int wv   = t >> 6;            // 0..7, each wave covers 256 keys
    const int col  = lane & 31;
    const int g5   = lane >> 5;
    const int base0 = 4 * g5;           // rows from acc regs 0..3
    const int base1 = 8 + 4 * g5;       // rows from acc regs 4..7

    // ---- phase A: single-product f16 MFMA scores, keys wv*256 .. +256 ----
    half8 ahi[4];
    {
        const int arow = col & 15;      // 16 valid Q rows (dup x2 over 32)
        #pragma unroll
        for (int ks = 0; ks < 4; ++ks)
            ahi[ks] = ld_half8(&Qhi[arow][g5 * 8 + ks * 16]);
    }
    unsigned int su[8][4];              // u16 keys, 8 rows x 8 tiles
    {
        const size_t kbase = ((size_t)(b * cS + wv * 256 + col)) * cE + h64;
        #pragma unroll
        for (int tl = 0; tl < 8; ++tl) {
            const unsigned short* kh = Khi + kbase + (size_t)tl * 32 * cE;
            f32x16 acc = {0.f,0.f,0.f,0.f,0.f,0.f,0.f,0.f,
                          0.f,0.f,0.f,0.f,0.f,0.f,0.f,0.f};
            #pragma unroll
            for (int ks = 0; ks < 4; ++ks) {
                const half8 bh8 = ld_half8(kh + g5 * 8 + ks * 16);
                acc = __builtin_amdgcn_mfma_f32_32x32x16_f16(ahi[ks], bh8, acc, 0, 0, 0);
            }
            unsigned int k[8];
            #pragma unroll
            for (int r = 0; r < 8; ++r)
                k[r] = f2key(acc[r] * 0.125f) >> 16;
            su[tl][0] = k[0] | (k[1] << 16);
            su[tl][1] = k[2] | (k[3] << 16);
            su[tl][2] = k[4] | (k[5] << 16);
            su[tl][3] = k[6] | (k[7] << 16);
            atomicAdd(&hist[base0 + 0][k[0] >> 8], 1u);
            atomicAdd(&hist[base0 + 1][k[1] >> 8], 1u);
            atomicAdd(&hist[base0 + 2][k[2] >> 8], 1u);
            atomicAdd(&hist[base0 + 3][k[3] >> 8], 1u);
            atomicAdd(&hist[base1 + 0][k[4] >> 8], 1u);
            atomicAdd(&hist[base1 + 1][k[5] >> 8], 1u);
            atomicAdd(&hist[base1 + 2][k[6] >> 8], 1u);
            atomicAdd(&hist[base1 + 3][k[7] >> 8], 1u);
        }
    }
    __syncthreads();                                               // B2

    // ---- scan 1 (wave-parallel): wave wv owns rows 2wv, 2wv+1 ----
    #pragma unroll
    for (int rx = 0; rx < 2; ++rx) {
        const int r  = wv * 2 + rx;
        const int b0 = lane * 4;
        const int h0 = (int)hist[r][b0 + 0];
        const int h1 = (int)hist[r][b0 + 1];
        const int h2 = (int)hist[r][b0 + 2];
        const int h3 = (int)hist[r][b0 + 3];
        const int local = h0 + h1 + h2 + h3;
        int s = local;                       // inclusive suffix over lanes
        #pragma unroll
        for (int off = 1; off < 64; off <<= 1) {
            const int v = __shfl_down(s, off);
            if (lane + off < 64) s += v;
        }
        const int above = s - local;         // sum of lanes > lane
        const int T3 = above + h3;
        const int T2 = T3 + h2;
        const int T1 = T2 + h1;
        const int T0 = T1 + h0;
        int cand = -1, candT = 0, candH = 0;
        if      (T3 >= 65) { cand = b0 + 3; candT = T3; candH = h3; }
        else if (T2 >= 65) { cand = b0 + 2; candT = T2; candH = h2; }
        else if (T1 >= 65) { cand = b0 + 1; candT = T1; candH = h1; }
        else if (T0 >= 65) { cand = b0 + 0; candT = T0; candH = h0; }
        int mx = cand;
        #pragma unroll
        for (int off = 32; off >= 1; off >>= 1)
            mx = max(mx, __shfl_xor(mx, off));
        if (cand >= 0 && cand == mx) {
            t16hi[r] = cand;
            rem[r]   = 65 - (candT - candH);
        }
    }
    __syncthreads();                                               // B3
    for (int i = t; i < 16 * 257; i += 512) (&hist[0][0])[i] = 0u;  // pass 2
    __syncthreads();                                               // B3b
    #pragma unroll
    for (int tl = 0; tl < 8; ++tl)
        #pragma unroll
        for (int w = 0; w < 4; ++w) {
            const unsigned int u = su[tl][w];
            const int rlo = (w < 2 ? base0 : base1) + (w & 1) * 2;
            const int rhi = rlo + 1;
            const unsigned int vlo = u & 0xFFFFu;
            const unsigned int vhi = u >> 16;
            if ((int)(vlo >> 8) == t16hi[rlo]) atomicAdd(&hist[rlo][vlo & 255u], 1u);
            if ((int)(vhi >> 8) == t16hi[rhi]) atomicAdd(&hist[rhi][vhi & 255u], 1u);
        }
    __syncthreads();                                               // B4

    // ---- scan 2 (wave-parallel, need = rem[r]) ----
    #pragma unroll
    for (int rx = 0; rx < 2; ++rx) {
        const int r    = wv * 2 + rx;
        const int need = rem[r];
        const int b0   = lane * 4;
        const int h0 = (int)hist[r][b0 + 0];
        const int h1 = (int)hist[r][b0 + 1];
        const int h2 = (int)hist[r][b0 + 2];
        const int h3 = (int)hist[r][b0 + 3];
        const int local = h0 + h1 + h2 + h3;
        int s = local;
        #pragma unroll
        for (int off = 1; off < 64; off <<= 1) {
            const int v = __shfl_down(s, off);
            if (lane + off < 64) s += v;
        }
        const int above = s - local;
        const int T3 = above + h3;
        const int T2 = T3 + h2;
        const int T1 = T2 + h1;
        const int T0 = T1 + h0;
        int cand = -1;
        if      (T3 >= need) cand = b0 + 3;
        else if (T2 >= need) cand = b0 + 2;
        else if (T1 >= need) cand = b0 + 1;
        else if (T0 >= need) cand = b0 + 0;
        int mx = cand;
        #pragma unroll
        for (int off = 32; off >= 1; off >>= 1)
            mx = max(mx, __shfl_xor(mx, off));
        if (cand >= 0 && cand == mx)
            t16[r] = (t16hi[r] << 8) | cand;
    }
    __syncthreads();                                               // B5

    // ---- candidate scan: u16 >= T16 - 3; write straight to global ----
    #pragma unroll
    for (int tl = 0; tl < 8; ++tl) {
        const int key = wv * 256 + tl * 32 + col;
        #pragma unroll
        for (int w = 0; w < 4; ++w) {
            const unsigned int u = su[tl][w];
            const int rlo = (w < 2 ? base0 : base1) + (w & 1) * 2;
            const int rhi = rlo + 1;
            const int v0 = (int)(u & 0xFFFFu);
            const int v1 = (int)(u >> 16);
            if (v0 >= max(t16[rlo] - 3, 0)) {
                const int slot = atomicAdd(&cnt[rlo], 1);
                if (slot < 128) gcidx[(rid0 + rlo) * 128 + slot] = (unsigned short)key;
            }
            if (v1 >= max(t16[rhi] - 3, 0)) {
                const int slot = atomicAdd(&cnt[rhi], 1);
                if (slot < 128) gcidx[(rid0 + rhi) * 128 + slot] = (unsigned short)key;
            }
        }
    }
    __syncthreads();                                               // B6
    if (t < 16) gcnt[rid0 + t] = cnt[t];
}

// ---------------------------------------------------------------------------
// Sparse attention (phases C/D, unchanged): fp64 recompute, ranking, hedge
// weights, unroll-8 PV gather. __launch_bounds__(256,8).
// ---------------------------------------------------------------------------
__global__ __launch_bounds__(256, 8)
void sparse_att(const float* __restrict__ Q,
                const unsigned short* __restrict__ gcidx,
                const int* __restrict__ gcnt,
                const float* __restrict__ Ks, const float* __restrict__ V,
                float* __restrict__ O)
{
    __shared__ float QfT[64][8];                 // 2 KB  (Q transposed)
    __shared__ unsigned short cidx[8][128];      // 2 KB
    __shared__ double cval[8][128];              // 8 KB
    __shared__ float cw[8][128];                 // 4 KB
    __shared__ int cnt[8];
    __shared__ double T64s[8], s65s[8], rowm[8];

    const int t   = threadIdx.x;
    const int bh  = blockIdx.y;
    const int b   = bh >> 4;
    const int h64 = (bh & 15) * 64;
    const int q0  = blockIdx.x * 8;
    const size_t rid0 = ((size_t)bh * 256 + blockIdx.x) * 8;

    if (t < 128) {
        const int r = t >> 4, c4 = (t & 15) * 4;
        const float4 v =
            *(const float4*)&Q[((size_t)(b * cS + q0 + r)) * cE + h64 + c4];
        QfT[c4 + 0][r] = v.x; QfT[c4 + 1][r] = v.y;
        QfT[c4 + 2][r] = v.z; QfT[c4 + 3][r] = v.w;
    }
    // 8 rows x 128 u16 are contiguous in gcidx -> one ushort4 per thread
    ((ushort4*)&cidx[0][0])[t] = ((const ushort4*)&gcidx[rid0 * 128])[t];
    if (t < 8) cnt[t] = gcnt[rid0 + t];
    __syncthreads();                                               // B6'

    const int wv = t >> 6, lane = t & 63;

    // ---- phase C: fp64 recompute, lane = candidate (2 rows per wave) ----
    #pragma unroll
    for (int rx = 0; rx < 2; ++rx) {
        const int rr = wv * 2 + rx;
        const int n = min(cnt[rr], 128);
        for (int c = lane; c < n; c += 64) {
            const int key = cidx[rr][c];
            const float* kp = Ks + ((size_t)(b * cS + key)) * cE + h64;
            double a = 0.0;
            #pragma unroll 4
            for (int d4 = 0; d4 < 64; d4 += 4) {
                const float4 kv = *(const float4*)&kp[d4];
                a = fma((double)QfT[d4 + 0][rr], (double)kv.x, a);
                a = fma((double)QfT[d4 + 1][rr], (double)kv.y, a);
                a = fma((double)QfT[d4 + 2][rr], (double)kv.z, a);
                a = fma((double)QfT[d4 + 3][rr], (double)kv.w, a);
            }
            cval[rr][c] = a * 0.125;
        }
    }
    __syncthreads();                                               // B7

    // ---- ranking: T64 (rank 63), s65 (rank 64), m (rank 0) ----
    #pragma unroll
    for (int rx = 0; rx < 2; ++rx) {
        const int rr = wv * 2 + rx;
        const int n = min(cnt[rr], 128);
        for (int c = lane; c < n; c += 64) {
            const double v = cval[rr][c];
            int rank = 0;
            for (int i = 0; i < n; ++i) rank += (cval[rr][i] > v) ? 1 : 0;
            if (rank == 0)  rowm[rr] = v;
            if (rank == 63) T64s[rr] = v;
            if (rank == 64) s65s[rr] = v;
        }
    }
    __syncthreads();                                               // B8

    // ---- weights: hedge formula (unchanged) ----
    #pragma unroll
    for (int rx = 0; rx < 2; ++rx) {
        const int rr = wv * 2 + rx;
        const int n = min(cnt[rr], 128);
        const double T64 = T64s[rr], s65 = s65s[rr], m = rowm[rr];
        float za = 0.f;
        for (int c = lane; c < n; c += 64) {
            const double v = cval[rr][c];
            if (v >= T64) za += expf((float)(v - m));
        }
        #pragma unroll
        for (int off = 32; off >= 1; off >>= 1)
            za += __shfl_xor(za, off);
        const float g   = (float)(T64 - s65);
        const float gm  = fmaxf(g - 5e-7f, 0.f);
        const float wB  = 0.5f * erfcf(gm * (1.0f / 2.2e-6f));
        const float wA  = 1.f - wB;
        const float e64 = expf((float)(T64 - m));
        const float e65 = expf((float)(s65 - m));
        const float ZB  = za - e64 + e65;
        const float cIn = wA / za + wB / ZB;
        const float c64 = wA / za;
        const float c65 = wB / ZB;
        for (int c = lane; c < n; c += 64) {
            const double v = cval[rr][c];
            float cc = 0.f;
            if (v > T64)       cc = cIn;
            else if (v == T64) cc = c64;
            else if (v == s65) cc = c65;
            cw[rr][c] = (cc != 0.f) ? cc * expf((float)(v - m)) : 0.f;
        }
    }
    __syncthreads();                                               // B9

    // ---- phase D: sparse PV gather, unroll-8 pipelined (same sum order) ----
    #pragma unroll
    for (int rx = 0; rx < 2; ++rx) {
        const int rr = wv * 2 + rx;
        const int n = min(cnt[rr], 128);
        float o = 0.f;
        int j = 0;
        for (; j + 8 <= n; j += 8) {
            float wreg[8];
            int   kreg[8];
            #pragma unroll
            for (int u = 0; u < 8; ++u) {
                wreg[u] = cw[rr][j + u];
                kreg[u] = cidx[rr][j + u];
            }
            float vreg[8];
            #pragma unroll
            for (int u = 0; u < 8; ++u)
                vreg[u] = V[((size_t)(b * cS + kreg[u])) * cE + h64 + lane];
            #pragma unroll
            for (int u = 0; u < 8; ++u)
                o = fmaf(wreg[u], vreg[u], o);
        }
        for (; j < n; ++j)
            o = fmaf(cw[rr][j],
                     V[((size_t)(b * cS + cidx[rr][j])) * cE + h64 + lane], o);
        O[((size_t)(b * cS + q0 + rr)) * cE + h64 + lane] = o;
    }
}

// ---------------------------------------------------------------------------
// Performer kv (unchanged)
// ---------------------------------------------------------------------------
__global__ __launch_bounds__(256)
void perf_kv(const float* __restrict__ Kp, const float* __restrict__ Vp,
             const float* __restrict__ Wfeat,
             float* __restrict__ kvpart, float* __restrict__ zpart)
{
    __shared__ __align__(16) float Wf[64][68];
    __shared__ __align__(16) float Kt[64][68];
    __shared__ __align__(16) float Vt[64][68];
    __shared__ __align__(16) float Ph[64][68];
    const int t    = threadIdx.x;
    const int mc   = blockIdx.x & 3;
    const int sc   = blockIdx.x >> 2;          // 0 or 1
    const int bh   = blockIdx.y;
    const int b    = bh >> 4;
    const int h64  = (bh & 15) * 64;
    const int m0   = mc * 64;
    const int sbase = sc * 1024;

    #pragma unroll
    for (int i = 0; i < 4; ++i) {
        const int lin = t + 256 * i;
        const int d   = lin >> 4;
        const int m4  = (lin & 15) * 4;
        *(float4*)&Wf[d][m4] = *(const float4*)&Wfeat[d * cM + m0 + m4];
    }

    const int tm = t >> 4, tn = t & 15;
    const int sr = tm * 4;
    const int cn = tn * 4;
    float akv[4][4] = {};
    float az = 0.f;

    for (int st = 0; st < 16; ++st) {
        const int s0g = sbase + st * 64;
        __syncthreads();
        #pragma unroll
        for (int i = 0; i < 4; ++i) {
            const int row = tm + 16 * i;
            const size_t base = ((size_t)(b * cS + s0g + row)) * cE + h64 + cn;
            *(float4*)&Kt[row][cn] = *(const float4*)&Kp[base];
            *(float4*)&Vt[row][cn] = *(const float4*)&Vp[base];
        }
        __syncthreads();
        float4 p0 = {0,0,0,0}, p1 = {0,0,0,0}, p2 = {0,0,0,0}, p3 = {0,0,0,0};
        #pragma unroll 8
        for (int d = 0; d < 64; ++d) {
            const float4 wv = *(const float4*)&Wf[d][cn];
            const float k0 = Kt[sr + 0][d], k1 = Kt[sr + 1][d];
            const float k2 = Kt[sr + 2][d], k3 = Kt[sr + 3][d];
            p0.x = fmaf(k0, wv.x, p0.x); p0.y = fmaf(k0, wv.y, p0.y);
            p0.z = fmaf(k0, wv.z, p0.z); p0.w = fmaf(k0, wv.w, p0.w);
            p1.x = fmaf(k1, wv.x, p1.x); p1.y = fmaf(k1, wv.y, p1.y);
            p1.z = fmaf(k1, wv.z, p1.z); p1.w = fmaf(k1, wv.w, p1.w);
            p2.x = fmaf(k2, wv.x, p2.x); p2.y = fmaf(k2, wv.y, p2.y);
            p2.z = fmaf(k2, wv.z, p2.z); p2.w = fmaf(k2, wv.w, p2.w);
            p3.x = fmaf(k3, wv.x, p3.x); p3.y = fmaf(k3, wv.y, p3.y);
            p3.z = fmaf(k3, wv.z, p3.z); p3.w = fmaf(k3, wv.w, p3.w);
        }
        p0.x = fmaxf(p0.x, 0.f) + cEPS; p0.y = fmaxf(p0.y, 0.f) + cEPS;
        p0.z = fmaxf(p0.z, 0.f) + cEPS; p0.w = fmaxf(p0.w, 0.f) + cEPS;
        p1.x = fmaxf(p1.x, 0.f) + cEPS; p1.y = fmaxf(p1.y, 0.f) + cEPS;
        p1.z = fmaxf(p1.z, 0.f) + cEPS; p1.w = fmaxf(p1.w, 0.f) + cEPS;
        p2.x = fmaxf(p2.x, 0.f) + cEPS; p2.y = fmaxf(p2.y, 0.f) + cEPS;
        p2.z = fmaxf(p2.z, 0.f) + cEPS; p2.w = fmaxf(p2.w, 0.f) + cEPS;
        p3.x = fmaxf(p3.x, 0.f) + cEPS; p3.y = fmaxf(p3.y, 0.f) + cEPS;
        p3.z = fmaxf(p3.z, 0.f) + cEPS; p3.w = fmaxf(p3.w, 0.f) + cEPS;
        *(float4*)&Ph[sr + 0][cn] = p0;
        *(float4*)&Ph[sr + 1][cn] = p1;
        *(float4*)&Ph[sr + 2][cn] = p2;
        *(float4*)&Ph[sr + 3][cn] = p3;
        __syncthreads();
        #pragma unroll 8
        for (int ss = 0; ss < 64; ++ss) {
            const float4 pv = *(const float4*)&Ph[ss][sr];
            const float4 vv = *(const float4*)&Vt[ss][cn];
            akv[0][0] = fmaf(pv.x, vv.x, akv[0][0]); akv[0][1] = fmaf(pv.x, vv.y, akv[0][1]);
            akv[0][2] = fmaf(pv.x, vv.z, akv[0][2]); akv[0][3] = fmaf(pv.x, vv.w, akv[0][3]);
            akv[1][0] = fmaf(pv.y, vv.x, akv[1][0]); akv[1][1] = fmaf(pv.y, vv.y, akv[1][1]);
            akv[1][2] = fmaf(pv.y, vv.z, akv[1][2]); akv[1][3] = fmaf(pv.y, vv.w, akv[1][3]);
            akv[2][0] = fmaf(pv.z, vv.x, akv[2][0]); akv[2][1] = fmaf(pv.z, vv.y, akv[2][1]);
            akv[2][2] = fmaf(pv.z, vv.z, akv[2][2]); akv[2][3] = fmaf(pv.z, vv.w, akv[2][3]);
            akv[3][0] = fmaf(pv.w, vv.x, akv[3][0]); akv[3][1] = fmaf(pv.w, vv.y, akv[3][1]);
            akv[3][2] = fmaf(pv.w, vv.z, akv[3][2]); akv[3][3] = fmaf(pv.w, vv.w, akv[3][3]);
        }
        if (t < 64) {
            float a = 0.f;
            #pragma unroll 8
            for (int ss = 0; ss < 64; ++ss) a += Ph[ss][t];
            az += a;
        }
    }
    const size_t obase = ((size_t)(sc * 32 + bh)) * cM + m0;
    #pragma unroll
    for (int i = 0; i < 4; ++i) {
        float4 v; v.x = akv[i][0]; v.y = akv[i][1]; v.z = akv[i][2]; v.w = akv[i][3];
        *(float4*)&kvpart[(obase + sr + i) * cD + cn] = v;
    }
    if (t < 64) zpart[obase + t] = az;
}

// ---------------------------------------------------------------------------
// Performer num/den (unchanged)
// ---------------------------------------------------------------------------
__global__ __launch_bounds__(256)
void perf_numden(const float* __restrict__ Qp, const float* __restrict__ Wfeat,
                 const float* __restrict__ kvpart, const float* __restrict__ zpart,
                 float* __restrict__ Ap)
{
    __shared__ __align__(16) float Wf[64][68];
    __shared__ __align__(16) float Qt[64][68];
    __shared__ __align__(16) float KV[64][68];
    __shared__ __align__(16) float Ph[64][68];
    __shared__ __align__(16) float zl[64];
    __shared__ float den[64];
    const int t   = threadIdx.x;
    const int stb = blockIdx.x;
    const int bh  = blockIdx.y;
    const int b   = bh >> 4;
    const int h64 = (bh & 15) * 64;
    const int s0  = stb * 64;
    const int tm  = t >> 4, tn = t & 15;
    const int sr  = tm * 4, cn = tn * 4;

    #pragma unroll
    for (int i = 0; i < 4; ++i) {
        const int row = tm + 16 * i;
        *(float4*)&Qt[row][cn] =
            *(const float4*)&Qp[((size_t)(b * cS + s0 + row)) * cE + h64 + cn];
    }

    float num[4][4] = {};
    float dacc = 0.f;

    for (int mc = 0; mc < 4; ++mc) {
        const int m0 = mc * 64;
        __syncthreads();
        #pragma unroll
        for (int i = 0; i < 4; ++i) {
            const int lin = t + 256 * i;
            const int d   = lin >> 4;
            const int m4  = (lin & 15) * 4;
            *(float4*)&Wf[d][m4] = *(const float4*)&Wfeat[d * cM + m0 + m4];
        }
        #pragma unroll
        for (int i = 0; i < 4; ++i) {
            const int row = tm + 16 * i;
            const size_t o0 = ((size_t)bh * cM + m0 + row) * cD + cn;
            const size_t o1 = ((size_t)(32 + bh) * cM + m0 + row) * cD + cn;
            const float4 a = *(const float4*)&kvpart[o0];
            const float4 c = *(const float4*)&kvpart[o1];
            float4 v; v.x = a.x + c.x; v.y = a.y + c.y; v.z = a.z + c.z; v.w = a.w + c.w;
            *(float4*)&KV[row][cn] = v;
        }
        if (t < 64)
            zl[t] = zpart[(size_t)bh * cM + m0 + t] + zpart[(size_t)(32 + bh) * cM + m0 + t];
        __syncthreads();
        float4 p0 = {0,0,0,0}, p1 = {0,0,0,0}, p2 = {0,0,0,0}, p3 = {0,0,0,0};
        #pragma unroll 8
        for (int d = 0; d < 64; ++d) {
            const float4 wv = *(const float4*)&Wf[d][cn];
            const float q0 = Qt[sr + 0][d], q1 = Qt[sr + 1][d];
            const float q2 = Qt[sr + 2][d], q3 = Qt[sr + 3][d];
            p0.x = fmaf(q0, wv.x, p0.x); p0.y = fmaf(q0, wv.y, p0.y);
            p0.z = fmaf(q0, wv.z, p0.z); p0.w = fmaf(q0, wv.w, p0.w);
            p1.x = fmaf(q1, wv.x, p1.x); p1.y = fmaf(q1, wv.y, p1.y);
            p1.z = fmaf(q1, wv.z, p1.z); p1.w = fmaf(q1, wv.w, p1.w);
            p2.x = fmaf(q2, wv.x, p2.x); p2.y = fmaf(q2, wv.y, p2.y);
            p2.z = fmaf(q2, wv.z, p2.z); p2.w = fmaf(q2, wv.w, p2.w);
            p3.x = fmaf(q3, wv.x, p3.x); p3.y = fmaf(q3, wv.y, p3.y);
            p3.z = fmaf(q3, wv.z, p3.z); p3.w = fmaf(q3, wv.w, p3.w);
        }
        p0.x = fmaxf(p0.x, 0.f) + cEPS; p0.y = fmaxf(p0.y, 0.f) + cEPS;
        p0.z = fmaxf(p0.z, 0.f) + cEPS; p0.w = fmaxf(p0.w, 0.f) + cEPS;
        p1.x = fmaxf(p1.x, 0.f) + cEPS; p1.y = fmaxf(p1.y, 0.f) + cEPS;
        p1.z = fmaxf(p1.z, 0.f) + cEPS; p1.w = fmaxf(p1.w, 0.f) + cEPS;
        p2.x = fmaxf(p2.x, 0.f) + cEPS; p2.y = fmaxf(p2.y, 0.f) + cEPS;
        p2.z = fmaxf(p2.z, 0.f) + cEPS; p2.w = fmaxf(p2.w, 0.f) + cEPS;
        p3.x = fmaxf(p3.x, 0.f) + cEPS; p3.y = fmaxf(p3.y, 0.f) + cEPS;
        p3.z = fmaxf(p3.z, 0.f) + cEPS; p3.w = fmaxf(p3.w, 0.f) + cEPS;
        *(float4*)&Ph[sr + 0][cn] = p0;
        *(float4*)&Ph[sr + 1][cn] = p1;
        *(float4*)&Ph[sr + 2][cn] = p2;
        *(float4*)&Ph[sr + 3][cn] = p3;
        __syncthreads();
        #pragma unroll 8
        for (int mm = 0; mm < 64; ++mm) {
            const float4 kvv = *(const float4*)&KV[mm][cn];
            const float a0 = Ph[sr + 0][mm], a1 = Ph[sr + 1][mm];
            const float a2 = Ph[sr + 2][mm], a3 = Ph[sr + 3][mm];
            num[0][0] = fmaf(a0, kvv.x, num[0][0]); num[0][1] = fmaf(a0, kvv.y, num[0][1]);
            num[0][2] = fmaf(a0, kvv.z, num[0][2]); num[0][3] = fmaf(a0, kvv.w, num[0][3]);
            num[1][0] = fmaf(a1, kvv.x, num[1][0]); num[1][1] = fmaf(a1, kvv.y, num[1][1]);
            num[1][2] = fmaf(a1, kvv.z, num[1][2]); num[1][3] = fmaf(a1, kvv.w, num[1][3]);
            num[2][0] = fmaf(a2, kvv.x, num[2][0]); num[2][1] = fmaf(a2, kvv.y, num[2][1]);
            num[2][2] = fmaf(a2, kvv.z, num[2][2]); num[2][3] = fmaf(a2, kvv.w, num[2][3]);
            num[3][0] = fmaf(a3, kvv.x, num[3][0]); num[3][1] = fmaf(a3, kvv.y, num[3][1]);
            num[3][2] = fmaf(a3, kvv.z, num[3][2]); num[3][3] = fmaf(a3, kvv.w, num[3][3]);
        }
        if (t < 64) {
            float a = 0.f;
            #pragma unroll
            for (int m4 = 0; m4 < 64; m4 += 4) {
                const float4 ph = *(const float4*)&Ph[t][m4];
                const float4 zz = *(const float4*)&zl[m4];
                a = fmaf(ph.x, zz.x, a); a = fmaf(ph.y, zz.y, a);
                a = fmaf(ph.z, zz.z, a); a = fmaf(ph.w, zz.w, a);
            }
            dacc += a;
        }
    }
    __syncthreads();
    if (t < 64) den[t] = dacc + cEPS;
    __syncthreads();
    #pragma unroll
    for (int i = 0; i < 4; ++i) {
        const float di = 1.f / den[sr + i];
        float4 v;
        v.x = num[i][0] * di; v.y = num[i][1] * di;
        v.z = num[i][2] * di; v.w = num[i][3] * di;
        *(float4*)&Ap[((size_t)(b * cS + s0 + sr + i)) * cE + h64 + cn] = v;
    }
}

// ---------------------------------------------------------------------------
// Gate (unchanged)
// ---------------------------------------------------------------------------
__global__ __launch_bounds__(256)
void gate_avg(const float* __restrict__ x, double* __restrict__ avgpart)
{
    const int i  = blockIdx.x * 256 + threadIdx.x;    // 0..2047: (b,e)
    const int sc = blockIdx.y;                        // 0..15
    const int b  = i >> 10, e = i & 1023;
    double acc = 0.0;
    const int sEnd = sc * 128 + 128;
    for (int s = sc * 128; s < sEnd; ++s)
        acc += (double)x[((size_t)(b * cS + s)) * cE + e];
    avgpart[(size_t)sc * 2048 + i] = acc;
}

__global__ void gate_final(const double* __restrict__ avgpart, const float* __restrict__ Wg,
                           const float* __restrict__ bg, float* __restrict__ gates)
{
    const int t = threadIdx.x;
    const int b = t >> 6, lane = t & 63;
    float l0 = 0.f, l1 = 0.f;
    for (int e = lane; e < cE; e += 64) {
        double s = 0.0;
        #pragma unroll
        for (int sc = 0; sc < 16; ++sc)
            s += avgpart[(size_t)sc * 2048 + b * 1024 + e];
        const float a = (float)(s / (double)cS);
        l0 = fmaf(a, Wg[e * 2 + 0], l0);
        l1 = fmaf(a, Wg[e * 2 + 1], l1);
    }
    for (int off = 32; off >= 1; off >>= 1) {
        l0 += __shfl_down(l0, off);
        l1 += __shfl_down(l1, off);
    }
    if (lane == 0) {
        l0 += bg[0]; l1 += bg[1];
        const float m = fmaxf(l0, l1);
        const float e0 = expf(l0 - m), e1 = expf(l1 - m);
        const float s = e0 + e1;
        gates[b * 2 + 0] = e0 / s;
        gates[b * 2 + 1] = e1 / s;
    }
}

// ---------------------------------------------------------------------------
extern "C" void kernel_launch(void* const* d_in, const int* in_sizes, int n_in,
                              void* d_out, int out_size, void* d_ws, size_t ws_size,
                              hipStream_t stream)
{
    (void)in_sizes; (void)n_in; (void)out_size; (void)ws_size;
    const float* x     = (const float*)d_in[0];
    const float* Wq_s  = (const float*)d_in[1];
    const float* Wk_s  = (const float*)d_in[2];
    const float* Wv_s  = (const float*)d_in[3];
    const float* Wo_s  = (const float*)d_in[4];
    const float* bq_s  = (const float*)d_in[5];
    const float* bk_s  = (const float*)d_in[6];
    const float* bv_s  = (const float*)d_in[7];
    const float* bo_s  = (const float*)d_in[8];
    const float* Wq_p  = (const float*)d_in[9];
    const float* Wk_p  = (const float*)d_in[10];
    const float* Wv_p  = (const float*)d_in[11];
    const float* Wo_p  = (const float*)d_in[12];
    const float* bo_p  = (const float*)d_in[13];
    const float* Wfeat = (const float*)d_in[14];
    const float* Wg    = (const float*)d_in[15];
    const float* bg    = (const float*)d_in[16];

    float* ws = (float*)d_ws;
    const size_t NRE = (size_t)cB * cS * cE;
    float* Qs    = ws;              // later: Qp
    float* Ks    = Qs + NRE;        // later: Kp
    float* KsT   = Ks + NRE;        // sparse: Khi (u16); later: Apout
    float* Vs    = KsT + NRE;       // later: Vp
    float* Asout = Vs + NRE;
    float* kvpart = Asout + NRE;                           // 2*32*256*64
    float* zpart  = kvpart + (size_t)2 * 32 * cM * cD;     // 2*32*256
    double* avgpart = (double*)(zpart + (size_t)2 * 32 * cM);  // 16*2048 doubles
    float* gates = (float*)(avgpart + (size_t)16 * 2048);  // 4
    unsigned short* wthi  = (unsigned short*)(gates + 16); // 1M ushorts (scratch, reused)
    unsigned short* wtlo  = wthi + (size_t)cE * cE;
    unsigned short* wo1hi = wtlo + (size_t)cE * cE;        // Wo_s split (persistent)
    unsigned short* wo1lo = wo1hi + (size_t)cE * cE;
    unsigned short* wo2hi = wo1lo + (size_t)cE * cE;       // Wo_p split (persistent)
    unsigned short* wo2lo = wo2hi + (size_t)cE * cE;
    unsigned short* gcidx = wo2lo + (size_t)cE * cE;       // 65536 rows * 128 u16 = 16 MB
    int* gcnt = (int*)(gcidx + (size_t)65536 * 128);       // 65536 ints

    unsigned short* Khi = (unsigned short*)KsT;            // NRE ushorts (8 MB)

    // ---- output-weight splits (independent of everything else) ----
    conv_wT<<<dim3(16, 16), 256, 0, stream>>>(Wo_s, wo1hi, wo1lo);
    conv_wT<<<dim3(16, 16), 256, 0, stream>>>(Wo_p, wo2hi, wo2lo);

    // ---- sparse branch: fused BLAS-mimic fp32 Q+K (+Khi), MFMA V ----
    gemm_qk2_blas<<<dim3(16, 64), 256, 0, stream>>>(x, Wq_s, Wk_s, bq_s, bk_s,
                                                    Qs, Ks, Khi, cE, cE);
    conv_wT<<<dim3(16, 16), 256, 0, stream>>>(Wv_s, wthi, wtlo);
    gemm_hilo<<<dim3(16, 32), 256, 0, stream>>>(x, wthi, wtlo, bv_s, Vs);
    sparse_sel<<<dim3(128, 32), 512, 0, stream>>>(Qs, Khi, gcidx, gcnt);
    sparse_att<<<dim3(256, 32), 256, 0, stream>>>(Qs, gcidx, gcnt, Ks, Vs, Asout);

    // ---- performer branch (reuses buffers) ----
    float* Qp    = Qs;
    float* Kp    = Ks;
    float* Vp    = Vs;
    float* Apout = KsT;
    conv_wT<<<dim3(16, 16), 256, 0, stream>>>(Wq_p, wthi, wtlo);
    gemm_hilo<<<dim3(16, 32), 256, 0, stream>>>(x, wthi, wtlo, nullptr, Qp);
    conv_wT<<<dim3(16, 16), 256, 0, stream>>>(Wk_p, wthi, wtlo);
    gemm_hilo<<<dim3(16, 32), 256, 0, stream>>>(x, wthi, wtlo, nullptr, Kp);
    conv_wT<<<dim3(16, 16), 256, 0, stream>>>(Wv_p, wthi, wtlo);
    gemm_hilo<<<dim3(16, 32), 256, 0, stream>>>(x, wthi, wtlo, nullptr, Vp);
    perf_kv<<<dim3(8, 32), 256, 0, stream>>>(Kp, Vp, Wfeat, kvpart, zpart);
    perf_numden<<<dim3(32, 32), 256, 0, stream>>>(Qp, Wfeat, kvpart, zpart, Apout);

    // ---- gate + fused MFMA output ----
    gate_avg<<<dim3(8, 16), 256, 0, stream>>>(x, avgpart);
    gate_final<<<dim3(1), 128, 0, stream>>>(avgpart, Wg, bg, gates);
    out_gemm_hilo<<<dim3(16, 32), 256, 0, stream>>>(Asout, Apout,
                                                    wo1hi, wo1lo, wo2hi, wo2lo,
                                                    bo_s, bo_p, gates,
                                                    (float*)d_out);
}